// Round 1
// baseline (1198.784 us; speedup 1.0000x reference)
//
#include <hip/hip_runtime.h>
#include <hip/hip_bf16.h>
#include <math.h>

// Problem dims (compile-time constants)
#define BATCH   2
#define SEQ     1024
#define DMODEL  768
#define DINNER  1536
#define DSTATE  16
#define DTRANK  48
#define NTOK    (BATCH*SEQ)          // 2048
#define XPROJ_N (DTRANK + 2*DSTATE)  // 80

// ---------------- Generic TN SGEMM: C[m,n] = act( sum_k A[m,lda+k] * W[n*K+k] + bias[n] ) ----------------
// BM=BN=64, BK=16, block 16x16 threads, 4x4 per thread.
#define BM 64
#define BN 64
#define BK 16

template<int ACT>  // 0 = none, 1 = softplus(x + bias)
__global__ __launch_bounds__(256)
void gemm_tn(const float* __restrict__ A, const float* __restrict__ W,
             const float* __restrict__ bias, float* __restrict__ C,
             int M, int N, int K, int lda)
{
    __shared__ float As[BK][BM + 4];   // pad 4 -> writes are 2-way (free), reads clean
    __shared__ float Ws[BK][BN + 4];

    const int t  = threadIdx.x;
    const int tx = t & 15;
    const int ty = t >> 4;
    const int row0 = blockIdx.y * BM;
    const int col0 = blockIdx.x * BN;

    // loader mapping: each thread loads one float4 of A-tile and one of W-tile
    const int m_l = t >> 2;          // 0..63
    const int k_l = (t & 3) * 4;     // 0,4,8,12

    float acc[4][4] = {};

    for (int kt = 0; kt < K; kt += BK) {
        float4 av, wv;
        {
            const float* ap = A + (size_t)(row0 + m_l) * lda + kt + k_l;
            av = *reinterpret_cast<const float4*>(ap);
        }
        {
            const int wn = col0 + m_l;
            if (wn < N) {
                const float* wp = W + (size_t)wn * K + kt + k_l;
                wv = *reinterpret_cast<const float4*>(wp);
            } else {
                wv = make_float4(0.f, 0.f, 0.f, 0.f);
            }
        }
        __syncthreads();   // protect previous-iteration LDS reads
        As[k_l + 0][m_l] = av.x; As[k_l + 1][m_l] = av.y;
        As[k_l + 2][m_l] = av.z; As[k_l + 3][m_l] = av.w;
        Ws[k_l + 0][m_l] = wv.x; Ws[k_l + 1][m_l] = wv.y;
        Ws[k_l + 2][m_l] = wv.z; Ws[k_l + 3][m_l] = wv.w;
        __syncthreads();

        #pragma unroll
        for (int k = 0; k < BK; ++k) {
            float4 a4 = *reinterpret_cast<const float4*>(&As[k][ty * 4]);
            float4 w4 = *reinterpret_cast<const float4*>(&Ws[k][tx * 4]);
            float af[4] = {a4.x, a4.y, a4.z, a4.w};
            float wf[4] = {w4.x, w4.y, w4.z, w4.w};
            #pragma unroll
            for (int i = 0; i < 4; ++i)
                #pragma unroll
                for (int j = 0; j < 4; ++j)
                    acc[i][j] += af[i] * wf[j];
        }
    }

    #pragma unroll
    for (int i = 0; i < 4; ++i) {
        const int m = row0 + ty * 4 + i;
        #pragma unroll
        for (int j = 0; j < 4; ++j) {
            const int n = col0 + tx * 4 + j;
            if (n < N) {
                float v = acc[i][j];
                if (ACT == 1) {
                    v += bias[n];
                    v = (v > 20.f) ? v : log1pf(expf(v));   // softplus
                }
                C[(size_t)m * N + n] = v;
            }
        }
    }
}

// ---------------- depthwise causal conv (k=4) + bias + SiLU ----------------
// xb = first DINNER columns of xz rows (row stride 2*DINNER)
__global__ __launch_bounds__(256)
void conv_silu(const float* __restrict__ xz, const float* __restrict__ cw,
               const float* __restrict__ cb, float* __restrict__ xc)
{
    int idx = blockIdx.x * 256 + threadIdx.x;      // over NTOK*DINNER
    if (idx >= NTOK * DINNER) return;
    const int c = idx % DINNER;
    const int m = idx / DINNER;                    // b*SEQ + l
    const int l = m & (SEQ - 1);

    const float w0 = cw[c * 4 + 0], w1 = cw[c * 4 + 1],
                w2 = cw[c * 4 + 2], w3 = cw[c * 4 + 3];
    const float* base = xz + (size_t)m * (2 * DINNER) + c;

    float acc = cb[c] + base[0] * w3;
    if (l >= 1) acc += base[-(2 * DINNER)]     * w2;
    if (l >= 2) acc += base[-2 * (2 * DINNER)] * w1;
    if (l >= 3) acc += base[-3 * (2 * DINNER)] * w0;

    const float sig = 1.f / (1.f + __expf(-acc));
    xc[idx] = acc * sig;
}

// ---------------- selective scan, fused with +u*D and *silu(z) epilogue ----------------
// block: 1024 threads = 64 channels x 16 states; grid: (BATCH, DINNER/64)
__global__ __launch_bounds__(1024)
void scan_kernel(const float* __restrict__ dt,    // (NTOK, DINNER)
                 const float* __restrict__ xc,    // (NTOK, DINNER)
                 const float* __restrict__ xdbl,  // (NTOK, 80): [0:48]=dtr [48:64]=B [64:80]=C
                 const float* __restrict__ xz,    // (NTOK, 3072): z at col 1536+d
                 const float* __restrict__ A_log, // (DINNER, 16)
                 const float* __restrict__ Dp,    // (DINNER)
                 float* __restrict__ y)           // (NTOK, DINNER)
{
    const int b  = blockIdx.x;
    const int d0 = blockIdx.y * 64;
    const int tid = threadIdx.x;
    const int dl = tid >> 4;
    const int s  = tid & 15;
    const int d  = d0 + dl;

    const float Aval = -expf(A_log[d * DSTATE + s]);
    const float Dd   = Dp[d];
    float h = 0.f;

    const size_t rowbase = (size_t)b * SEQ;
    for (int l = 0; l < SEQ; ++l) {
        const size_t m = rowbase + l;
        const float dtv = dt[m * DINNER + d];
        const float u   = xc[m * DINNER + d];
        const float Bv  = xdbl[m * XPROJ_N + DTRANK + s];
        const float Cv  = xdbl[m * XPROJ_N + DTRANK + DSTATE + s];

        const float dA = __expf(dtv * Aval);
        h = h * dA + dtv * u * Bv;

        float p = h * Cv;
        p += __shfl_xor(p, 1);
        p += __shfl_xor(p, 2);
        p += __shfl_xor(p, 4);
        p += __shfl_xor(p, 8);

        if (s == 0) {
            const float zv  = xz[m * (2 * DINNER) + DINNER + d];
            const float yv  = p + u * Dd;
            const float sig = 1.f / (1.f + __expf(-zv));
            y[m * DINNER + d] = yv * zv * sig;
        }
    }
}

// ---------------- residual + LayerNorm ----------------
// one block (256 threads) per row of 768
__global__ __launch_bounds__(256)
void ln_kernel(const float* __restrict__ mo, const float* __restrict__ x,
               const float* __restrict__ w, const float* __restrict__ bias,
               float* __restrict__ out)
{
    const int m = blockIdx.x;
    const int t = threadIdx.x;
    const float* mrow = mo + (size_t)m * DMODEL;
    const float* xrow = x  + (size_t)m * DMODEL;

    float v[3];
    float sum = 0.f, ss = 0.f;
    #pragma unroll
    for (int i = 0; i < 3; ++i) {
        const int col = t + 256 * i;
        v[i] = mrow[col] + xrow[col];
        sum += v[i];
        ss  += v[i] * v[i];
    }
    #pragma unroll
    for (int o = 1; o < 64; o <<= 1) {
        sum += __shfl_xor(sum, o);
        ss  += __shfl_xor(ss, o);
    }
    __shared__ float red[2][4];
    const int wid = t >> 6;
    if ((t & 63) == 0) { red[0][wid] = sum; red[1][wid] = ss; }
    __syncthreads();
    sum = red[0][0] + red[0][1] + red[0][2] + red[0][3];
    ss  = red[1][0] + red[1][1] + red[1][2] + red[1][3];

    const float mu   = sum * (1.f / DMODEL);
    const float var  = ss * (1.f / DMODEL) - mu * mu;
    const float rstd = rsqrtf(var + 1e-5f);

    #pragma unroll
    for (int i = 0; i < 3; ++i) {
        const int col = t + 256 * i;
        out[(size_t)m * DMODEL + col] = (v[i] - mu) * rstd * w[col] + bias[col];
    }
}

// ---------------- launcher ----------------
extern "C" void kernel_launch(void* const* d_in, const int* in_sizes, int n_in,
                              void* d_out, int out_size, void* d_ws, size_t ws_size,
                              hipStream_t stream)
{
    const float* x          = (const float*)d_in[0];
    const float* in_proj_w  = (const float*)d_in[1];
    const float* conv_w     = (const float*)d_in[2];
    const float* conv_b     = (const float*)d_in[3];
    const float* x_proj_w   = (const float*)d_in[4];
    const float* dt_proj_w  = (const float*)d_in[5];
    const float* dt_proj_b  = (const float*)d_in[6];
    const float* A_log      = (const float*)d_in[7];
    const float* Dp         = (const float*)d_in[8];
    const float* out_proj_w = (const float*)d_in[9];
    const float* ln_w       = (const float*)d_in[10];
    const float* ln_b       = (const float*)d_in[11];
    float* out = (float*)d_out;

    // workspace layout (floats), all 16B-aligned offsets
    float* ws   = (float*)d_ws;
    float* xz   = ws;                         // NTOK*3072
    float* xc   = xz  + (size_t)NTOK * 3072;  // NTOK*1536
    float* xdbl = xc  + (size_t)NTOK * 1536;  // NTOK*80
    float* dt   = xdbl+ (size_t)NTOK * 80;    // NTOK*1536
    float* yb   = dt  + (size_t)NTOK * 1536;  // NTOK*1536
    float* mo   = yb  + (size_t)NTOK * 1536;  // NTOK*768

    // 1) xz = x @ in_proj_w^T           (2048 x 3072, K=768)
    gemm_tn<0><<<dim3(2 * DINNER / BN, NTOK / BM), 256, 0, stream>>>(
        x, in_proj_w, nullptr, xz, NTOK, 2 * DINNER, DMODEL, DMODEL);

    // 2) xc = silu(conv(xb) + conv_b)
    conv_silu<<<(NTOK * DINNER) / 256, 256, 0, stream>>>(xz, conv_w, conv_b, xc);

    // 3) x_dbl = xc @ x_proj_w^T        (2048 x 80, K=1536)
    gemm_tn<0><<<dim3((XPROJ_N + BN - 1) / BN, NTOK / BM), 256, 0, stream>>>(
        xc, x_proj_w, nullptr, xdbl, NTOK, XPROJ_N, DINNER, DINNER);

    // 4) dt = softplus(dtr @ dt_proj_w^T + dt_proj_b)   (2048 x 1536, K=48, lda=80)
    gemm_tn<1><<<dim3(DINNER / BN, NTOK / BM), 256, 0, stream>>>(
        xdbl, dt_proj_w, dt_proj_b, dt, NTOK, DINNER, DTRANK, XPROJ_N);

    // 5) selective scan fused with (+u*D) * silu(z)
    scan_kernel<<<dim3(BATCH, DINNER / 64), 1024, 0, stream>>>(
        dt, xc, xdbl, xz, A_log, Dp, yb);

    // 6) mo = y @ out_proj_w^T          (2048 x 768, K=1536)
    gemm_tn<0><<<dim3(DMODEL / BN, NTOK / BM), 256, 0, stream>>>(
        yb, out_proj_w, nullptr, mo, NTOK, DMODEL, DINNER, DINNER);

    // 7) out = LayerNorm(mo + x) * ln_w + ln_b
    ln_kernel<<<NTOK, 256, 0, stream>>>(mo, x, ln_w, ln_b, out);
}

// Round 2
// 556.795 us; speedup vs baseline: 2.1530x; 2.1530x over previous
//
#include <hip/hip_runtime.h>
#include <hip/hip_bf16.h>
#include <math.h>

// Problem dims (compile-time constants)
#define BATCH   2
#define SEQ     1024
#define DMODEL  768
#define DINNER  1536
#define DSTATE  16
#define DTRANK  48
#define NTOK    (BATCH*SEQ)          // 2048
#define XPROJ_N (DTRANK + 2*DSTATE)  // 80

// chunked scan params
#define LC      64                   // chunk length
#define NC      (SEQ/LC)             // 16 chunks

// ---------------- Generic TN SGEMM: C[m,n] = act( sum_k A[m,lda+k] * W[n*K+k] + bias[n] ) ----------------
// BM=BN=64, BK=16, block 16x16 threads, 4x4 per thread.
#define BM 64
#define BN 64
#define BK 16

template<int ACT>  // 0 = none, 1 = softplus(x + bias)
__global__ __launch_bounds__(256)
void gemm_tn(const float* __restrict__ A, const float* __restrict__ W,
             const float* __restrict__ bias, float* __restrict__ C,
             int M, int N, int K, int lda)
{
    __shared__ float As[BK][BM + 4];
    __shared__ float Ws[BK][BN + 4];

    const int t  = threadIdx.x;
    const int tx = t & 15;
    const int ty = t >> 4;
    const int row0 = blockIdx.y * BM;
    const int col0 = blockIdx.x * BN;

    const int m_l = t >> 2;          // 0..63
    const int k_l = (t & 3) * 4;     // 0,4,8,12

    float acc[4][4] = {};

    for (int kt = 0; kt < K; kt += BK) {
        float4 av, wv;
        {
            const float* ap = A + (size_t)(row0 + m_l) * lda + kt + k_l;
            av = *reinterpret_cast<const float4*>(ap);
        }
        {
            const int wn = col0 + m_l;
            if (wn < N) {
                const float* wp = W + (size_t)wn * K + kt + k_l;
                wv = *reinterpret_cast<const float4*>(wp);
            } else {
                wv = make_float4(0.f, 0.f, 0.f, 0.f);
            }
        }
        __syncthreads();   // protect previous-iteration LDS reads
        As[k_l + 0][m_l] = av.x; As[k_l + 1][m_l] = av.y;
        As[k_l + 2][m_l] = av.z; As[k_l + 3][m_l] = av.w;
        Ws[k_l + 0][m_l] = wv.x; Ws[k_l + 1][m_l] = wv.y;
        Ws[k_l + 2][m_l] = wv.z; Ws[k_l + 3][m_l] = wv.w;
        __syncthreads();

        #pragma unroll
        for (int k = 0; k < BK; ++k) {
            float4 a4 = *reinterpret_cast<const float4*>(&As[k][ty * 4]);
            float4 w4 = *reinterpret_cast<const float4*>(&Ws[k][tx * 4]);
            float af[4] = {a4.x, a4.y, a4.z, a4.w};
            float wf[4] = {w4.x, w4.y, w4.z, w4.w};
            #pragma unroll
            for (int i = 0; i < 4; ++i)
                #pragma unroll
                for (int j = 0; j < 4; ++j)
                    acc[i][j] += af[i] * wf[j];
        }
    }

    #pragma unroll
    for (int i = 0; i < 4; ++i) {
        const int m = row0 + ty * 4 + i;
        #pragma unroll
        for (int j = 0; j < 4; ++j) {
            const int n = col0 + tx * 4 + j;
            if (n < N) {
                float v = acc[i][j];
                if (ACT == 1) {
                    v += bias[n];
                    v = (v > 20.f) ? v : log1pf(expf(v));   // softplus
                }
                C[(size_t)m * N + n] = v;
            }
        }
    }
}

// ---------------- depthwise causal conv (k=4) + bias + SiLU ----------------
__global__ __launch_bounds__(256)
void conv_silu(const float* __restrict__ xz, const float* __restrict__ cw,
               const float* __restrict__ cb, float* __restrict__ xc)
{
    int idx = blockIdx.x * 256 + threadIdx.x;      // over NTOK*DINNER
    if (idx >= NTOK * DINNER) return;
    const int c = idx % DINNER;
    const int m = idx / DINNER;                    // b*SEQ + l
    const int l = m & (SEQ - 1);

    const float w0 = cw[c * 4 + 0], w1 = cw[c * 4 + 1],
                w2 = cw[c * 4 + 2], w3 = cw[c * 4 + 3];
    const float* base = xz + (size_t)m * (2 * DINNER) + c;

    float acc = cb[c] + base[0] * w3;
    if (l >= 1) acc += base[-(2 * DINNER)]     * w2;
    if (l >= 2) acc += base[-2 * (2 * DINNER)] * w1;
    if (l >= 3) acc += base[-3 * (2 * DINNER)] * w0;

    const float sig = 1.f / (1.f + __expf(-acc));
    xc[idx] = acc * sig;
}

// ---------------- chunked selective scan ----------------
// Recurrence h_l = dA_l * h_{l-1} + dt_l*u_l*B_l is linear in h ->
// chunk c maps h_start -> aP_c * h_start + hA_c, with
// aP_c = prod(dA) = exp(A * sum dt), hA_c = chunk scan from h=0.

// Phase A: per (b, chunk, d, s): chunk-local scan from 0.
// grid (NC, DINNER/16, BATCH); block 256 = 16 ch x 16 s.
__global__ __launch_bounds__(256)
void scan_chunk_state(const float* __restrict__ dt, const float* __restrict__ xc,
                      const float* __restrict__ xdbl, const float* __restrict__ A_log,
                      float* __restrict__ hA, float* __restrict__ aP)
{
    const int c = blockIdx.x;
    const int b = blockIdx.z;
    const int d = blockIdx.y * 16 + (threadIdx.x >> 4);
    const int s = threadIdx.x & 15;

    const float Aval = -expf(A_log[d * DSTATE + s]);

    const size_t row0 = (size_t)b * SEQ + (size_t)c * LC;
    const float* dtp = dt   + row0 * DINNER  + d;
    const float* up  = xc   + row0 * DINNER  + d;
    const float* Bp  = xdbl + row0 * XPROJ_N + DTRANK + s;

    float h = 0.f, dts = 0.f;
    #pragma unroll 4
    for (int l = 0; l < LC; ++l) {
        const float dtv = dtp[(size_t)l * DINNER];
        const float u   = up [(size_t)l * DINNER];
        const float Bv  = Bp [(size_t)l * XPROJ_N];
        dts += dtv;
        h = h * __expf(dtv * Aval) + dtv * u * Bv;
    }

    const size_t o = (((size_t)(b * NC + c) * DINNER) + d) * DSTATE + s;
    hA[o] = h;
    aP[o] = __expf(Aval * dts);
}

// Phase B: sequential combine over NC chunk aggregates per (b,d,s).
// hA is rewritten in place to hold the INITIAL state of each chunk.
__global__ __launch_bounds__(256)
void scan_combine(float* __restrict__ hA, const float* __restrict__ aP)
{
    const int idx = blockIdx.x * 256 + threadIdx.x;   // over BATCH*DINNER*DSTATE
    const int b  = idx / (DINNER * DSTATE);
    const int ds = idx % (DINNER * DSTATE);

    float h = 0.f;
    #pragma unroll
    for (int c = 0; c < NC; ++c) {
        const size_t o = ((size_t)(b * NC + c) * DINNER * DSTATE) + ds;
        const float a = hA[o];
        const float p = aP[o];
        hA[o] = h;                 // initial state for chunk c
        h = a + h * p;
    }
}

// Phase C: re-run each chunk from its true initial state; emit
// y = (C.h + u*D) * silu(z).
__global__ __launch_bounds__(256)
void scan_apply(const float* __restrict__ dt, const float* __restrict__ xc,
                const float* __restrict__ xdbl, const float* __restrict__ xz,
                const float* __restrict__ A_log, const float* __restrict__ Dp,
                const float* __restrict__ hInit, float* __restrict__ y)
{
    const int c = blockIdx.x;
    const int b = blockIdx.z;
    const int d = blockIdx.y * 16 + (threadIdx.x >> 4);
    const int s = threadIdx.x & 15;

    const float Aval = -expf(A_log[d * DSTATE + s]);
    const float Dd   = Dp[d];

    const size_t o = (((size_t)(b * NC + c) * DINNER) + d) * DSTATE + s;
    float h = hInit[o];

    const size_t row0 = (size_t)b * SEQ + (size_t)c * LC;
    for (int l = 0; l < LC; ++l) {
        const size_t m = row0 + l;
        const float dtv = dt[m * DINNER + d];
        const float u   = xc[m * DINNER + d];
        const float Bv  = xdbl[m * XPROJ_N + DTRANK + s];
        const float Cv  = xdbl[m * XPROJ_N + DTRANK + DSTATE + s];

        h = h * __expf(dtv * Aval) + dtv * u * Bv;

        float p = h * Cv;
        p += __shfl_xor(p, 1);
        p += __shfl_xor(p, 2);
        p += __shfl_xor(p, 4);
        p += __shfl_xor(p, 8);

        if (s == 0) {
            const float zv  = xz[m * (2 * DINNER) + DINNER + d];
            const float yv  = p + u * Dd;
            const float sig = 1.f / (1.f + __expf(-zv));
            y[m * DINNER + d] = yv * zv * sig;
        }
    }
}

// ---------------- residual + LayerNorm ----------------
__global__ __launch_bounds__(256)
void ln_kernel(const float* __restrict__ mo, const float* __restrict__ x,
               const float* __restrict__ w, const float* __restrict__ bias,
               float* __restrict__ out)
{
    const int m = blockIdx.x;
    const int t = threadIdx.x;
    const float* mrow = mo + (size_t)m * DMODEL;
    const float* xrow = x  + (size_t)m * DMODEL;

    float v[3];
    float sum = 0.f, ss = 0.f;
    #pragma unroll
    for (int i = 0; i < 3; ++i) {
        const int col = t + 256 * i;
        v[i] = mrow[col] + xrow[col];
        sum += v[i];
        ss  += v[i] * v[i];
    }
    #pragma unroll
    for (int o = 1; o < 64; o <<= 1) {
        sum += __shfl_xor(sum, o);
        ss  += __shfl_xor(ss, o);
    }
    __shared__ float red[2][4];
    const int wid = t >> 6;
    if ((t & 63) == 0) { red[0][wid] = sum; red[1][wid] = ss; }
    __syncthreads();
    sum = red[0][0] + red[0][1] + red[0][2] + red[0][3];
    ss  = red[1][0] + red[1][1] + red[1][2] + red[1][3];

    const float mu   = sum * (1.f / DMODEL);
    const float var  = ss * (1.f / DMODEL) - mu * mu;
    const float rstd = rsqrtf(var + 1e-5f);

    #pragma unroll
    for (int i = 0; i < 3; ++i) {
        const int col = t + 256 * i;
        out[(size_t)m * DMODEL + col] = (v[i] - mu) * rstd * w[col] + bias[col];
    }
}

// ---------------- launcher ----------------
extern "C" void kernel_launch(void* const* d_in, const int* in_sizes, int n_in,
                              void* d_out, int out_size, void* d_ws, size_t ws_size,
                              hipStream_t stream)
{
    const float* x          = (const float*)d_in[0];
    const float* in_proj_w  = (const float*)d_in[1];
    const float* conv_w     = (const float*)d_in[2];
    const float* conv_b     = (const float*)d_in[3];
    const float* x_proj_w   = (const float*)d_in[4];
    const float* dt_proj_w  = (const float*)d_in[5];
    const float* dt_proj_b  = (const float*)d_in[6];
    const float* A_log      = (const float*)d_in[7];
    const float* Dp         = (const float*)d_in[8];
    const float* out_proj_w = (const float*)d_in[9];
    const float* ln_w       = (const float*)d_in[10];
    const float* ln_b       = (const float*)d_in[11];
    float* out = (float*)d_out;

    // workspace layout (floats) — identical footprint to round 1 (~70 MB)
    float* ws   = (float*)d_ws;
    float* xz   = ws;                         // NTOK*3072
    float* xc   = xz  + (size_t)NTOK * 3072;  // NTOK*1536
    float* xdbl = xc  + (size_t)NTOK * 1536;  // NTOK*80
    float* dt   = xdbl+ (size_t)NTOK * 80;    // NTOK*1536
    float* yb   = dt  + (size_t)NTOK * 1536;  // NTOK*1536
    float* mo   = yb  + (size_t)NTOK * 1536;  // NTOK*768

    // scan scratch aliased onto regions dead during the scan:
    //   aP (3.1 MB)        -> mo region (6.3 MB, written only after scan)
    //   hA/hInit (3.1 MB)  -> d_out      (6.3 MB, written only by ln_kernel)
    float* aP = mo;
    float* hA = (float*)d_out;

    // 1) xz = x @ in_proj_w^T           (2048 x 3072, K=768)
    gemm_tn<0><<<dim3(2 * DINNER / BN, NTOK / BM), 256, 0, stream>>>(
        x, in_proj_w, nullptr, xz, NTOK, 2 * DINNER, DMODEL, DMODEL);

    // 2) xc = silu(conv(xb) + conv_b)
    conv_silu<<<(NTOK * DINNER) / 256, 256, 0, stream>>>(xz, conv_w, conv_b, xc);

    // 3) x_dbl = xc @ x_proj_w^T        (2048 x 80, K=1536)
    gemm_tn<0><<<dim3((XPROJ_N + BN - 1) / BN, NTOK / BM), 256, 0, stream>>>(
        xc, x_proj_w, nullptr, xdbl, NTOK, XPROJ_N, DINNER, DINNER);

    // 4) dt = softplus(dtr @ dt_proj_w^T + dt_proj_b)   (2048 x 1536, K=48, lda=80)
    gemm_tn<1><<<dim3(DINNER / BN, NTOK / BM), 256, 0, stream>>>(
        xdbl, dt_proj_w, dt_proj_b, dt, NTOK, DINNER, DTRANK, XPROJ_N);

    // 5) chunked selective scan (3 phases), fused epilogue in phase C
    scan_chunk_state<<<dim3(NC, DINNER / 16, BATCH), 256, 0, stream>>>(
        dt, xc, xdbl, A_log, hA, aP);
    scan_combine<<<(BATCH * DINNER * DSTATE) / 256, 256, 0, stream>>>(hA, aP);
    scan_apply<<<dim3(NC, DINNER / 16, BATCH), 256, 0, stream>>>(
        dt, xc, xdbl, xz, A_log, Dp, hA, yb);

    // 6) mo = y @ out_proj_w^T          (2048 x 768, K=1536)
    gemm_tn<0><<<dim3(DMODEL / BN, NTOK / BM), 256, 0, stream>>>(
        yb, out_proj_w, nullptr, mo, NTOK, DMODEL, DINNER, DINNER);

    // 7) out = LayerNorm(mo + x) * ln_w + ln_b
    ln_kernel<<<NTOK, 256, 0, stream>>>(mo, x, ln_w, ln_b, out);
}

// Round 4
// 385.472 us; speedup vs baseline: 3.1099x; 1.4444x over previous
//
#include <hip/hip_runtime.h>
#include <hip/hip_bf16.h>
#include <math.h>

// Problem dims (compile-time constants)
#define BATCH   2
#define SEQ     1024
#define DMODEL  768
#define DINNER  1536
#define DSTATE  16
#define DTRANK  48
#define NTOK    (BATCH*SEQ)          // 2048
#define XPROJ_N (DTRANK + 2*DSTATE)  // 80

// chunked scan params
#define LC      64
#define NC      (SEQ/LC)             // 16

typedef unsigned short ushort_t;
typedef __attribute__((ext_vector_type(8))) short bf16x8;
typedef __attribute__((ext_vector_type(4))) float f32x4;

__device__ __forceinline__ ushort_t f2bf(float f) {
    unsigned int u = __float_as_uint(f);
    u += 0x7FFF + ((u >> 16) & 1);       // round-to-nearest-even
    return (ushort_t)(u >> 16);
}

// ---------------- fused fp32 -> bf16 converter (3 segments) ----------------
__global__ __launch_bounds__(256)
void f2b_3(const float* __restrict__ s0, ushort_t* __restrict__ d0, int n0,
           const float* __restrict__ s1, ushort_t* __restrict__ d1, int n1,
           const float* __restrict__ s2, ushort_t* __restrict__ d2, int n2)
{
    const int i = (blockIdx.x * 256 + threadIdx.x) * 4;
    const float* s; ushort_t* d;
    if (i < n0)               { s = s0 + i;            d = d0 + i; }
    else if (i < n0 + n1)     { s = s1 + (i - n0);     d = d1 + (i - n0); }
    else if (i < n0 + n1 + n2){ s = s2 + (i - n0 - n1);d = d2 + (i - n0 - n1); }
    else return;
    const float4 v = *reinterpret_cast<const float4*>(s);
    ushort4 o;
    o.x = f2bf(v.x); o.y = f2bf(v.y); o.z = f2bf(v.z); o.w = f2bf(v.w);
    *reinterpret_cast<ushort4*>(d) = o;
}

// ---------------- bf16 MFMA GEMM (TN / "B^T input"): C[m,n] = sum_k A[m,k]*W[n,k] ----------------
// m93/m97 structure: 128x128 tile, BK=32, 4 waves of 64x64 (4x4 16x16x32 frags),
// global_load_lds width-16 staging, linear LDS, 2-barrier K-loop.
// Requires M%128==0, N%128==0, K%32==0.
#define GLOAD_LDS16(gp, lp) \
    __builtin_amdgcn_global_load_lds((const __attribute__((address_space(1))) void*)(gp), \
                                     (__attribute__((address_space(3))) void*)(lp), 16, 0, 0)

__global__ __launch_bounds__(256)
void gemm_mfma_bt(const ushort_t* __restrict__ A, const ushort_t* __restrict__ W,
                  float* __restrict__ C, int M, int N, int K)
{
    __shared__ ushort_t As[128 * 32];
    __shared__ ushort_t Bs[128 * 32];

    const int tid  = threadIdx.x;
    const int w    = tid >> 6;
    const int lane = tid & 63;
    const int m0 = blockIdx.y * 128;
    const int n0 = blockIdx.x * 128;

    // staging map: each wave-call covers 16 rows (lane/4) x 4 col-blocks (lane%4)*8
    const int lrow = lane >> 2;
    const int lcol = (lane & 3) * 8;

    const ushort_t* ga0 = A + (size_t)(m0 + w * 16 + lrow) * K + lcol;
    const ushort_t* ga1 = ga0 + (size_t)64 * K;
    const ushort_t* gb0 = W + (size_t)(n0 + w * 16 + lrow) * K + lcol;
    const ushort_t* gb1 = gb0 + (size_t)64 * K;

    // wave-uniform LDS bases; HW writes lane i at base + i*16B
    ushort_t* lA0 = As + w * 512;
    ushort_t* lA1 = As + 64 * 32 + w * 512;
    ushort_t* lB0 = Bs + w * 512;
    ushort_t* lB1 = Bs + 64 * 32 + w * 512;

    const int wm = w >> 1, wn = w & 1;   // 2x2 wave grid
    const int fr = lane & 15;            // fragment row (A) / col (B)
    const int kg = lane >> 4;            // k-group (8 elems each)

    f32x4 acc[4][4] = {};

    for (int kt = 0; kt < K; kt += 32) {
        __syncthreads();                 // prev iteration's LDS reads complete
        GLOAD_LDS16(ga0 + kt, lA0);
        GLOAD_LDS16(ga1 + kt, lA1);
        GLOAD_LDS16(gb0 + kt, lB0);
        GLOAD_LDS16(gb1 + kt, lB1);
        __syncthreads();                 // staging drained (vmcnt(0) before barrier)

        bf16x8 af[4], bfr[4];
        #pragma unroll
        for (int i = 0; i < 4; ++i) {
            af[i]  = *reinterpret_cast<const bf16x8*>(&As[(wm * 64 + i * 16 + fr) * 32 + kg * 8]);
            bfr[i] = *reinterpret_cast<const bf16x8*>(&Bs[(wn * 64 + i * 16 + fr) * 32 + kg * 8]);
        }
        #pragma unroll
        for (int i = 0; i < 4; ++i)
            #pragma unroll
            for (int j = 0; j < 4; ++j)
                acc[i][j] = __builtin_amdgcn_mfma_f32_16x16x32_bf16(af[i], bfr[j], acc[i][j], 0, 0, 0);
    }

    // C/D layout: col = lane&15, row = (lane>>4)*4 + reg   [guide §3, m89/m91-verified]
    #pragma unroll
    for (int i = 0; i < 4; ++i) {
        const int row_base = m0 + wm * 64 + i * 16 + kg * 4;
        #pragma unroll
        for (int j = 0; j < 4; ++j) {
            const int col = n0 + wn * 64 + j * 16 + fr;
            #pragma unroll
            for (int r = 0; r < 4; ++r)
                C[(size_t)(row_base + r) * N + col] = acc[i][j][r];
        }
    }
}

// ---------------- fp32 fallback SGEMM (small GEMMs: x_proj, dt_proj) ----------------
#define BM 64
#define BN 64
#define BK 16

template<int ACT>  // 0 = none, 1 = softplus(x + bias)
__global__ __launch_bounds__(256)
void gemm_tn(const float* __restrict__ A, const float* __restrict__ W,
             const float* __restrict__ bias, float* __restrict__ C,
             int M, int N, int K, int lda)
{
    __shared__ float As[BK][BM + 4];
    __shared__ float Ws[BK][BN + 4];

    const int t  = threadIdx.x;
    const int tx = t & 15;
    const int ty = t >> 4;
    const int row0 = blockIdx.y * BM;
    const int col0 = blockIdx.x * BN;

    const int m_l = t >> 2;
    const int k_l = (t & 3) * 4;

    float acc[4][4] = {};

    for (int kt = 0; kt < K; kt += BK) {
        float4 av, wv;
        {
            const float* ap = A + (size_t)(row0 + m_l) * lda + kt + k_l;
            av = *reinterpret_cast<const float4*>(ap);
        }
        {
            const int wn = col0 + m_l;
            if (wn < N) {
                const float* wp = W + (size_t)wn * K + kt + k_l;
                wv = *reinterpret_cast<const float4*>(wp);
            } else {
                wv = make_float4(0.f, 0.f, 0.f, 0.f);
            }
        }
        __syncthreads();
        As[k_l + 0][m_l] = av.x; As[k_l + 1][m_l] = av.y;
        As[k_l + 2][m_l] = av.z; As[k_l + 3][m_l] = av.w;
        Ws[k_l + 0][m_l] = wv.x; Ws[k_l + 1][m_l] = wv.y;
        Ws[k_l + 2][m_l] = wv.z; Ws[k_l + 3][m_l] = wv.w;
        __syncthreads();

        #pragma unroll
        for (int k = 0; k < BK; ++k) {
            float4 a4 = *reinterpret_cast<const float4*>(&As[k][ty * 4]);
            float4 w4 = *reinterpret_cast<const float4*>(&Ws[k][tx * 4]);
            float af[4] = {a4.x, a4.y, a4.z, a4.w};
            float wf[4] = {w4.x, w4.y, w4.z, w4.w};
            #pragma unroll
            for (int i = 0; i < 4; ++i)
                #pragma unroll
                for (int j = 0; j < 4; ++j)
                    acc[i][j] += af[i] * wf[j];
        }
    }

    #pragma unroll
    for (int i = 0; i < 4; ++i) {
        const int m = row0 + ty * 4 + i;
        #pragma unroll
        for (int j = 0; j < 4; ++j) {
            const int n = col0 + tx * 4 + j;
            if (n < N) {
                float v = acc[i][j];
                if (ACT == 1) {
                    v += bias[n];
                    v = (v > 20.f) ? v : log1pf(expf(v));
                }
                C[(size_t)m * N + n] = v;
            }
        }
    }
}

// ---------------- depthwise causal conv (k=4) + bias + SiLU ----------------
__global__ __launch_bounds__(256)
void conv_silu(const float* __restrict__ xz, const float* __restrict__ cw,
               const float* __restrict__ cb, float* __restrict__ xc)
{
    int idx = blockIdx.x * 256 + threadIdx.x;
    if (idx >= NTOK * DINNER) return;
    const int c = idx % DINNER;
    const int m = idx / DINNER;
    const int l = m & (SEQ - 1);

    const float w0 = cw[c * 4 + 0], w1 = cw[c * 4 + 1],
                w2 = cw[c * 4 + 2], w3 = cw[c * 4 + 3];
    const float* base = xz + (size_t)m * (2 * DINNER) + c;

    float acc = cb[c] + base[0] * w3;
    if (l >= 1) acc += base[-(2 * DINNER)]     * w2;
    if (l >= 2) acc += base[-2 * (2 * DINNER)] * w1;
    if (l >= 3) acc += base[-3 * (2 * DINNER)] * w0;

    const float sig = 1.f / (1.f + __expf(-acc));
    xc[idx] = acc * sig;
}

// ---------------- chunked selective scan ----------------
__global__ __launch_bounds__(256)
void scan_chunk_state(const float* __restrict__ dt, const float* __restrict__ xc,
                      const float* __restrict__ xdbl, const float* __restrict__ A_log,
                      float* __restrict__ hA, float* __restrict__ aP)
{
    const int c = blockIdx.x;
    const int b = blockIdx.z;
    const int d = blockIdx.y * 16 + (threadIdx.x >> 4);
    const int s = threadIdx.x & 15;

    const float Aval = -expf(A_log[d * DSTATE + s]);

    const size_t row0 = (size_t)b * SEQ + (size_t)c * LC;
    const float* dtp = dt   + row0 * DINNER  + d;
    const float* up  = xc   + row0 * DINNER  + d;
    const float* Bp  = xdbl + row0 * XPROJ_N + DTRANK + s;

    float h = 0.f, dts = 0.f;
    #pragma unroll 4
    for (int l = 0; l < LC; ++l) {
        const float dtv = dtp[(size_t)l * DINNER];
        const float u   = up [(size_t)l * DINNER];
        const float Bv  = Bp [(size_t)l * XPROJ_N];
        dts += dtv;
        h = h * __expf(dtv * Aval) + dtv * u * Bv;
    }

    const size_t o = (((size_t)(b * NC + c) * DINNER) + d) * DSTATE + s;
    hA[o] = h;
    aP[o] = __expf(Aval * dts);
}

__global__ __launch_bounds__(256)
void scan_combine(float* __restrict__ hA, const float* __restrict__ aP)
{
    const int idx = blockIdx.x * 256 + threadIdx.x;
    const int b  = idx / (DINNER * DSTATE);
    const int ds = idx % (DINNER * DSTATE);

    float h = 0.f;
    #pragma unroll
    for (int c = 0; c < NC; ++c) {
        const size_t o = ((size_t)(b * NC + c) * DINNER * DSTATE) + ds;
        const float a = hA[o];
        const float p = aP[o];
        hA[o] = h;
        h = a + h * p;
    }
}

// Phase C: emit y = (C.h + u*D) * silu(z)  as BF16 (feeds out_proj MFMA GEMM)
__global__ __launch_bounds__(256)
void scan_apply(const float* __restrict__ dt, const float* __restrict__ xc,
                const float* __restrict__ xdbl, const float* __restrict__ xz,
                const float* __restrict__ A_log, const float* __restrict__ Dp,
                const float* __restrict__ hInit, ushort_t* __restrict__ y)
{
    const int c = blockIdx.x;
    const int b = blockIdx.z;
    const int d = blockIdx.y * 16 + (threadIdx.x >> 4);
    const int s = threadIdx.x & 15;

    const float Aval = -expf(A_log[d * DSTATE + s]);
    const float Dd   = Dp[d];

    const size_t o = (((size_t)(b * NC + c) * DINNER) + d) * DSTATE + s;
    float h = hInit[o];

    const size_t row0 = (size_t)b * SEQ + (size_t)c * LC;
    for (int l = 0; l < LC; ++l) {
        const size_t m = row0 + l;
        const float dtv = dt[m * DINNER + d];
        const float u   = xc[m * DINNER + d];
        const float Bv  = xdbl[m * XPROJ_N + DTRANK + s];
        const float Cv  = xdbl[m * XPROJ_N + DTRANK + DSTATE + s];

        h = h * __expf(dtv * Aval) + dtv * u * Bv;

        float p = h * Cv;
        p += __shfl_xor(p, 1);
        p += __shfl_xor(p, 2);
        p += __shfl_xor(p, 4);
        p += __shfl_xor(p, 8);

        if (s == 0) {
            const float zv  = xz[m * (2 * DINNER) + DINNER + d];
            const float yv  = p + u * Dd;
            const float sig = 1.f / (1.f + __expf(-zv));
            y[m * DINNER + d] = f2bf(yv * zv * sig);
        }
    }
}

// ---------------- residual + LayerNorm ----------------
__global__ __launch_bounds__(256)
void ln_kernel(const float* __restrict__ mo, const float* __restrict__ x,
               const float* __restrict__ w, const float* __restrict__ bias,
               float* __restrict__ out)
{
    const int m = blockIdx.x;
    const int t = threadIdx.x;
    const float* mrow = mo + (size_t)m * DMODEL;
    const float* xrow = x  + (size_t)m * DMODEL;

    float v[3];
    float sum = 0.f, ss = 0.f;
    #pragma unroll
    for (int i = 0; i < 3; ++i) {
        const int col = t + 256 * i;
        v[i] = mrow[col] + xrow[col];
        sum += v[i];
        ss  += v[i] * v[i];
    }
    #pragma unroll
    for (int o = 1; o < 64; o <<= 1) {
        sum += __shfl_xor(sum, o);
        ss  += __shfl_xor(ss, o);
    }
    __shared__ float red[2][4];
    const int wid = t >> 6;
    if ((t & 63) == 0) { red[0][wid] = sum; red[1][wid] = ss; }
    __syncthreads();
    sum = red[0][0] + red[0][1] + red[0][2] + red[0][3];
    ss  = red[1][0] + red[1][1] + red[1][2] + red[1][3];

    const float mu   = sum * (1.f / DMODEL);
    const float var  = ss * (1.f / DMODEL) - mu * mu;
    const float rstd = rsqrtf(var + 1e-5f);

    #pragma unroll
    for (int i = 0; i < 3; ++i) {
        const int col = t + 256 * i;
        out[(size_t)m * DMODEL + col] = (v[i] - mu) * rstd * w[col] + bias[col];
    }
}

// ---------------- launcher ----------------
extern "C" void kernel_launch(void* const* d_in, const int* in_sizes, int n_in,
                              void* d_out, int out_size, void* d_ws, size_t ws_size,
                              hipStream_t stream)
{
    const float* x          = (const float*)d_in[0];
    const float* in_proj_w  = (const float*)d_in[1];
    const float* conv_w     = (const float*)d_in[2];
    const float* conv_b     = (const float*)d_in[3];
    const float* x_proj_w   = (const float*)d_in[4];
    const float* dt_proj_w  = (const float*)d_in[5];
    const float* dt_proj_b  = (const float*)d_in[6];
    const float* A_log      = (const float*)d_in[7];
    const float* Dp         = (const float*)d_in[8];
    const float* out_proj_w = (const float*)d_in[9];
    const float* ln_w       = (const float*)d_in[10];
    const float* ln_b       = (const float*)d_in[11];
    float* out = (float*)d_out;

    // workspace layout (fp32 region then bf16 region), ~74 MB total
    float* ws   = (float*)d_ws;
    float* xz   = ws;                              // NTOK*3072 = 6,291,456
    float* xc   = xz   + (size_t)NTOK * 3072;      // NTOK*1536
    float* xdbl = xc   + (size_t)NTOK * 1536;      // NTOK*80
    float* dt   = xdbl + (size_t)NTOK * 80;        // NTOK*1536
    float* mo   = dt   + (size_t)NTOK * 1536;      // NTOK*768
    ushort_t* xb16 = (ushort_t*)(mo + (size_t)NTOK * 768);
    ushort_t* ipw16 = xb16  + (size_t)NTOK * DMODEL;          // 2*DINNER*DMODEL
    ushort_t* opw16 = ipw16 + (size_t)2 * DINNER * DMODEL;    // DMODEL*DINNER
    ushort_t* ybb   = opw16 + (size_t)DMODEL * DINNER;        // NTOK*DINNER

    // scan scratch aliases (regions dead during scan)
    float* aP = mo;             // 786,432 floats <= mo size
    float* hA = (float*)d_out;  // 786,432 floats <= out size

    // 0) bf16 conversions: x, in_proj_w, out_proj_w
    {
        const int n0 = NTOK * DMODEL;               // 1,572,864
        const int n1 = 2 * DINNER * DMODEL;         // 2,359,296
        const int n2 = DMODEL * DINNER;             // 1,179,648
        const int nvec = (n0 + n1 + n2) / 4;
        f2b_3<<<(nvec + 255) / 256, 256, 0, stream>>>(
            x, xb16, n0, in_proj_w, ipw16, n1, out_proj_w, opw16, n2);
    }

    // 1) xz = x @ in_proj_w^T   (bf16 MFMA; 2048 x 3072, K=768)
    gemm_mfma_bt<<<dim3(2 * DINNER / 128, NTOK / 128), 256, 0, stream>>>(
        xb16, ipw16, xz, NTOK, 2 * DINNER, DMODEL);

    // 2) xc = silu(conv(xb) + conv_b)
    conv_silu<<<(NTOK * DINNER) / 256, 256, 0, stream>>>(xz, conv_w, conv_b, xc);

    // 3) x_dbl = xc @ x_proj_w^T  (fp32; 2048 x 80, K=1536)
    gemm_tn<0><<<dim3((XPROJ_N + BN - 1) / BN, NTOK / BM), 256, 0, stream>>>(
        xc, x_proj_w, nullptr, xdbl, NTOK, XPROJ_N, DINNER, DINNER);

    // 4) dt = softplus(dtr @ dt_proj_w^T + dt_proj_b)  (fp32; K=48, lda=80)
    gemm_tn<1><<<dim3(DINNER / BN, NTOK / BM), 256, 0, stream>>>(
        xdbl, dt_proj_w, dt_proj_b, dt, NTOK, DINNER, DTRANK, XPROJ_N);

    // 5) chunked selective scan; phase C writes y as bf16
    scan_chunk_state<<<dim3(NC, DINNER / 16, BATCH), 256, 0, stream>>>(
        dt, xc, xdbl, A_log, hA, aP);
    scan_combine<<<(BATCH * DINNER * DSTATE) / 256, 256, 0, stream>>>(hA, aP);
    scan_apply<<<dim3(NC, DINNER / 16, BATCH), 256, 0, stream>>>(
        dt, xc, xdbl, xz, A_log, Dp, hA, ybb);

    // 6) mo = y @ out_proj_w^T  (bf16 MFMA; 2048 x 768, K=1536)
    gemm_mfma_bt<<<dim3(DMODEL / 128, NTOK / 128), 256, 0, stream>>>(
        ybb, opw16, mo, NTOK, DMODEL, DINNER);

    // 7) out = LayerNorm(mo + x) * ln_w + ln_b
    ln_kernel<<<NTOK, 256, 0, stream>>>(mo, x, ln_w, ln_b, out);
}

// Round 6
// 339.328 us; speedup vs baseline: 3.5328x; 1.1360x over previous
//
#include <hip/hip_runtime.h>
#include <hip/hip_bf16.h>
#include <math.h>

// Problem dims (compile-time constants)
#define BATCH   2
#define SEQ     1024
#define DMODEL  768
#define DINNER  1536
#define DSTATE  16
#define DTRANK  48
#define NTOK    (BATCH*SEQ)          // 2048
#define XPROJ_N (DTRANK + 2*DSTATE)  // 80

// chunked scan params
#define LC      64
#define NC      (SEQ/LC)             // 16

typedef unsigned short ushort_t;
typedef __attribute__((ext_vector_type(8))) short bf16x8;
typedef __attribute__((ext_vector_type(4))) float f32x4;

__device__ __forceinline__ ushort_t f2bf(float f) {
    unsigned int u = __float_as_uint(f);
    u += 0x7FFF + ((u >> 16) & 1);       // round-to-nearest-even
    return (ushort_t)(u >> 16);
}

// ---------------- fused fp32 -> bf16 converter (3 segments) ----------------
__global__ __launch_bounds__(256)
void f2b_3(const float* __restrict__ s0, ushort_t* __restrict__ d0, int n0,
           const float* __restrict__ s1, ushort_t* __restrict__ d1, int n1,
           const float* __restrict__ s2, ushort_t* __restrict__ d2, int n2)
{
    const int i = (blockIdx.x * 256 + threadIdx.x) * 4;
    const float* s; ushort_t* d;
    if (i < n0)               { s = s0 + i;            d = d0 + i; }
    else if (i < n0 + n1)     { s = s1 + (i - n0);     d = d1 + (i - n0); }
    else if (i < n0 + n1 + n2){ s = s2 + (i - n0 - n1);d = d2 + (i - n0 - n1); }
    else return;
    const float4 v = *reinterpret_cast<const float4*>(s);
    ushort4 o;
    o.x = f2bf(v.x); o.y = f2bf(v.y); o.z = f2bf(v.z); o.w = f2bf(v.w);
    *reinterpret_cast<ushort4*>(d) = o;
}

// ---------------- bf16 MFMA GEMM (TN / "B^T input"): C[m,n] = sum_k A[m,k]*W[n,k] ----------------
// m93/m97 structure: 128x128 tile, BK=32, 4 waves of 64x64 (4x4 16x16x32 frags),
// global_load_lds width-16 staging, linear LDS, 2-barrier K-loop.
#define GLOAD_LDS16(gp, lp) \
    __builtin_amdgcn_global_load_lds((const __attribute__((address_space(1))) void*)(gp), \
                                     (__attribute__((address_space(3))) void*)(lp), 16, 0, 0)

__global__ __launch_bounds__(256)
void gemm_mfma_bt(const ushort_t* __restrict__ A, const ushort_t* __restrict__ W,
                  float* __restrict__ C, int M, int N, int K)
{
    __shared__ ushort_t As[128 * 32];
    __shared__ ushort_t Bs[128 * 32];

    const int tid  = threadIdx.x;
    const int w    = tid >> 6;
    const int lane = tid & 63;
    const int m0 = blockIdx.y * 128;
    const int n0 = blockIdx.x * 128;

    const int lrow = lane >> 2;
    const int lcol = (lane & 3) * 8;

    const ushort_t* ga0 = A + (size_t)(m0 + w * 16 + lrow) * K + lcol;
    const ushort_t* ga1 = ga0 + (size_t)64 * K;
    const ushort_t* gb0 = W + (size_t)(n0 + w * 16 + lrow) * K + lcol;
    const ushort_t* gb1 = gb0 + (size_t)64 * K;

    ushort_t* lA0 = As + w * 512;
    ushort_t* lA1 = As + 64 * 32 + w * 512;
    ushort_t* lB0 = Bs + w * 512;
    ushort_t* lB1 = Bs + 64 * 32 + w * 512;

    const int wm = w >> 1, wn = w & 1;
    const int fr = lane & 15;
    const int kg = lane >> 4;

    f32x4 acc[4][4] = {};

    for (int kt = 0; kt < K; kt += 32) {
        __syncthreads();
        GLOAD_LDS16(ga0 + kt, lA0);
        GLOAD_LDS16(ga1 + kt, lA1);
        GLOAD_LDS16(gb0 + kt, lB0);
        GLOAD_LDS16(gb1 + kt, lB1);
        __syncthreads();

        bf16x8 af[4], bfr[4];
        #pragma unroll
        for (int i = 0; i < 4; ++i) {
            af[i]  = *reinterpret_cast<const bf16x8*>(&As[(wm * 64 + i * 16 + fr) * 32 + kg * 8]);
            bfr[i] = *reinterpret_cast<const bf16x8*>(&Bs[(wn * 64 + i * 16 + fr) * 32 + kg * 8]);
        }
        #pragma unroll
        for (int i = 0; i < 4; ++i)
            #pragma unroll
            for (int j = 0; j < 4; ++j)
                acc[i][j] = __builtin_amdgcn_mfma_f32_16x16x32_bf16(af[i], bfr[j], acc[i][j], 0, 0, 0);
    }

    #pragma unroll
    for (int i = 0; i < 4; ++i) {
        const int row_base = m0 + wm * 64 + i * 16 + kg * 4;
        #pragma unroll
        for (int j = 0; j < 4; ++j) {
            const int col = n0 + wn * 64 + j * 16 + fr;
            #pragma unroll
            for (int r = 0; r < 4; ++r)
                C[(size_t)(row_base + r) * N + col] = acc[i][j][r];
        }
    }
}

// ---------------- fp32 fallback SGEMM (small GEMMs: x_proj, dt_proj) ----------------
#define BM 64
#define BN 64
#define BK 16

template<int ACT>  // 0 = none, 1 = softplus(x + bias)
__global__ __launch_bounds__(256)
void gemm_tn(const float* __restrict__ A, const float* __restrict__ W,
             const float* __restrict__ bias, float* __restrict__ C,
             int M, int N, int K, int lda)
{
    __shared__ float As[BK][BM + 4];
    __shared__ float Ws[BK][BN + 4];

    const int t  = threadIdx.x;
    const int tx = t & 15;
    const int ty = t >> 4;
    const int row0 = blockIdx.y * BM;
    const int col0 = blockIdx.x * BN;

    const int m_l = t >> 2;
    const int k_l = (t & 3) * 4;

    float acc[4][4] = {};

    for (int kt = 0; kt < K; kt += BK) {
        float4 av, wv;
        {
            const float* ap = A + (size_t)(row0 + m_l) * lda + kt + k_l;
            av = *reinterpret_cast<const float4*>(ap);
        }
        {
            const int wn = col0 + m_l;
            if (wn < N) {
                const float* wp = W + (size_t)wn * K + kt + k_l;
                wv = *reinterpret_cast<const float4*>(wp);
            } else {
                wv = make_float4(0.f, 0.f, 0.f, 0.f);
            }
        }
        __syncthreads();
        As[k_l + 0][m_l] = av.x; As[k_l + 1][m_l] = av.y;
        As[k_l + 2][m_l] = av.z; As[k_l + 3][m_l] = av.w;
        Ws[k_l + 0][m_l] = wv.x; Ws[k_l + 1][m_l] = wv.y;
        Ws[k_l + 2][m_l] = wv.z; Ws[k_l + 3][m_l] = wv.w;
        __syncthreads();

        #pragma unroll
        for (int k = 0; k < BK; ++k) {
            float4 a4 = *reinterpret_cast<const float4*>(&As[k][ty * 4]);
            float4 w4 = *reinterpret_cast<const float4*>(&Ws[k][tx * 4]);
            float af[4] = {a4.x, a4.y, a4.z, a4.w};
            float wf[4] = {w4.x, w4.y, w4.z, w4.w};
            #pragma unroll
            for (int i = 0; i < 4; ++i)
                #pragma unroll
                for (int j = 0; j < 4; ++j)
                    acc[i][j] += af[i] * wf[j];
        }
    }

    #pragma unroll
    for (int i = 0; i < 4; ++i) {
        const int m = row0 + ty * 4 + i;
        #pragma unroll
        for (int j = 0; j < 4; ++j) {
            const int n = col0 + tx * 4 + j;
            if (n < N) {
                float v = acc[i][j];
                if (ACT == 1) {
                    v += bias[n];
                    v = (v > 20.f) ? v : log1pf(expf(v));
                }
                C[(size_t)m * N + n] = v;
            }
        }
    }
}

// ---------------- depthwise causal conv (k=4) + bias + SiLU ----------------
__global__ __launch_bounds__(256)
void conv_silu(const float* __restrict__ xz, const float* __restrict__ cw,
               const float* __restrict__ cb, float* __restrict__ xc)
{
    int idx = blockIdx.x * 256 + threadIdx.x;
    if (idx >= NTOK * DINNER) return;
    const int c = idx % DINNER;
    const int m = idx / DINNER;
    const int l = m & (SEQ - 1);

    const float w0 = cw[c * 4 + 0], w1 = cw[c * 4 + 1],
                w2 = cw[c * 4 + 2], w3 = cw[c * 4 + 3];
    const float* base = xz + (size_t)m * (2 * DINNER) + c;

    float acc = cb[c] + base[0] * w3;
    if (l >= 1) acc += base[-(2 * DINNER)]     * w2;
    if (l >= 2) acc += base[-2 * (2 * DINNER)] * w1;
    if (l >= 3) acc += base[-3 * (2 * DINNER)] * w0;

    const float sig = 1.f / (1.f + __expf(-acc));
    xc[idx] = acc * sig;
}

// ---------------- chunked selective scan, LDS-staged ----------------
// Phase A: per (b, chunk, d, s): chunk-local scan from 0, operands bulk-staged
// in LDS (coalesced) so the serial h-chain never waits on global latency.
// grid (NC, DINNER/16, BATCH); block 256 = 16 d x 16 s.
__global__ __launch_bounds__(256)
void scan_chunk_state(const float* __restrict__ dt, const float* __restrict__ xc,
                      const float* __restrict__ xdbl, const float* __restrict__ A_log,
                      float* __restrict__ hA, float* __restrict__ aP)
{
    __shared__ float dt_s[LC * 16];
    __shared__ float xc_s[LC * 16];
    __shared__ float B_s [LC * 16];

    const int c = blockIdx.x;
    const int b = blockIdx.z;
    const int d0 = blockIdx.y * 16;
    const int t  = threadIdx.x;

    const size_t row0 = (size_t)b * SEQ + (size_t)c * LC;

    // stage: 4 passes x 256 threads cover 1024 elements per tile
    #pragma unroll
    for (int p = 0; p < (LC * 16) / 256; ++p) {
        const int idx = p * 256 + t;
        const int l = idx >> 4, j = idx & 15;
        const size_t m = row0 + l;
        dt_s[idx] = dt  [m * DINNER  + d0 + j];
        xc_s[idx] = xc  [m * DINNER  + d0 + j];
        B_s [idx] = xdbl[m * XPROJ_N + DTRANK + j];
    }
    __syncthreads();

    const int dl = t >> 4;
    const int s  = t & 15;
    const int d  = d0 + dl;
    const float Aval = -expf(A_log[d * DSTATE + s]);

    float h = 0.f, dts = 0.f;
    #pragma unroll 4
    for (int l = 0; l < LC; ++l) {
        const float dtv = dt_s[l * 16 + dl];
        const float u   = xc_s[l * 16 + dl];
        const float Bv  = B_s [l * 16 + s];
        dts += dtv;
        h = h * __expf(dtv * Aval) + dtv * u * Bv;
    }

    const size_t o = (((size_t)(b * NC + c) * DINNER) + d) * DSTATE + s;
    hA[o] = h;
    aP[o] = __expf(Aval * dts);
}

__global__ __launch_bounds__(256)
void scan_combine(float* __restrict__ hA, const float* __restrict__ aP)
{
    const int idx = blockIdx.x * 256 + threadIdx.x;
    const int b  = idx / (DINNER * DSTATE);
    const int ds = idx % (DINNER * DSTATE);

    float h = 0.f;
    #pragma unroll
    for (int c = 0; c < NC; ++c) {
        const size_t o = ((size_t)(b * NC + c) * DINNER * DSTATE) + ds;
        const float a = hA[o];
        const float p = aP[o];
        hA[o] = h;
        h = a + h * p;
    }
}

// Phase C: re-run chunk from true initial state; operands LDS-staged; emit
// y = (C.h + u*D) * silu(z) as BF16 (feeds out_proj MFMA GEMM).
__global__ __launch_bounds__(256)
void scan_apply(const float* __restrict__ dt, const float* __restrict__ xc,
                const float* __restrict__ xdbl, const float* __restrict__ xz,
                const float* __restrict__ A_log, const float* __restrict__ Dp,
                const float* __restrict__ hInit, ushort_t* __restrict__ y)
{
    __shared__ float dt_s[LC * 16];
    __shared__ float xc_s[LC * 16];
    __shared__ float B_s [LC * 16];
    __shared__ float C_s [LC * 16];
    __shared__ float z_s [LC * 16];

    const int c = blockIdx.x;
    const int b = blockIdx.z;
    const int d0 = blockIdx.y * 16;
    const int t  = threadIdx.x;

    const size_t row0 = (size_t)b * SEQ + (size_t)c * LC;

    #pragma unroll
    for (int p = 0; p < (LC * 16) / 256; ++p) {
        const int idx = p * 256 + t;
        const int l = idx >> 4, j = idx & 15;
        const size_t m = row0 + l;
        dt_s[idx] = dt  [m * DINNER  + d0 + j];
        xc_s[idx] = xc  [m * DINNER  + d0 + j];
        B_s [idx] = xdbl[m * XPROJ_N + DTRANK + j];
        C_s [idx] = xdbl[m * XPROJ_N + DTRANK + DSTATE + j];
        z_s [idx] = xz  [m * (2 * DINNER) + DINNER + d0 + j];
    }
    __syncthreads();

    const int dl = t >> 4;
    const int s  = t & 15;
    const int d  = d0 + dl;

    const float Aval = -expf(A_log[d * DSTATE + s]);
    const float Dd   = Dp[d];

    const size_t o = (((size_t)(b * NC + c) * DINNER) + d) * DSTATE + s;
    float h = hInit[o];

    #pragma unroll 4
    for (int l = 0; l < LC; ++l) {
        const float dtv = dt_s[l * 16 + dl];
        const float u   = xc_s[l * 16 + dl];
        const float Bv  = B_s [l * 16 + s];
        const float Cv  = C_s [l * 16 + s];

        h = h * __expf(dtv * Aval) + dtv * u * Bv;

        // p-chain hangs off h but doesn't feed it -> pipelines across l
        float p = h * Cv;
        p += __shfl_xor(p, 1);
        p += __shfl_xor(p, 2);
        p += __shfl_xor(p, 4);
        p += __shfl_xor(p, 8);

        if (s == 0) {
            const float zv  = z_s[l * 16 + dl];
            const float yv  = p + u * Dd;
            const float sig = 1.f / (1.f + __expf(-zv));
            y[(row0 + l) * DINNER + d] = f2bf(yv * zv * sig);
        }
    }
}

// ---------------- residual + LayerNorm ----------------
__global__ __launch_bounds__(256)
void ln_kernel(const float* __restrict__ mo, const float* __restrict__ x,
               const float* __restrict__ w, const float* __restrict__ bias,
               float* __restrict__ out)
{
    const int m = blockIdx.x;
    const int t = threadIdx.x;
    const float* mrow = mo + (size_t)m * DMODEL;
    const float* xrow = x  + (size_t)m * DMODEL;

    float v[3];
    float sum = 0.f, ss = 0.f;
    #pragma unroll
    for (int i = 0; i < 3; ++i) {
        const int col = t + 256 * i;
        v[i] = mrow[col] + xrow[col];
        sum += v[i];
        ss  += v[i] * v[i];
    }
    #pragma unroll
    for (int o = 1; o < 64; o <<= 1) {
        sum += __shfl_xor(sum, o);
        ss  += __shfl_xor(ss, o);
    }
    __shared__ float red[2][4];
    const int wid = t >> 6;
    if ((t & 63) == 0) { red[0][wid] = sum; red[1][wid] = ss; }
    __syncthreads();
    sum = red[0][0] + red[0][1] + red[0][2] + red[0][3];
    ss  = red[1][0] + red[1][1] + red[1][2] + red[1][3];

    const float mu   = sum * (1.f / DMODEL);
    const float var  = ss * (1.f / DMODEL) - mu * mu;
    const float rstd = rsqrtf(var + 1e-5f);

    #pragma unroll
    for (int i = 0; i < 3; ++i) {
        const int col = t + 256 * i;
        out[(size_t)m * DMODEL + col] = (v[i] - mu) * rstd * w[col] + bias[col];
    }
}

// ---------------- launcher ----------------
extern "C" void kernel_launch(void* const* d_in, const int* in_sizes, int n_in,
                              void* d_out, int out_size, void* d_ws, size_t ws_size,
                              hipStream_t stream)
{
    const float* x          = (const float*)d_in[0];
    const float* in_proj_w  = (const float*)d_in[1];
    const float* conv_w     = (const float*)d_in[2];
    const float* conv_b     = (const float*)d_in[3];
    const float* x_proj_w   = (const float*)d_in[4];
    const float* dt_proj_w  = (const float*)d_in[5];
    const float* dt_proj_b  = (const float*)d_in[6];
    const float* A_log      = (const float*)d_in[7];
    const float* Dp         = (const float*)d_in[8];
    const float* out_proj_w = (const float*)d_in[9];
    const float* ln_w       = (const float*)d_in[10];
    const float* ln_b       = (const float*)d_in[11];
    float* out = (float*)d_out;

    // workspace layout (fp32 region then bf16 region), ~74 MB total
    float* ws   = (float*)d_ws;
    float* xz   = ws;                              // NTOK*3072
    float* xc   = xz   + (size_t)NTOK * 3072;      // NTOK*1536
    float* xdbl = xc   + (size_t)NTOK * 1536;      // NTOK*80
    float* dt   = xdbl + (size_t)NTOK * 80;        // NTOK*1536
    float* mo   = dt   + (size_t)NTOK * 1536;      // NTOK*768
    ushort_t* xb16 = (ushort_t*)(mo + (size_t)NTOK * 768);
    ushort_t* ipw16 = xb16  + (size_t)NTOK * DMODEL;          // 2*DINNER*DMODEL
    ushort_t* opw16 = ipw16 + (size_t)2 * DINNER * DMODEL;    // DMODEL*DINNER
    ushort_t* ybb   = opw16 + (size_t)DMODEL * DINNER;        // NTOK*DINNER

    // scan scratch aliases (regions dead during scan)
    float* aP = mo;             // 786,432 floats <= mo size
    float* hA = (float*)d_out;  // 786,432 floats <= out size

    // 0) bf16 conversions: x, in_proj_w, out_proj_w
    {
        const int n0 = NTOK * DMODEL;
        const int n1 = 2 * DINNER * DMODEL;
        const int n2 = DMODEL * DINNER;
        const int nvec = (n0 + n1 + n2) / 4;
        f2b_3<<<(nvec + 255) / 256, 256, 0, stream>>>(
            x, xb16, n0, in_proj_w, ipw16, n1, out_proj_w, opw16, n2);
    }

    // 1) xz = x @ in_proj_w^T   (bf16 MFMA; 2048 x 3072, K=768)
    gemm_mfma_bt<<<dim3(2 * DINNER / 128, NTOK / 128), 256, 0, stream>>>(
        xb16, ipw16, xz, NTOK, 2 * DINNER, DMODEL);

    // 2) xc = silu(conv(xb) + conv_b)
    conv_silu<<<(NTOK * DINNER) / 256, 256, 0, stream>>>(xz, conv_w, conv_b, xc);

    // 3) x_dbl = xc @ x_proj_w^T  (fp32; 2048 x 80, K=1536)
    gemm_tn<0><<<dim3((XPROJ_N + BN - 1) / BN, NTOK / BM), 256, 0, stream>>>(
        xc, x_proj_w, nullptr, xdbl, NTOK, XPROJ_N, DINNER, DINNER);

    // 4) dt = softplus(dtr @ dt_proj_w^T + dt_proj_b)  (fp32; K=48, lda=80)
    gemm_tn<1><<<dim3(DINNER / BN, NTOK / BM), 256, 0, stream>>>(
        xdbl, dt_proj_w, dt_proj_b, dt, NTOK, DINNER, DTRANK, XPROJ_N);

    // 5) chunked selective scan; phase C writes y as bf16
    scan_chunk_state<<<dim3(NC, DINNER / 16, BATCH), 256, 0, stream>>>(
        dt, xc, xdbl, A_log, hA, aP);
    scan_combine<<<(BATCH * DINNER * DSTATE) / 256, 256, 0, stream>>>(hA, aP);
    scan_apply<<<dim3(NC, DINNER / 16, BATCH), 256, 0, stream>>>(
        dt, xc, xdbl, xz, A_log, Dp, hA, ybb);

    // 6) mo = y @ out_proj_w^T  (bf16 MFMA; 2048 x 768, K=1536)
    gemm_mfma_bt<<<dim3(DMODEL / 128, NTOK / 128), 256, 0, stream>>>(
        ybb, opw16, mo, NTOK, DMODEL, DINNER);

    // 7) out = LayerNorm(mo + x) * ln_w + ln_b
    ln_kernel<<<NTOK, 256, 0, stream>>>(mo, x, ln_w, ln_b, out);
}

// Round 8
// 293.150 us; speedup vs baseline: 4.0893x; 1.1575x over previous
//
#include <hip/hip_runtime.h>
#include <hip/hip_bf16.h>
#include <math.h>

// Problem dims (compile-time constants)
#define BATCH   2
#define SEQ     1024
#define DMODEL  768
#define DINNER  1536
#define DSTATE  16
#define DTRANK  48
#define NTOK    (BATCH*SEQ)          // 2048
#define XPROJ_N (DTRANK + 2*DSTATE)  // 80

// chunked scan params
#define LC      64
#define NC      (SEQ/LC)             // 16

typedef unsigned short ushort_t;
typedef __attribute__((ext_vector_type(8))) short bf16x8;
typedef __attribute__((ext_vector_type(4))) float f32x4;

__device__ __forceinline__ ushort_t f2bf(float f) {
    unsigned int u = __float_as_uint(f);
    u += 0x7FFF + ((u >> 16) & 1);       // round-to-nearest-even
    return (ushort_t)(u >> 16);
}

// ---------------- fused fp32 -> bf16 converter (3 segments) ----------------
__global__ __launch_bounds__(256)
void f2b_3(const float* __restrict__ s0, ushort_t* __restrict__ d0, int n0,
           const float* __restrict__ s1, ushort_t* __restrict__ d1, int n1,
           const float* __restrict__ s2, ushort_t* __restrict__ d2, int n2)
{
    const int i = (blockIdx.x * 256 + threadIdx.x) * 4;
    const float* s; ushort_t* d;
    if (i < n0)               { s = s0 + i;            d = d0 + i; }
    else if (i < n0 + n1)     { s = s1 + (i - n0);     d = d1 + (i - n0); }
    else if (i < n0 + n1 + n2){ s = s2 + (i - n0 - n1);d = d2 + (i - n0 - n1); }
    else return;
    const float4 v = *reinterpret_cast<const float4*>(s);
    ushort4 o;
    o.x = f2bf(v.x); o.y = f2bf(v.y); o.z = f2bf(v.z); o.w = f2bf(v.w);
    *reinterpret_cast<ushort4*>(d) = o;
}

// ---------------- bf16 MFMA GEMM (TN / "B^T input"): C[m,n] = sum_k A[m,k]*W[n,k] ----------------
// m93/m97 structure: 128x128 tile, BK=32, 4 waves of 64x64 (4x4 16x16x32 frags),
// global_load_lds width-16 staging, linear LDS, 2-barrier K-loop.
#define GLOAD_LDS16(gp, lp) \
    __builtin_amdgcn_global_load_lds((const __attribute__((address_space(1))) void*)(gp), \
                                     (__attribute__((address_space(3))) void*)(lp), 16, 0, 0)

__global__ __launch_bounds__(256)
void gemm_mfma_bt(const ushort_t* __restrict__ A, const ushort_t* __restrict__ W,
                  float* __restrict__ C, int M, int N, int K)
{
    __shared__ ushort_t As[128 * 32];
    __shared__ ushort_t Bs[128 * 32];

    const int tid  = threadIdx.x;
    const int w    = tid >> 6;
    const int lane = tid & 63;
    const int m0 = blockIdx.y * 128;
    const int n0 = blockIdx.x * 128;

    const int lrow = lane >> 2;
    const int lcol = (lane & 3) * 8;

    const ushort_t* ga0 = A + (size_t)(m0 + w * 16 + lrow) * K + lcol;
    const ushort_t* ga1 = ga0 + (size_t)64 * K;
    const ushort_t* gb0 = W + (size_t)(n0 + w * 16 + lrow) * K + lcol;
    const ushort_t* gb1 = gb0 + (size_t)64 * K;

    ushort_t* lA0 = As + w * 512;
    ushort_t* lA1 = As + 64 * 32 + w * 512;
    ushort_t* lB0 = Bs + w * 512;
    ushort_t* lB1 = Bs + 64 * 32 + w * 512;

    const int wm = w >> 1, wn = w & 1;
    const int fr = lane & 15;
    const int kg = lane >> 4;

    f32x4 acc[4][4] = {};

    for (int kt = 0; kt < K; kt += 32) {
        __syncthreads();
        GLOAD_LDS16(ga0 + kt, lA0);
        GLOAD_LDS16(ga1 + kt, lA1);
        GLOAD_LDS16(gb0 + kt, lB0);
        GLOAD_LDS16(gb1 + kt, lB1);
        __syncthreads();

        bf16x8 af[4], bfr[4];
        #pragma unroll
        for (int i = 0; i < 4; ++i) {
            af[i]  = *reinterpret_cast<const bf16x8*>(&As[(wm * 64 + i * 16 + fr) * 32 + kg * 8]);
            bfr[i] = *reinterpret_cast<const bf16x8*>(&Bs[(wn * 64 + i * 16 + fr) * 32 + kg * 8]);
        }
        #pragma unroll
        for (int i = 0; i < 4; ++i)
            #pragma unroll
            for (int j = 0; j < 4; ++j)
                acc[i][j] = __builtin_amdgcn_mfma_f32_16x16x32_bf16(af[i], bfr[j], acc[i][j], 0, 0, 0);
    }

    #pragma unroll
    for (int i = 0; i < 4; ++i) {
        const int row_base = m0 + wm * 64 + i * 16 + kg * 4;
        #pragma unroll
        for (int j = 0; j < 4; ++j) {
            const int col = n0 + wn * 64 + j * 16 + fr;
            #pragma unroll
            for (int r = 0; r < 4; ++r)
                C[(size_t)(row_base + r) * N + col] = acc[i][j][r];
        }
    }
}

// ---------------- fp32 SGEMM (dt_proj; ACT=1 softplus) ----------------
#define BM 64
#define BN 64
#define BK 16

template<int ACT>  // 0 = none, 1 = softplus(x + bias)
__global__ __launch_bounds__(256)
void gemm_tn(const float* __restrict__ A, const float* __restrict__ W,
             const float* __restrict__ bias, float* __restrict__ C,
             int M, int N, int K, int lda)
{
    __shared__ float As[BK][BM + 4];
    __shared__ float Ws[BK][BN + 4];

    const int t  = threadIdx.x;
    const int tx = t & 15;
    const int ty = t >> 4;
    const int row0 = blockIdx.y * BM;
    const int col0 = blockIdx.x * BN;

    const int m_l = t >> 2;
    const int k_l = (t & 3) * 4;

    float acc[4][4] = {};

    for (int kt = 0; kt < K; kt += BK) {
        float4 av, wv;
        {
            const float* ap = A + (size_t)(row0 + m_l) * lda + kt + k_l;
            av = *reinterpret_cast<const float4*>(ap);
        }
        {
            const int wn = col0 + m_l;
            if (wn < N) {
                const float* wp = W + (size_t)wn * K + kt + k_l;
                wv = *reinterpret_cast<const float4*>(wp);
            } else {
                wv = make_float4(0.f, 0.f, 0.f, 0.f);
            }
        }
        __syncthreads();
        As[k_l + 0][m_l] = av.x; As[k_l + 1][m_l] = av.y;
        As[k_l + 2][m_l] = av.z; As[k_l + 3][m_l] = av.w;
        Ws[k_l + 0][m_l] = wv.x; Ws[k_l + 1][m_l] = wv.y;
        Ws[k_l + 2][m_l] = wv.z; Ws[k_l + 3][m_l] = wv.w;
        __syncthreads();

        #pragma unroll
        for (int k = 0; k < BK; ++k) {
            float4 a4 = *reinterpret_cast<const float4*>(&As[k][ty * 4]);
            float4 w4 = *reinterpret_cast<const float4*>(&Ws[k][tx * 4]);
            float af[4] = {a4.x, a4.y, a4.z, a4.w};
            float wf[4] = {w4.x, w4.y, w4.z, w4.w};
            #pragma unroll
            for (int i = 0; i < 4; ++i)
                #pragma unroll
                for (int j = 0; j < 4; ++j)
                    acc[i][j] += af[i] * wf[j];
        }
    }

    #pragma unroll
    for (int i = 0; i < 4; ++i) {
        const int m = row0 + ty * 4 + i;
        #pragma unroll
        for (int j = 0; j < 4; ++j) {
            const int n = col0 + tx * 4 + j;
            if (n < N) {
                float v = acc[i][j];
                if (ACT == 1) {
                    v += bias[n];
                    v = (v > 20.f) ? v : log1pf(expf(v));
                }
                C[(size_t)m * N + n] = v;
            }
        }
    }
}

// ---------------- split-K fp32 SGEMM (x_proj: tall-skinny, latency-starved otherwise) ----------------
// grid (N/BN, M/BM, KSPLIT); each block accumulates its K-chunk and atomicAdds into C.
// C must be pre-zeroed (hipMemsetAsync).
__global__ __launch_bounds__(256)
void gemm_tn_splitk(const float* __restrict__ A, const float* __restrict__ W,
                    float* __restrict__ C, int M, int N, int K, int lda, int kchunk)
{
    __shared__ float As[BK][BM + 4];
    __shared__ float Ws[BK][BN + 4];

    const int t  = threadIdx.x;
    const int tx = t & 15;
    const int ty = t >> 4;
    const int row0 = blockIdx.y * BM;
    const int col0 = blockIdx.x * BN;
    const int kbeg = blockIdx.z * kchunk;
    const int kend = kbeg + kchunk;

    const int m_l = t >> 2;
    const int k_l = (t & 3) * 4;

    float acc[4][4] = {};

    for (int kt = kbeg; kt < kend; kt += BK) {
        float4 av, wv;
        {
            const float* ap = A + (size_t)(row0 + m_l) * lda + kt + k_l;
            av = *reinterpret_cast<const float4*>(ap);
        }
        {
            const int wn = col0 + m_l;
            if (wn < N) {
                const float* wp = W + (size_t)wn * K + kt + k_l;
                wv = *reinterpret_cast<const float4*>(wp);
            } else {
                wv = make_float4(0.f, 0.f, 0.f, 0.f);
            }
        }
        __syncthreads();
        As[k_l + 0][m_l] = av.x; As[k_l + 1][m_l] = av.y;
        As[k_l + 2][m_l] = av.z; As[k_l + 3][m_l] = av.w;
        Ws[k_l + 0][m_l] = wv.x; Ws[k_l + 1][m_l] = wv.y;
        Ws[k_l + 2][m_l] = wv.z; Ws[k_l + 3][m_l] = wv.w;
        __syncthreads();

        #pragma unroll
        for (int k = 0; k < BK; ++k) {
            float4 a4 = *reinterpret_cast<const float4*>(&As[k][ty * 4]);
            float4 w4 = *reinterpret_cast<const float4*>(&Ws[k][tx * 4]);
            float af[4] = {a4.x, a4.y, a4.z, a4.w};
            float wf[4] = {w4.x, w4.y, w4.z, w4.w};
            #pragma unroll
            for (int i = 0; i < 4; ++i)
                #pragma unroll
                for (int j = 0; j < 4; ++j)
                    acc[i][j] += af[i] * wf[j];
        }
    }

    #pragma unroll
    for (int i = 0; i < 4; ++i) {
        const int m = row0 + ty * 4 + i;
        #pragma unroll
        for (int j = 0; j < 4; ++j) {
            const int n = col0 + tx * 4 + j;
            if (n < N)
                atomicAdd(&C[(size_t)m * N + n], acc[i][j]);
        }
    }
}

// ---------------- depthwise causal conv (k=4) + bias + SiLU ----------------
__global__ __launch_bounds__(256)
void conv_silu(const float* __restrict__ xz, const float* __restrict__ cw,
               const float* __restrict__ cb, float* __restrict__ xc)
{
    int idx = blockIdx.x * 256 + threadIdx.x;
    if (idx >= NTOK * DINNER) return;
    const int c = idx % DINNER;
    const int m = idx / DINNER;
    const int l = m & (SEQ - 1);

    const float w0 = cw[c * 4 + 0], w1 = cw[c * 4 + 1],
                w2 = cw[c * 4 + 2], w3 = cw[c * 4 + 3];
    const float* base = xz + (size_t)m * (2 * DINNER) + c;

    float acc = cb[c] + base[0] * w3;
    if (l >= 1) acc += base[-(2 * DINNER)]     * w2;
    if (l >= 2) acc += base[-2 * (2 * DINNER)] * w1;
    if (l >= 3) acc += base[-3 * (2 * DINNER)] * w0;

    const float sig = 1.f / (1.f + __expf(-acc));
    xc[idx] = acc * sig;
}

// ---------------- chunked selective scan, LDS-staged ----------------
__global__ __launch_bounds__(256)
void scan_chunk_state(const float* __restrict__ dt, const float* __restrict__ xc,
                      const float* __restrict__ xdbl, const float* __restrict__ A_log,
                      float* __restrict__ hA, float* __restrict__ aP)
{
    __shared__ float dt_s[LC * 16];
    __shared__ float xc_s[LC * 16];
    __shared__ float B_s [LC * 16];

    const int c = blockIdx.x;
    const int b = blockIdx.z;
    const int d0 = blockIdx.y * 16;
    const int t  = threadIdx.x;

    const size_t row0 = (size_t)b * SEQ + (size_t)c * LC;

    #pragma unroll
    for (int p = 0; p < (LC * 16) / 256; ++p) {
        const int idx = p * 256 + t;
        const int l = idx >> 4, j = idx & 15;
        const size_t m = row0 + l;
        dt_s[idx] = dt  [m * DINNER  + d0 + j];
        xc_s[idx] = xc  [m * DINNER  + d0 + j];
        B_s [idx] = xdbl[m * XPROJ_N + DTRANK + j];
    }
    __syncthreads();

    const int dl = t >> 4;
    const int s  = t & 15;
    const int d  = d0 + dl;
    const float Aval = -expf(A_log[d * DSTATE + s]);

    float h = 0.f, dts = 0.f;
    #pragma unroll 4
    for (int l = 0; l < LC; ++l) {
        const float dtv = dt_s[l * 16 + dl];
        const float u   = xc_s[l * 16 + dl];
        const float Bv  = B_s [l * 16 + s];
        dts += dtv;
        h = h * __expf(dtv * Aval) + dtv * u * Bv;
    }

    const size_t o = (((size_t)(b * NC + c) * DINNER) + d) * DSTATE + s;
    hA[o] = h;
    aP[o] = __expf(Aval * dts);
}

__global__ __launch_bounds__(256)
void scan_combine(float* __restrict__ hA, const float* __restrict__ aP)
{
    const int idx = blockIdx.x * 256 + threadIdx.x;
    const int b  = idx / (DINNER * DSTATE);
    const int ds = idx % (DINNER * DSTATE);

    float h = 0.f;
    #pragma unroll
    for (int c = 0; c < NC; ++c) {
        const size_t o = ((size_t)(b * NC + c) * DINNER * DSTATE) + ds;
        const float a = hA[o];
        const float p = aP[o];
        hA[o] = h;
        h = a + h * p;
    }
}

// Phase C: re-run chunk from true initial state; operands LDS-staged; emit
// y = (C.h + u*D) * silu(z) as BF16 (feeds out_proj MFMA GEMM).
__global__ __launch_bounds__(256)
void scan_apply(const float* __restrict__ dt, const float* __restrict__ xc,
                const float* __restrict__ xdbl, const float* __restrict__ xz,
                const float* __restrict__ A_log, const float* __restrict__ Dp,
                const float* __restrict__ hInit, ushort_t* __restrict__ y)
{
    __shared__ float dt_s[LC * 16];
    __shared__ float xc_s[LC * 16];
    __shared__ float B_s [LC * 16];
    __shared__ float C_s [LC * 16];
    __shared__ float z_s [LC * 16];

    const int c = blockIdx.x;
    const int b = blockIdx.z;
    const int d0 = blockIdx.y * 16;
    const int t  = threadIdx.x;

    const size_t row0 = (size_t)b * SEQ + (size_t)c * LC;

    #pragma unroll
    for (int p = 0; p < (LC * 16) / 256; ++p) {
        const int idx = p * 256 + t;
        const int l = idx >> 4, j = idx & 15;
        const size_t m = row0 + l;
        dt_s[idx] = dt  [m * DINNER  + d0 + j];
        xc_s[idx] = xc  [m * DINNER  + d0 + j];
        B_s [idx] = xdbl[m * XPROJ_N + DTRANK + j];
        C_s [idx] = xdbl[m * XPROJ_N + DTRANK + DSTATE + j];
        z_s [idx] = xz  [m * (2 * DINNER) + DINNER + d0 + j];
    }
    __syncthreads();

    const int dl = t >> 4;
    const int s  = t & 15;
    const int d  = d0 + dl;

    const float Aval = -expf(A_log[d * DSTATE + s]);
    const float Dd   = Dp[d];

    const size_t o = (((size_t)(b * NC + c) * DINNER) + d) * DSTATE + s;
    float h = hInit[o];

    #pragma unroll 4
    for (int l = 0; l < LC; ++l) {
        const float dtv = dt_s[l * 16 + dl];
        const float u   = xc_s[l * 16 + dl];
        const float Bv  = B_s [l * 16 + s];
        const float Cv  = C_s [l * 16 + s];

        h = h * __expf(dtv * Aval) + dtv * u * Bv;

        // p-chain hangs off h but doesn't feed it -> pipelines across l
        float p = h * Cv;
        p += __shfl_xor(p, 1);
        p += __shfl_xor(p, 2);
        p += __shfl_xor(p, 4);
        p += __shfl_xor(p, 8);

        if (s == 0) {
            const float zv  = z_s[l * 16 + dl];
            const float yv  = p + u * Dd;
            const float sig = 1.f / (1.f + __expf(-zv));
            y[(row0 + l) * DINNER + d] = f2bf(yv * zv * sig);
        }
    }
}

// ---------------- residual + LayerNorm ----------------
__global__ __launch_bounds__(256)
void ln_kernel(const float* __restrict__ mo, const float* __restrict__ x,
               const float* __restrict__ w, const float* __restrict__ bias,
               float* __restrict__ out)
{
    const int m = blockIdx.x;
    const int t = threadIdx.x;
    const float* mrow = mo + (size_t)m * DMODEL;
    const float* xrow = x  + (size_t)m * DMODEL;

    float v[3];
    float sum = 0.f, ss = 0.f;
    #pragma unroll
    for (int i = 0; i < 3; ++i) {
        const int col = t + 256 * i;
        v[i] = mrow[col] + xrow[col];
        sum += v[i];
        ss  += v[i] * v[i];
    }
    #pragma unroll
    for (int o = 1; o < 64; o <<= 1) {
        sum += __shfl_xor(sum, o);
        ss  += __shfl_xor(ss, o);
    }
    __shared__ float red[2][4];
    const int wid = t >> 6;
    if ((t & 63) == 0) { red[0][wid] = sum; red[1][wid] = ss; }
    __syncthreads();
    sum = red[0][0] + red[0][1] + red[0][2] + red[0][3];
    ss  = red[1][0] + red[1][1] + red[1][2] + red[1][3];

    const float mu   = sum * (1.f / DMODEL);
    const float var  = ss * (1.f / DMODEL) - mu * mu;
    const float rstd = rsqrtf(var + 1e-5f);

    #pragma unroll
    for (int i = 0; i < 3; ++i) {
        const int col = t + 256 * i;
        out[(size_t)m * DMODEL + col] = (v[i] - mu) * rstd * w[col] + bias[col];
    }
}

// ---------------- launcher ----------------
extern "C" void kernel_launch(void* const* d_in, const int* in_sizes, int n_in,
                              void* d_out, int out_size, void* d_ws, size_t ws_size,
                              hipStream_t stream)
{
    const float* x          = (const float*)d_in[0];
    const float* in_proj_w  = (const float*)d_in[1];
    const float* conv_w     = (const float*)d_in[2];
    const float* conv_b     = (const float*)d_in[3];
    const float* x_proj_w   = (const float*)d_in[4];
    const float* dt_proj_w  = (const float*)d_in[5];
    const float* dt_proj_b  = (const float*)d_in[6];
    const float* A_log      = (const float*)d_in[7];
    const float* Dp         = (const float*)d_in[8];
    const float* out_proj_w = (const float*)d_in[9];
    const float* ln_w       = (const float*)d_in[10];
    const float* ln_b       = (const float*)d_in[11];
    float* out = (float*)d_out;

    // workspace layout (fp32 region then bf16 region), ~74 MB total
    float* ws   = (float*)d_ws;
    float* xz   = ws;                              // NTOK*3072
    float* xc   = xz   + (size_t)NTOK * 3072;      // NTOK*1536
    float* xdbl = xc   + (size_t)NTOK * 1536;      // NTOK*80
    float* dt   = xdbl + (size_t)NTOK * 80;        // NTOK*1536
    float* mo   = dt   + (size_t)NTOK * 1536;      // NTOK*768
    ushort_t* xb16 = (ushort_t*)(mo + (size_t)NTOK * 768);
    ushort_t* ipw16 = xb16  + (size_t)NTOK * DMODEL;          // 2*DINNER*DMODEL
    ushort_t* opw16 = ipw16 + (size_t)2 * DINNER * DMODEL;    // DMODEL*DINNER
    ushort_t* ybb   = opw16 + (size_t)DMODEL * DINNER;        // NTOK*DINNER

    // scan scratch aliases (regions dead during scan)
    float* aP = mo;             // 786,432 floats <= mo size
    float* hA = (float*)d_out;  // 786,432 floats <= out size

    // 0) bf16 conversions: x, in_proj_w, out_proj_w
    {
        const int n0 = NTOK * DMODEL;
        const int n1 = 2 * DINNER * DMODEL;
        const int n2 = DMODEL * DINNER;
        const int nvec = (n0 + n1 + n2) / 4;
        f2b_3<<<(nvec + 255) / 256, 256, 0, stream>>>(
            x, xb16, n0, in_proj_w, ipw16, n1, out_proj_w, opw16, n2);
    }

    // 1) xz = x @ in_proj_w^T   (bf16 MFMA; 2048 x 3072, K=768)
    gemm_mfma_bt<<<dim3(2 * DINNER / 128, NTOK / 128), 256, 0, stream>>>(
        xb16, ipw16, xz, NTOK, 2 * DINNER, DMODEL);

    // 2) xc = silu(conv(xb) + conv_b)
    conv_silu<<<(NTOK * DINNER) / 256, 256, 0, stream>>>(xz, conv_w, conv_b, xc);

    // 3) x_dbl = xc @ x_proj_w^T  (fp32 split-K; 2048 x 80, K=1536, KSPLIT=8)
    hipMemsetAsync(xdbl, 0, (size_t)NTOK * XPROJ_N * sizeof(float), stream);
    gemm_tn_splitk<<<dim3((XPROJ_N + BN - 1) / BN, NTOK / BM, 8), 256, 0, stream>>>(
        xc, x_proj_w, xdbl, NTOK, XPROJ_N, DINNER, DINNER, DINNER / 8);

    // 4) dt = softplus(dtr @ dt_proj_w^T + dt_proj_b)  (fp32; K=48, lda=80)
    gemm_tn<1><<<dim3(DINNER / BN, NTOK / BM), 256, 0, stream>>>(
        xdbl, dt_proj_w, dt_proj_b, dt, NTOK, DINNER, DTRANK, XPROJ_N);

    // 5) chunked selective scan; phase C writes y as bf16
    scan_chunk_state<<<dim3(NC, DINNER / 16, BATCH), 256, 0, stream>>>(
        dt, xc, xdbl, A_log, hA, aP);
    scan_combine<<<(BATCH * DINNER * DSTATE) / 256, 256, 0, stream>>>(hA, aP);
    scan_apply<<<dim3(NC, DINNER / 16, BATCH), 256, 0, stream>>>(
        dt, xc, xdbl, xz, A_log, Dp, hA, ybb);

    // 6) mo = y @ out_proj_w^T  (bf16 MFMA; 2048 x 768, K=1536)
    gemm_mfma_bt<<<dim3(DMODEL / 128, NTOK / 128), 256, 0, stream>>>(
        ybb, opw16, mo, NTOK, DMODEL, DINNER);

    // 7) out = LayerNorm(mo + x) * ln_w + ln_b
    ln_kernel<<<NTOK, 256, 0, stream>>>(mo, x, ln_w, ln_b, out);
}

// Round 9
// 274.570 us; speedup vs baseline: 4.3660x; 1.0677x over previous
//
#include <hip/hip_runtime.h>
#include <hip/hip_bf16.h>
#include <math.h>

// Problem dims (compile-time constants)
#define BATCH   2
#define SEQ     1024
#define DMODEL  768
#define DINNER  1536
#define DSTATE  16
#define DTRANK  48
#define NTOK    (BATCH*SEQ)          // 2048
#define XPROJ_N (DTRANK + 2*DSTATE)  // 80

// chunked scan params (LC=32 -> NC=32 for TLP with per-thread-16-state layout)
#define LC      32
#define NC      (SEQ/LC)             // 32

typedef unsigned short ushort_t;
typedef __attribute__((ext_vector_type(8))) short bf16x8;
typedef __attribute__((ext_vector_type(4))) float f32x4;

__device__ __forceinline__ ushort_t f2bf(float f) {
    unsigned int u = __float_as_uint(f);
    u += 0x7FFF + ((u >> 16) & 1);       // round-to-nearest-even
    return (ushort_t)(u >> 16);
}

// ---------------- fused fp32 -> bf16 converter (3 segments) ----------------
__global__ __launch_bounds__(256)
void f2b_3(const float* __restrict__ s0, ushort_t* __restrict__ d0, int n0,
           const float* __restrict__ s1, ushort_t* __restrict__ d1, int n1,
           const float* __restrict__ s2, ushort_t* __restrict__ d2, int n2)
{
    const int i = (blockIdx.x * 256 + threadIdx.x) * 4;
    const float* s; ushort_t* d;
    if (i < n0)               { s = s0 + i;            d = d0 + i; }
    else if (i < n0 + n1)     { s = s1 + (i - n0);     d = d1 + (i - n0); }
    else if (i < n0 + n1 + n2){ s = s2 + (i - n0 - n1);d = d2 + (i - n0 - n1); }
    else return;
    const float4 v = *reinterpret_cast<const float4*>(s);
    ushort4 o;
    o.x = f2bf(v.x); o.y = f2bf(v.y); o.z = f2bf(v.z); o.w = f2bf(v.w);
    *reinterpret_cast<ushort4*>(d) = o;
}

// ---------------- bf16 MFMA GEMM (TN / "B^T input"): C[m,n] = sum_k A[m,k]*W[n,k] ----------------
#define GLOAD_LDS16(gp, lp) \
    __builtin_amdgcn_global_load_lds((const __attribute__((address_space(1))) void*)(gp), \
                                     (__attribute__((address_space(3))) void*)(lp), 16, 0, 0)

__global__ __launch_bounds__(256)
void gemm_mfma_bt(const ushort_t* __restrict__ A, const ushort_t* __restrict__ W,
                  float* __restrict__ C, int M, int N, int K)
{
    __shared__ ushort_t As[128 * 32];
    __shared__ ushort_t Bs[128 * 32];

    const int tid  = threadIdx.x;
    const int w    = tid >> 6;
    const int lane = tid & 63;
    const int m0 = blockIdx.y * 128;
    const int n0 = blockIdx.x * 128;

    const int lrow = lane >> 2;
    const int lcol = (lane & 3) * 8;

    const ushort_t* ga0 = A + (size_t)(m0 + w * 16 + lrow) * K + lcol;
    const ushort_t* ga1 = ga0 + (size_t)64 * K;
    const ushort_t* gb0 = W + (size_t)(n0 + w * 16 + lrow) * K + lcol;
    const ushort_t* gb1 = gb0 + (size_t)64 * K;

    ushort_t* lA0 = As + w * 512;
    ushort_t* lA1 = As + 64 * 32 + w * 512;
    ushort_t* lB0 = Bs + w * 512;
    ushort_t* lB1 = Bs + 64 * 32 + w * 512;

    const int wm = w >> 1, wn = w & 1;
    const int fr = lane & 15;
    const int kg = lane >> 4;

    f32x4 acc[4][4] = {};

    for (int kt = 0; kt < K; kt += 32) {
        __syncthreads();
        GLOAD_LDS16(ga0 + kt, lA0);
        GLOAD_LDS16(ga1 + kt, lA1);
        GLOAD_LDS16(gb0 + kt, lB0);
        GLOAD_LDS16(gb1 + kt, lB1);
        __syncthreads();

        bf16x8 af[4], bfr[4];
        #pragma unroll
        for (int i = 0; i < 4; ++i) {
            af[i]  = *reinterpret_cast<const bf16x8*>(&As[(wm * 64 + i * 16 + fr) * 32 + kg * 8]);
            bfr[i] = *reinterpret_cast<const bf16x8*>(&Bs[(wn * 64 + i * 16 + fr) * 32 + kg * 8]);
        }
        #pragma unroll
        for (int i = 0; i < 4; ++i)
            #pragma unroll
            for (int j = 0; j < 4; ++j)
                acc[i][j] = __builtin_amdgcn_mfma_f32_16x16x32_bf16(af[i], bfr[j], acc[i][j], 0, 0, 0);
    }

    #pragma unroll
    for (int i = 0; i < 4; ++i) {
        const int row_base = m0 + wm * 64 + i * 16 + kg * 4;
        #pragma unroll
        for (int j = 0; j < 4; ++j) {
            const int col = n0 + wn * 64 + j * 16 + fr;
            #pragma unroll
            for (int r = 0; r < 4; ++r)
                C[(size_t)(row_base + r) * N + col] = acc[i][j][r];
        }
    }
}

// ---------------- fp32 SGEMM (dt_proj; ACT=1 softplus) ----------------
#define BM 64
#define BN 64
#define BK 16

template<int ACT>  // 0 = none, 1 = softplus(x + bias)
__global__ __launch_bounds__(256)
void gemm_tn(const float* __restrict__ A, const float* __restrict__ W,
             const float* __restrict__ bias, float* __restrict__ C,
             int M, int N, int K, int lda)
{
    __shared__ float As[BK][BM + 4];
    __shared__ float Ws[BK][BN + 4];

    const int t  = threadIdx.x;
    const int tx = t & 15;
    const int ty = t >> 4;
    const int row0 = blockIdx.y * BM;
    const int col0 = blockIdx.x * BN;

    const int m_l = t >> 2;
    const int k_l = (t & 3) * 4;

    float acc[4][4] = {};

    for (int kt = 0; kt < K; kt += BK) {
        float4 av, wv;
        {
            const float* ap = A + (size_t)(row0 + m_l) * lda + kt + k_l;
            av = *reinterpret_cast<const float4*>(ap);
        }
        {
            const int wn = col0 + m_l;
            if (wn < N) {
                const float* wp = W + (size_t)wn * K + kt + k_l;
                wv = *reinterpret_cast<const float4*>(wp);
            } else {
                wv = make_float4(0.f, 0.f, 0.f, 0.f);
            }
        }
        __syncthreads();
        As[k_l + 0][m_l] = av.x; As[k_l + 1][m_l] = av.y;
        As[k_l + 2][m_l] = av.z; As[k_l + 3][m_l] = av.w;
        Ws[k_l + 0][m_l] = wv.x; Ws[k_l + 1][m_l] = wv.y;
        Ws[k_l + 2][m_l] = wv.z; Ws[k_l + 3][m_l] = wv.w;
        __syncthreads();

        #pragma unroll
        for (int k = 0; k < BK; ++k) {
            float4 a4 = *reinterpret_cast<const float4*>(&As[k][ty * 4]);
            float4 w4 = *reinterpret_cast<const float4*>(&Ws[k][tx * 4]);
            float af[4] = {a4.x, a4.y, a4.z, a4.w};
            float wf[4] = {w4.x, w4.y, w4.z, w4.w};
            #pragma unroll
            for (int i = 0; i < 4; ++i)
                #pragma unroll
                for (int j = 0; j < 4; ++j)
                    acc[i][j] += af[i] * wf[j];
        }
    }

    #pragma unroll
    for (int i = 0; i < 4; ++i) {
        const int m = row0 + ty * 4 + i;
        #pragma unroll
        for (int j = 0; j < 4; ++j) {
            const int n = col0 + tx * 4 + j;
            if (n < N) {
                float v = acc[i][j];
                if (ACT == 1) {
                    v += bias[n];
                    v = (v > 20.f) ? v : log1pf(expf(v));
                }
                C[(size_t)m * N + n] = v;
            }
        }
    }
}

// ---------------- split-K fp32 SGEMM (x_proj) ----------------
__global__ __launch_bounds__(256)
void gemm_tn_splitk(const float* __restrict__ A, const float* __restrict__ W,
                    float* __restrict__ C, int M, int N, int K, int lda, int kchunk)
{
    __shared__ float As[BK][BM + 4];
    __shared__ float Ws[BK][BN + 4];

    const int t  = threadIdx.x;
    const int tx = t & 15;
    const int ty = t >> 4;
    const int row0 = blockIdx.y * BM;
    const int col0 = blockIdx.x * BN;
    const int kbeg = blockIdx.z * kchunk;
    const int kend = kbeg + kchunk;

    const int m_l = t >> 2;
    const int k_l = (t & 3) * 4;

    float acc[4][4] = {};

    for (int kt = kbeg; kt < kend; kt += BK) {
        float4 av, wv;
        {
            const float* ap = A + (size_t)(row0 + m_l) * lda + kt + k_l;
            av = *reinterpret_cast<const float4*>(ap);
        }
        {
            const int wn = col0 + m_l;
            if (wn < N) {
                const float* wp = W + (size_t)wn * K + kt + k_l;
                wv = *reinterpret_cast<const float4*>(wp);
            } else {
                wv = make_float4(0.f, 0.f, 0.f, 0.f);
            }
        }
        __syncthreads();
        As[k_l + 0][m_l] = av.x; As[k_l + 1][m_l] = av.y;
        As[k_l + 2][m_l] = av.z; As[k_l + 3][m_l] = av.w;
        Ws[k_l + 0][m_l] = wv.x; Ws[k_l + 1][m_l] = wv.y;
        Ws[k_l + 2][m_l] = wv.z; Ws[k_l + 3][m_l] = wv.w;
        __syncthreads();

        #pragma unroll
        for (int k = 0; k < BK; ++k) {
            float4 a4 = *reinterpret_cast<const float4*>(&As[k][ty * 4]);
            float4 w4 = *reinterpret_cast<const float4*>(&Ws[k][tx * 4]);
            float af[4] = {a4.x, a4.y, a4.z, a4.w};
            float wf[4] = {w4.x, w4.y, w4.z, w4.w};
            #pragma unroll
            for (int i = 0; i < 4; ++i)
                #pragma unroll
                for (int j = 0; j < 4; ++j)
                    acc[i][j] += af[i] * wf[j];
        }
    }

    #pragma unroll
    for (int i = 0; i < 4; ++i) {
        const int m = row0 + ty * 4 + i;
        #pragma unroll
        for (int j = 0; j < 4; ++j) {
            const int n = col0 + tx * 4 + j;
            if (n < N)
                atomicAdd(&C[(size_t)m * N + n], acc[i][j]);
        }
    }
}

// ---------------- depthwise causal conv (k=4) + bias + SiLU ----------------
__global__ __launch_bounds__(256)
void conv_silu(const float* __restrict__ xz, const float* __restrict__ cw,
               const float* __restrict__ cb, float* __restrict__ xc)
{
    int idx = blockIdx.x * 256 + threadIdx.x;
    if (idx >= NTOK * DINNER) return;
    const int c = idx % DINNER;
    const int m = idx / DINNER;
    const int l = m & (SEQ - 1);

    const float w0 = cw[c * 4 + 0], w1 = cw[c * 4 + 1],
                w2 = cw[c * 4 + 2], w3 = cw[c * 4 + 3];
    const float* base = xz + (size_t)m * (2 * DINNER) + c;

    float acc = cb[c] + base[0] * w3;
    if (l >= 1) acc += base[-(2 * DINNER)]     * w2;
    if (l >= 2) acc += base[-2 * (2 * DINNER)] * w1;
    if (l >= 3) acc += base[-3 * (2 * DINNER)] * w0;

    const float sig = 1.f / (1.f + __expf(-acc));
    xc[idx] = acc * sig;
}

// ---------------- chunked selective scan: thread-owns-d, 16 states in registers ----------------
// Phase A: per (b, chunk, d): scan from h=0; emit hA (chunk partial) and aP (decay).
// grid (NC, DINNER/256, BATCH); block 256 threads = 256 channels.
__global__ __launch_bounds__(256)
void scan_chunk_state(const float* __restrict__ dt, const float* __restrict__ xc,
                      const float* __restrict__ xdbl, const float* __restrict__ A_log,
                      float* __restrict__ hA, float* __restrict__ aP)
{
    __shared__ float B_s[LC * 16];

    const int c  = blockIdx.x;
    const int d0 = blockIdx.y * 256;
    const int b  = blockIdx.z;
    const int t  = threadIdx.x;
    const int d  = d0 + t;

    const size_t row0 = (size_t)b * SEQ + (size_t)c * LC;

    // stage B[l][s] (coalesced-ish, 2 passes)
    #pragma unroll
    for (int p = 0; p < (LC * 16) / 256; ++p) {
        const int idx = p * 256 + t;
        const int l = idx >> 4, j = idx & 15;
        B_s[idx] = xdbl[(row0 + l) * XPROJ_N + DTRANK + j];
    }
    __syncthreads();

    float Aval[16];
    #pragma unroll
    for (int q = 0; q < 4; ++q) {
        const float4 a4 = *reinterpret_cast<const float4*>(&A_log[(size_t)d * DSTATE + q * 4]);
        Aval[q*4+0] = -expf(a4.x); Aval[q*4+1] = -expf(a4.y);
        Aval[q*4+2] = -expf(a4.z); Aval[q*4+3] = -expf(a4.w);
    }

    float h[16];
    #pragma unroll
    for (int s = 0; s < 16; ++s) h[s] = 0.f;
    float dts = 0.f;

    #pragma unroll 2
    for (int l = 0; l < LC; ++l) {
        const size_t m = row0 + l;
        const float dtv = dt[m * DINNER + d];
        const float u   = xc[m * DINNER + d];
        const float du  = dtv * u;
        dts += dtv;
        float Bv[16];
        #pragma unroll
        for (int q = 0; q < 4; ++q) {
            const float4 b4 = *reinterpret_cast<const float4*>(&B_s[l * 16 + q * 4]);
            Bv[q*4+0] = b4.x; Bv[q*4+1] = b4.y; Bv[q*4+2] = b4.z; Bv[q*4+3] = b4.w;
        }
        #pragma unroll
        for (int s = 0; s < 16; ++s)
            h[s] = h[s] * __expf(dtv * Aval[s]) + du * Bv[s];
    }

    const size_t o = (((size_t)(b * NC + c) * DINNER) + d) * DSTATE;
    #pragma unroll
    for (int q = 0; q < 4; ++q) {
        float4 hv = make_float4(h[q*4+0], h[q*4+1], h[q*4+2], h[q*4+3]);
        float4 pv = make_float4(__expf(Aval[q*4+0]*dts), __expf(Aval[q*4+1]*dts),
                                __expf(Aval[q*4+2]*dts), __expf(Aval[q*4+3]*dts));
        *reinterpret_cast<float4*>(&hA[o + q*4]) = hv;
        *reinterpret_cast<float4*>(&aP[o + q*4]) = pv;
    }
}

// Phase B: sequential combine over NC chunk aggregates per (b,d,s).
__global__ __launch_bounds__(256)
void scan_combine(float* __restrict__ hA, const float* __restrict__ aP)
{
    const int idx = blockIdx.x * 256 + threadIdx.x;
    const int b  = idx / (DINNER * DSTATE);
    const int ds = idx % (DINNER * DSTATE);

    float h = 0.f;
    #pragma unroll
    for (int c = 0; c < NC; ++c) {
        const size_t o = ((size_t)(b * NC + c) * DINNER * DSTATE) + ds;
        const float a = hA[o];
        const float p = aP[o];
        hA[o] = h;
        h = a + h * p;
    }
}

// Phase C: re-run chunk from true initial state; emit y = (C.h + u*D)*silu(z) as bf16.
__global__ __launch_bounds__(256)
void scan_apply(const float* __restrict__ dt, const float* __restrict__ xc,
                const float* __restrict__ xdbl, const float* __restrict__ xz,
                const float* __restrict__ A_log, const float* __restrict__ Dp,
                const float* __restrict__ hInit, ushort_t* __restrict__ y)
{
    __shared__ float B_s[LC * 16];
    __shared__ float C_s[LC * 16];

    const int c  = blockIdx.x;
    const int d0 = blockIdx.y * 256;
    const int b  = blockIdx.z;
    const int t  = threadIdx.x;
    const int d  = d0 + t;

    const size_t row0 = (size_t)b * SEQ + (size_t)c * LC;

    #pragma unroll
    for (int p = 0; p < (LC * 16) / 256; ++p) {
        const int idx = p * 256 + t;
        const int l = idx >> 4, j = idx & 15;
        B_s[idx] = xdbl[(row0 + l) * XPROJ_N + DTRANK + j];
        C_s[idx] = xdbl[(row0 + l) * XPROJ_N + DTRANK + DSTATE + j];
    }
    __syncthreads();

    float Aval[16];
    #pragma unroll
    for (int q = 0; q < 4; ++q) {
        const float4 a4 = *reinterpret_cast<const float4*>(&A_log[(size_t)d * DSTATE + q * 4]);
        Aval[q*4+0] = -expf(a4.x); Aval[q*4+1] = -expf(a4.y);
        Aval[q*4+2] = -expf(a4.z); Aval[q*4+3] = -expf(a4.w);
    }
    const float Dd = Dp[d];

    const size_t o = (((size_t)(b * NC + c) * DINNER) + d) * DSTATE;
    float h[16];
    #pragma unroll
    for (int q = 0; q < 4; ++q) {
        const float4 h4 = *reinterpret_cast<const float4*>(&hInit[o + q*4]);
        h[q*4+0] = h4.x; h[q*4+1] = h4.y; h[q*4+2] = h4.z; h[q*4+3] = h4.w;
    }

    #pragma unroll 2
    for (int l = 0; l < LC; ++l) {
        const size_t m = row0 + l;
        const float dtv = dt[m * DINNER + d];
        const float u   = xc[m * DINNER + d];
        const float zv  = xz[m * (2 * DINNER) + DINNER + d];
        const float du  = dtv * u;

        float acc = 0.f;
        #pragma unroll
        for (int q = 0; q < 4; ++q) {
            const float4 b4 = *reinterpret_cast<const float4*>(&B_s[l * 16 + q * 4]);
            const float4 c4 = *reinterpret_cast<const float4*>(&C_s[l * 16 + q * 4]);
            const float bb[4] = {b4.x, b4.y, b4.z, b4.w};
            const float cc[4] = {c4.x, c4.y, c4.z, c4.w};
            #pragma unroll
            for (int r = 0; r < 4; ++r) {
                const int s = q * 4 + r;
                h[s] = h[s] * __expf(dtv * Aval[s]) + du * bb[r];
                acc += h[s] * cc[r];
            }
        }

        const float yv  = acc + u * Dd;
        const float sig = 1.f / (1.f + __expf(-zv));
        y[m * DINNER + d] = f2bf(yv * zv * sig);
    }
}

// ---------------- residual + LayerNorm ----------------
__global__ __launch_bounds__(256)
void ln_kernel(const float* __restrict__ mo, const float* __restrict__ x,
               const float* __restrict__ w, const float* __restrict__ bias,
               float* __restrict__ out)
{
    const int m = blockIdx.x;
    const int t = threadIdx.x;
    const float* mrow = mo + (size_t)m * DMODEL;
    const float* xrow = x  + (size_t)m * DMODEL;

    float v[3];
    float sum = 0.f, ss = 0.f;
    #pragma unroll
    for (int i = 0; i < 3; ++i) {
        const int col = t + 256 * i;
        v[i] = mrow[col] + xrow[col];
        sum += v[i];
        ss  += v[i] * v[i];
    }
    #pragma unroll
    for (int o = 1; o < 64; o <<= 1) {
        sum += __shfl_xor(sum, o);
        ss  += __shfl_xor(ss, o);
    }
    __shared__ float red[2][4];
    const int wid = t >> 6;
    if ((t & 63) == 0) { red[0][wid] = sum; red[1][wid] = ss; }
    __syncthreads();
    sum = red[0][0] + red[0][1] + red[0][2] + red[0][3];
    ss  = red[1][0] + red[1][1] + red[1][2] + red[1][3];

    const float mu   = sum * (1.f / DMODEL);
    const float var  = ss * (1.f / DMODEL) - mu * mu;
    const float rstd = rsqrtf(var + 1e-5f);

    #pragma unroll
    for (int i = 0; i < 3; ++i) {
        const int col = t + 256 * i;
        out[(size_t)m * DMODEL + col] = (v[i] - mu) * rstd * w[col] + bias[col];
    }
}

// ---------------- launcher ----------------
extern "C" void kernel_launch(void* const* d_in, const int* in_sizes, int n_in,
                              void* d_out, int out_size, void* d_ws, size_t ws_size,
                              hipStream_t stream)
{
    const float* x          = (const float*)d_in[0];
    const float* in_proj_w  = (const float*)d_in[1];
    const float* conv_w     = (const float*)d_in[2];
    const float* conv_b     = (const float*)d_in[3];
    const float* x_proj_w   = (const float*)d_in[4];
    const float* dt_proj_w  = (const float*)d_in[5];
    const float* dt_proj_b  = (const float*)d_in[6];
    const float* A_log      = (const float*)d_in[7];
    const float* Dp         = (const float*)d_in[8];
    const float* out_proj_w = (const float*)d_in[9];
    const float* ln_w       = (const float*)d_in[10];
    const float* ln_b       = (const float*)d_in[11];
    float* out = (float*)d_out;

    // workspace layout (fp32 region then bf16 region), ~74 MB total
    float* ws   = (float*)d_ws;
    float* xz   = ws;                              // NTOK*3072
    float* xc   = xz   + (size_t)NTOK * 3072;      // NTOK*1536
    float* xdbl = xc   + (size_t)NTOK * 1536;      // NTOK*80
    float* dt   = xdbl + (size_t)NTOK * 80;        // NTOK*1536
    float* mo   = dt   + (size_t)NTOK * 1536;      // NTOK*768
    ushort_t* xb16 = (ushort_t*)(mo + (size_t)NTOK * 768);
    ushort_t* ipw16 = xb16  + (size_t)NTOK * DMODEL;          // 2*DINNER*DMODEL
    ushort_t* opw16 = ipw16 + (size_t)2 * DINNER * DMODEL;    // DMODEL*DINNER
    ushort_t* ybb   = opw16 + (size_t)DMODEL * DINNER;        // NTOK*DINNER

    // scan scratch aliases (regions dead during scan); B*NC*DINNER*DSTATE = 1,572,864 floats
    float* aP = mo;             // == NTOK*768 floats, exact fit
    float* hA = (float*)d_out;  // == out_size floats, exact fit

    // 0) bf16 conversions: x, in_proj_w, out_proj_w
    {
        const int n0 = NTOK * DMODEL;
        const int n1 = 2 * DINNER * DMODEL;
        const int n2 = DMODEL * DINNER;
        const int nvec = (n0 + n1 + n2) / 4;
        f2b_3<<<(nvec + 255) / 256, 256, 0, stream>>>(
            x, xb16, n0, in_proj_w, ipw16, n1, out_proj_w, opw16, n2);
    }

    // 1) xz = x @ in_proj_w^T   (bf16 MFMA; 2048 x 3072, K=768)
    gemm_mfma_bt<<<dim3(2 * DINNER / 128, NTOK / 128), 256, 0, stream>>>(
        xb16, ipw16, xz, NTOK, 2 * DINNER, DMODEL);

    // 2) xc = silu(conv(xb) + conv_b)
    conv_silu<<<(NTOK * DINNER) / 256, 256, 0, stream>>>(xz, conv_w, conv_b, xc);

    // 3) x_dbl = xc @ x_proj_w^T  (fp32 split-K; 2048 x 80, K=1536, KSPLIT=8)
    hipMemsetAsync(xdbl, 0, (size_t)NTOK * XPROJ_N * sizeof(float), stream);
    gemm_tn_splitk<<<dim3((XPROJ_N + BN - 1) / BN, NTOK / BM, 8), 256, 0, stream>>>(
        xc, x_proj_w, xdbl, NTOK, XPROJ_N, DINNER, DINNER, DINNER / 8);

    // 4) dt = softplus(dtr @ dt_proj_w^T + dt_proj_b)  (fp32; K=48, lda=80)
    gemm_tn<1><<<dim3(DINNER / BN, NTOK / BM), 256, 0, stream>>>(
        xdbl, dt_proj_w, dt_proj_b, dt, NTOK, DINNER, DTRANK, XPROJ_N);

    // 5) chunked selective scan (thread-owns-d); phase C writes y as bf16
    scan_chunk_state<<<dim3(NC, DINNER / 256, BATCH), 256, 0, stream>>>(
        dt, xc, xdbl, A_log, hA, aP);
    scan_combine<<<(BATCH * DINNER * DSTATE) / 256, 256, 0, stream>>>(hA, aP);
    scan_apply<<<dim3(NC, DINNER / 256, BATCH), 256, 0, stream>>>(
        dt, xc, xdbl, xz, A_log, Dp, hA, ybb);

    // 6) mo = y @ out_proj_w^T  (bf16 MFMA; 2048 x 768, K=1536)
    gemm_mfma_bt<<<dim3(DMODEL / 128, NTOK / 128), 256, 0, stream>>>(
        ybb, opw16, mo, NTOK, DMODEL, DINNER);

    // 7) out = LayerNorm(mo + x) * ln_w + ln_b
    ln_kernel<<<NTOK, 256, 0, stream>>>(mo, x, ln_w, ln_b, out);
}

// Round 10
// 257.150 us; speedup vs baseline: 4.6618x; 1.0677x over previous
//
#include <hip/hip_runtime.h>
#include <hip/hip_bf16.h>
#include <math.h>

// Problem dims (compile-time constants)
#define BATCH   2
#define SEQ     1024
#define DMODEL  768
#define DINNER  1536
#define DSTATE  16
#define DTRANK  48
#define NTOK    (BATCH*SEQ)          // 2048
#define XPROJ_N (DTRANK + 2*DSTATE)  // 80

// chunked scan params
#define LC      32
#define NC      (SEQ/LC)             // 32

// split-K factors (fix block starvation: 256 CUs need >=256 blocks)
#define KSPL_IN   2                  // in_proj: 24x16x2 = 768 blocks
#define KSPL_OUT  4                  // out_proj: 6x16x4 = 384 blocks

typedef unsigned short ushort_t;
typedef __attribute__((ext_vector_type(8))) short bf16x8;
typedef __attribute__((ext_vector_type(4))) float f32x4;

__device__ __forceinline__ ushort_t f2bf(float f) {
    unsigned int u = __float_as_uint(f);
    u += 0x7FFF + ((u >> 16) & 1);       // round-to-nearest-even
    return (ushort_t)(u >> 16);
}

// ---------------- fused fp32 -> bf16 converter (3 segments) ----------------
__global__ __launch_bounds__(256)
void f2b_3(const float* __restrict__ s0, ushort_t* __restrict__ d0, int n0,
           const float* __restrict__ s1, ushort_t* __restrict__ d1, int n1,
           const float* __restrict__ s2, ushort_t* __restrict__ d2, int n2)
{
    const int i = (blockIdx.x * 256 + threadIdx.x) * 4;
    const float* s; ushort_t* d;
    if (i < n0)               { s = s0 + i;            d = d0 + i; }
    else if (i < n0 + n1)     { s = s1 + (i - n0);     d = d1 + (i - n0); }
    else if (i < n0 + n1 + n2){ s = s2 + (i - n0 - n1);d = d2 + (i - n0 - n1); }
    else return;
    const float4 v = *reinterpret_cast<const float4*>(s);
    ushort4 o;
    o.x = f2bf(v.x); o.y = f2bf(v.y); o.z = f2bf(v.z); o.w = f2bf(v.w);
    *reinterpret_cast<ushort4*>(d) = o;
}

// ---------------- split-K bf16 MFMA GEMM (TN): Cz[m,n] = sum_{k in slice z} A[m,k]*W[n,k] ----------------
// m97 structure per slice; grid (N/128, M/128, KSPLIT); partial z written to C + z*M*N.
// Consumers sum the KSPLIT partials (no atomics).
#define GLOAD_LDS16(gp, lp) \
    __builtin_amdgcn_global_load_lds((const __attribute__((address_space(1))) void*)(gp), \
                                     (__attribute__((address_space(3))) void*)(lp), 16, 0, 0)

__global__ __launch_bounds__(256)
void gemm_mfma_bt_sk(const ushort_t* __restrict__ A, const ushort_t* __restrict__ W,
                     float* __restrict__ C, int M, int N, int K, int klen)
{
    __shared__ ushort_t As[128 * 32];
    __shared__ ushort_t Bs[128 * 32];

    const int tid  = threadIdx.x;
    const int w    = tid >> 6;
    const int lane = tid & 63;
    const int m0 = blockIdx.y * 128;
    const int n0 = blockIdx.x * 128;
    const int kbeg = blockIdx.z * klen;
    float* Cp = C + (size_t)blockIdx.z * M * N;

    const int lrow = lane >> 2;
    const int lcol = (lane & 3) * 8;

    const ushort_t* ga0 = A + (size_t)(m0 + w * 16 + lrow) * K + kbeg + lcol;
    const ushort_t* ga1 = ga0 + (size_t)64 * K;
    const ushort_t* gb0 = W + (size_t)(n0 + w * 16 + lrow) * K + kbeg + lcol;
    const ushort_t* gb1 = gb0 + (size_t)64 * K;

    ushort_t* lA0 = As + w * 512;
    ushort_t* lA1 = As + 64 * 32 + w * 512;
    ushort_t* lB0 = Bs + w * 512;
    ushort_t* lB1 = Bs + 64 * 32 + w * 512;

    const int wm = w >> 1, wn = w & 1;
    const int fr = lane & 15;
    const int kg = lane >> 4;

    f32x4 acc[4][4] = {};

    for (int kt = 0; kt < klen; kt += 32) {
        __syncthreads();
        GLOAD_LDS16(ga0 + kt, lA0);
        GLOAD_LDS16(ga1 + kt, lA1);
        GLOAD_LDS16(gb0 + kt, lB0);
        GLOAD_LDS16(gb1 + kt, lB1);
        __syncthreads();

        bf16x8 af[4], bfr[4];
        #pragma unroll
        for (int i = 0; i < 4; ++i) {
            af[i]  = *reinterpret_cast<const bf16x8*>(&As[(wm * 64 + i * 16 + fr) * 32 + kg * 8]);
            bfr[i] = *reinterpret_cast<const bf16x8*>(&Bs[(wn * 64 + i * 16 + fr) * 32 + kg * 8]);
        }
        #pragma unroll
        for (int i = 0; i < 4; ++i)
            #pragma unroll
            for (int j = 0; j < 4; ++j)
                acc[i][j] = __builtin_amdgcn_mfma_f32_16x16x32_bf16(af[i], bfr[j], acc[i][j], 0, 0, 0);
    }

    // C/D layout: col = lane&15, row = (lane>>4)*4 + reg
    #pragma unroll
    for (int i = 0; i < 4; ++i) {
        const int row_base = m0 + wm * 64 + i * 16 + kg * 4;
        #pragma unroll
        for (int j = 0; j < 4; ++j) {
            const int col = n0 + wn * 64 + j * 16 + fr;
            #pragma unroll
            for (int r = 0; r < 4; ++r)
                Cp[(size_t)(row_base + r) * N + col] = acc[i][j][r];
        }
    }
}

// ---------------- fp32 SGEMM (dt_proj; ACT=1 softplus) ----------------
#define BM 64
#define BN 64
#define BK 16

template<int ACT>
__global__ __launch_bounds__(256)
void gemm_tn(const float* __restrict__ A, const float* __restrict__ W,
             const float* __restrict__ bias, float* __restrict__ C,
             int M, int N, int K, int lda)
{
    __shared__ float As[BK][BM + 4];
    __shared__ float Ws[BK][BN + 4];

    const int t  = threadIdx.x;
    const int tx = t & 15;
    const int ty = t >> 4;
    const int row0 = blockIdx.y * BM;
    const int col0 = blockIdx.x * BN;

    const int m_l = t >> 2;
    const int k_l = (t & 3) * 4;

    float acc[4][4] = {};

    for (int kt = 0; kt < K; kt += BK) {
        float4 av, wv;
        {
            const float* ap = A + (size_t)(row0 + m_l) * lda + kt + k_l;
            av = *reinterpret_cast<const float4*>(ap);
        }
        {
            const int wn = col0 + m_l;
            if (wn < N) {
                const float* wp = W + (size_t)wn * K + kt + k_l;
                wv = *reinterpret_cast<const float4*>(wp);
            } else {
                wv = make_float4(0.f, 0.f, 0.f, 0.f);
            }
        }
        __syncthreads();
        As[k_l + 0][m_l] = av.x; As[k_l + 1][m_l] = av.y;
        As[k_l + 2][m_l] = av.z; As[k_l + 3][m_l] = av.w;
        Ws[k_l + 0][m_l] = wv.x; Ws[k_l + 1][m_l] = wv.y;
        Ws[k_l + 2][m_l] = wv.z; Ws[k_l + 3][m_l] = wv.w;
        __syncthreads();

        #pragma unroll
        for (int k = 0; k < BK; ++k) {
            float4 a4 = *reinterpret_cast<const float4*>(&As[k][ty * 4]);
            float4 w4 = *reinterpret_cast<const float4*>(&Ws[k][tx * 4]);
            float af[4] = {a4.x, a4.y, a4.z, a4.w};
            float wf[4] = {w4.x, w4.y, w4.z, w4.w};
            #pragma unroll
            for (int i = 0; i < 4; ++i)
                #pragma unroll
                for (int j = 0; j < 4; ++j)
                    acc[i][j] += af[i] * wf[j];
        }
    }

    #pragma unroll
    for (int i = 0; i < 4; ++i) {
        const int m = row0 + ty * 4 + i;
        #pragma unroll
        for (int j = 0; j < 4; ++j) {
            const int n = col0 + tx * 4 + j;
            if (n < N) {
                float v = acc[i][j];
                if (ACT == 1) {
                    v += bias[n];
                    v = (v > 20.f) ? v : log1pf(expf(v));
                }
                C[(size_t)m * N + n] = v;
            }
        }
    }
}

// ---------------- split-K fp32 SGEMM (x_proj) ----------------
__global__ __launch_bounds__(256)
void gemm_tn_splitk(const float* __restrict__ A, const float* __restrict__ W,
                    float* __restrict__ C, int M, int N, int K, int lda, int kchunk)
{
    __shared__ float As[BK][BM + 4];
    __shared__ float Ws[BK][BN + 4];

    const int t  = threadIdx.x;
    const int tx = t & 15;
    const int ty = t >> 4;
    const int row0 = blockIdx.y * BM;
    const int col0 = blockIdx.x * BN;
    const int kbeg = blockIdx.z * kchunk;
    const int kend = kbeg + kchunk;

    const int m_l = t >> 2;
    const int k_l = (t & 3) * 4;

    float acc[4][4] = {};

    for (int kt = kbeg; kt < kend; kt += BK) {
        float4 av, wv;
        {
            const float* ap = A + (size_t)(row0 + m_l) * lda + kt + k_l;
            av = *reinterpret_cast<const float4*>(ap);
        }
        {
            const int wn = col0 + m_l;
            if (wn < N) {
                const float* wp = W + (size_t)wn * K + kt + k_l;
                wv = *reinterpret_cast<const float4*>(wp);
            } else {
                wv = make_float4(0.f, 0.f, 0.f, 0.f);
            }
        }
        __syncthreads();
        As[k_l + 0][m_l] = av.x; As[k_l + 1][m_l] = av.y;
        As[k_l + 2][m_l] = av.z; As[k_l + 3][m_l] = av.w;
        Ws[k_l + 0][m_l] = wv.x; Ws[k_l + 1][m_l] = wv.y;
        Ws[k_l + 2][m_l] = wv.z; Ws[k_l + 3][m_l] = wv.w;
        __syncthreads();

        #pragma unroll
        for (int k = 0; k < BK; ++k) {
            float4 a4 = *reinterpret_cast<const float4*>(&As[k][ty * 4]);
            float4 w4 = *reinterpret_cast<const float4*>(&Ws[k][tx * 4]);
            float af[4] = {a4.x, a4.y, a4.z, a4.w};
            float wf[4] = {w4.x, w4.y, w4.z, w4.w};
            #pragma unroll
            for (int i = 0; i < 4; ++i)
                #pragma unroll
                for (int j = 0; j < 4; ++j)
                    acc[i][j] += af[i] * wf[j];
        }
    }

    #pragma unroll
    for (int i = 0; i < 4; ++i) {
        const int m = row0 + ty * 4 + i;
        #pragma unroll
        for (int j = 0; j < 4; ++j) {
            const int n = col0 + tx * 4 + j;
            if (n < N)
                atomicAdd(&C[(size_t)m * N + n], acc[i][j]);
        }
    }
}

// ---------------- depthwise causal conv (k=4) + bias + SiLU; input = sum of 2 xz partials ----------------
__global__ __launch_bounds__(256)
void conv_silu(const float* __restrict__ xzA, const float* __restrict__ xzB,
               const float* __restrict__ cw, const float* __restrict__ cb,
               float* __restrict__ xc)
{
    int idx = blockIdx.x * 256 + threadIdx.x;
    if (idx >= NTOK * DINNER) return;
    const int c = idx % DINNER;
    const int m = idx / DINNER;
    const int l = m & (SEQ - 1);

    const float w0 = cw[c * 4 + 0], w1 = cw[c * 4 + 1],
                w2 = cw[c * 4 + 2], w3 = cw[c * 4 + 3];
    const float* a = xzA + (size_t)m * (2 * DINNER) + c;
    const float* b = xzB + (size_t)m * (2 * DINNER) + c;
    const int R = 2 * DINNER;

    float acc = cb[c] + (a[0] + b[0]) * w3;
    if (l >= 1) acc += (a[-R]     + b[-R])     * w2;
    if (l >= 2) acc += (a[-2 * R] + b[-2 * R]) * w1;
    if (l >= 3) acc += (a[-3 * R] + b[-3 * R]) * w0;

    const float sig = 1.f / (1.f + __expf(-acc));
    xc[idx] = acc * sig;
}

// ---------------- chunked selective scan: thread-owns-d, 16 states in registers ----------------
__global__ __launch_bounds__(256)
void scan_chunk_state(const float* __restrict__ dt, const float* __restrict__ xc,
                      const float* __restrict__ xdbl, const float* __restrict__ A_log,
                      float* __restrict__ hA, float* __restrict__ aP)
{
    __shared__ float B_s[LC * 16];

    const int c  = blockIdx.x;
    const int d0 = blockIdx.y * 256;
    const int b  = blockIdx.z;
    const int t  = threadIdx.x;
    const int d  = d0 + t;

    const size_t row0 = (size_t)b * SEQ + (size_t)c * LC;

    #pragma unroll
    for (int p = 0; p < (LC * 16) / 256; ++p) {
        const int idx = p * 256 + t;
        const int l = idx >> 4, j = idx & 15;
        B_s[idx] = xdbl[(row0 + l) * XPROJ_N + DTRANK + j];
    }
    __syncthreads();

    float Aval[16];
    #pragma unroll
    for (int q = 0; q < 4; ++q) {
        const float4 a4 = *reinterpret_cast<const float4*>(&A_log[(size_t)d * DSTATE + q * 4]);
        Aval[q*4+0] = -expf(a4.x); Aval[q*4+1] = -expf(a4.y);
        Aval[q*4+2] = -expf(a4.z); Aval[q*4+3] = -expf(a4.w);
    }

    float h[16];
    #pragma unroll
    for (int s = 0; s < 16; ++s) h[s] = 0.f;
    float dts = 0.f;

    #pragma unroll 2
    for (int l = 0; l < LC; ++l) {
        const size_t m = row0 + l;
        const float dtv = dt[m * DINNER + d];
        const float u   = xc[m * DINNER + d];
        const float du  = dtv * u;
        dts += dtv;
        float Bv[16];
        #pragma unroll
        for (int q = 0; q < 4; ++q) {
            const float4 b4 = *reinterpret_cast<const float4*>(&B_s[l * 16 + q * 4]);
            Bv[q*4+0] = b4.x; Bv[q*4+1] = b4.y; Bv[q*4+2] = b4.z; Bv[q*4+3] = b4.w;
        }
        #pragma unroll
        for (int s = 0; s < 16; ++s)
            h[s] = h[s] * __expf(dtv * Aval[s]) + du * Bv[s];
    }

    const size_t o = (((size_t)(b * NC + c) * DINNER) + d) * DSTATE;
    #pragma unroll
    for (int q = 0; q < 4; ++q) {
        float4 hv = make_float4(h[q*4+0], h[q*4+1], h[q*4+2], h[q*4+3]);
        float4 pv = make_float4(__expf(Aval[q*4+0]*dts), __expf(Aval[q*4+1]*dts),
                                __expf(Aval[q*4+2]*dts), __expf(Aval[q*4+3]*dts));
        *reinterpret_cast<float4*>(&hA[o + q*4]) = hv;
        *reinterpret_cast<float4*>(&aP[o + q*4]) = pv;
    }
}

__global__ __launch_bounds__(256)
void scan_combine(float* __restrict__ hA, const float* __restrict__ aP)
{
    const int idx = blockIdx.x * 256 + threadIdx.x;
    const int b  = idx / (DINNER * DSTATE);
    const int ds = idx % (DINNER * DSTATE);

    float h = 0.f;
    #pragma unroll
    for (int c = 0; c < NC; ++c) {
        const size_t o = ((size_t)(b * NC + c) * DINNER * DSTATE) + ds;
        const float a = hA[o];
        const float p = aP[o];
        hA[o] = h;
        h = a + h * p;
    }
}

// Phase C: z comes from 2 in_proj partials; emit y as bf16.
__global__ __launch_bounds__(256)
void scan_apply(const float* __restrict__ dt, const float* __restrict__ xc,
                const float* __restrict__ xdbl,
                const float* __restrict__ xzA, const float* __restrict__ xzB,
                const float* __restrict__ A_log, const float* __restrict__ Dp,
                const float* __restrict__ hInit, ushort_t* __restrict__ y)
{
    __shared__ float B_s[LC * 16];
    __shared__ float C_s[LC * 16];

    const int c  = blockIdx.x;
    const int d0 = blockIdx.y * 256;
    const int b  = blockIdx.z;
    const int t  = threadIdx.x;
    const int d  = d0 + t;

    const size_t row0 = (size_t)b * SEQ + (size_t)c * LC;

    #pragma unroll
    for (int p = 0; p < (LC * 16) / 256; ++p) {
        const int idx = p * 256 + t;
        const int l = idx >> 4, j = idx & 15;
        B_s[idx] = xdbl[(row0 + l) * XPROJ_N + DTRANK + j];
        C_s[idx] = xdbl[(row0 + l) * XPROJ_N + DTRANK + DSTATE + j];
    }
    __syncthreads();

    float Aval[16];
    #pragma unroll
    for (int q = 0; q < 4; ++q) {
        const float4 a4 = *reinterpret_cast<const float4*>(&A_log[(size_t)d * DSTATE + q * 4]);
        Aval[q*4+0] = -expf(a4.x); Aval[q*4+1] = -expf(a4.y);
        Aval[q*4+2] = -expf(a4.z); Aval[q*4+3] = -expf(a4.w);
    }
    const float Dd = Dp[d];

    const size_t o = (((size_t)(b * NC + c) * DINNER) + d) * DSTATE;
    float h[16];
    #pragma unroll
    for (int q = 0; q < 4; ++q) {
        const float4 h4 = *reinterpret_cast<const float4*>(&hInit[o + q*4]);
        h[q*4+0] = h4.x; h[q*4+1] = h4.y; h[q*4+2] = h4.z; h[q*4+3] = h4.w;
    }

    #pragma unroll 2
    for (int l = 0; l < LC; ++l) {
        const size_t m = row0 + l;
        const float dtv = dt[m * DINNER + d];
        const float u   = xc[m * DINNER + d];
        const size_t zi = m * (2 * DINNER) + DINNER + d;
        const float zv  = xzA[zi] + xzB[zi];
        const float du  = dtv * u;

        float acc = 0.f;
        #pragma unroll
        for (int q = 0; q < 4; ++q) {
            const float4 b4 = *reinterpret_cast<const float4*>(&B_s[l * 16 + q * 4]);
            const float4 c4 = *reinterpret_cast<const float4*>(&C_s[l * 16 + q * 4]);
            const float bb[4] = {b4.x, b4.y, b4.z, b4.w};
            const float cc[4] = {c4.x, c4.y, c4.z, c4.w};
            #pragma unroll
            for (int r = 0; r < 4; ++r) {
                const int s = q * 4 + r;
                h[s] = h[s] * __expf(dtv * Aval[s]) + du * bb[r];
                acc += h[s] * cc[r];
            }
        }

        const float yv  = acc + u * Dd;
        const float sig = 1.f / (1.f + __expf(-zv));
        y[m * DINNER + d] = f2bf(yv * zv * sig);
    }
}

// ---------------- residual + LayerNorm; mo = sum of KSPL_OUT partials ----------------
__global__ __launch_bounds__(256)
void ln_kernel(const float* __restrict__ mo, const float* __restrict__ x,
               const float* __restrict__ w, const float* __restrict__ bias,
               float* __restrict__ out)
{
    const int m = blockIdx.x;
    const int t = threadIdx.x;
    const size_t MN = (size_t)NTOK * DMODEL;
    const float* mrow = mo + (size_t)m * DMODEL;
    const float* xrow = x  + (size_t)m * DMODEL;

    float v[3];
    float sum = 0.f, ss = 0.f;
    #pragma unroll
    for (int i = 0; i < 3; ++i) {
        const int col = t + 256 * i;
        float acc = xrow[col];
        #pragma unroll
        for (int p = 0; p < KSPL_OUT; ++p)
            acc += mrow[p * MN + col];
        v[i] = acc;
        sum += acc;
        ss  += acc * acc;
    }
    #pragma unroll
    for (int o = 1; o < 64; o <<= 1) {
        sum += __shfl_xor(sum, o);
        ss  += __shfl_xor(ss, o);
    }
    __shared__ float red[2][4];
    const int wid = t >> 6;
    if ((t & 63) == 0) { red[0][wid] = sum; red[1][wid] = ss; }
    __syncthreads();
    sum = red[0][0] + red[0][1] + red[0][2] + red[0][3];
    ss  = red[1][0] + red[1][1] + red[1][2] + red[1][3];

    const float mu   = sum * (1.f / DMODEL);
    const float var  = ss * (1.f / DMODEL) - mu * mu;
    const float rstd = rsqrtf(var + 1e-5f);

    #pragma unroll
    for (int i = 0; i < 3; ++i) {
        const int col = t + 256 * i;
        out[(size_t)m * DMODEL + col] = (v[i] - mu) * rstd * w[col] + bias[col];
    }
}

// ---------------- launcher ----------------
extern "C" void kernel_launch(void* const* d_in, const int* in_sizes, int n_in,
                              void* d_out, int out_size, void* d_ws, size_t ws_size,
                              hipStream_t stream)
{
    const float* x          = (const float*)d_in[0];
    const float* in_proj_w  = (const float*)d_in[1];
    const float* conv_w     = (const float*)d_in[2];
    const float* conv_b     = (const float*)d_in[3];
    const float* x_proj_w   = (const float*)d_in[4];
    const float* dt_proj_w  = (const float*)d_in[5];
    const float* dt_proj_b  = (const float*)d_in[6];
    const float* A_log      = (const float*)d_in[7];
    const float* Dp         = (const float*)d_in[8];
    const float* out_proj_w = (const float*)d_in[9];
    const float* ln_w       = (const float*)d_in[10];
    const float* ln_b       = (const float*)d_in[11];
    float* out = (float*)d_out;

    // workspace layout (~115 MB; ws is ~268 MB per measured fill)
    float* ws   = (float*)d_ws;
    float* xz   = ws;                                      // 2 partials x NTOK*3072
    float* xc   = xz   + (size_t)KSPL_IN * NTOK * 3072;    // NTOK*1536
    float* xdbl = xc   + (size_t)NTOK * 1536;              // NTOK*80
    float* dt   = xdbl + (size_t)NTOK * 80;                // NTOK*1536
    float* mo   = dt   + (size_t)NTOK * 1536;              // KSPL_OUT x NTOK*768
    ushort_t* xb16 = (ushort_t*)(mo + (size_t)KSPL_OUT * NTOK * 768);
    ushort_t* ipw16 = xb16  + (size_t)NTOK * DMODEL;           // 2*DINNER*DMODEL
    ushort_t* opw16 = ipw16 + (size_t)2 * DINNER * DMODEL;     // DMODEL*DINNER
    ushort_t* ybb   = opw16 + (size_t)DMODEL * DINNER;         // NTOK*DINNER

    float* xzA = xz;
    float* xzB = xz + (size_t)NTOK * 3072;

    // scan scratch aliases (dead during scan): aP -> mo partial 0; hA -> d_out
    float* aP = mo;             // 1,572,864 floats == NTOK*768, exact fit
    float* hA = (float*)d_out;  // == out_size, exact fit

    // 0) bf16 conversions: x, in_proj_w, out_proj_w
    {
        const int n0 = NTOK * DMODEL;
        const int n1 = 2 * DINNER * DMODEL;
        const int n2 = DMODEL * DINNER;
        const int nvec = (n0 + n1 + n2) / 4;
        f2b_3<<<(nvec + 255) / 256, 256, 0, stream>>>(
            x, xb16, n0, in_proj_w, ipw16, n1, out_proj_w, opw16, n2);
    }

    // 1) xz = x @ in_proj_w^T  (bf16 MFMA split-K=2; 2048 x 3072, K=768 -> 768 blocks)
    gemm_mfma_bt_sk<<<dim3(2 * DINNER / 128, NTOK / 128, KSPL_IN), 256, 0, stream>>>(
        xb16, ipw16, xz, NTOK, 2 * DINNER, DMODEL, DMODEL / KSPL_IN);

    // 2) xc = silu(conv(xbA+xbB) + conv_b)
    conv_silu<<<(NTOK * DINNER) / 256, 256, 0, stream>>>(xzA, xzB, conv_w, conv_b, xc);

    // 3) x_dbl = xc @ x_proj_w^T  (fp32 split-K=8)
    hipMemsetAsync(xdbl, 0, (size_t)NTOK * XPROJ_N * sizeof(float), stream);
    gemm_tn_splitk<<<dim3((XPROJ_N + BN - 1) / BN, NTOK / BM, 8), 256, 0, stream>>>(
        xc, x_proj_w, xdbl, NTOK, XPROJ_N, DINNER, DINNER, DINNER / 8);

    // 4) dt = softplus(dtr @ dt_proj_w^T + dt_proj_b)
    gemm_tn<1><<<dim3(DINNER / BN, NTOK / BM), 256, 0, stream>>>(
        xdbl, dt_proj_w, dt_proj_b, dt, NTOK, DINNER, DTRANK, XPROJ_N);

    // 5) chunked selective scan (thread-owns-d); phase C writes y as bf16
    scan_chunk_state<<<dim3(NC, DINNER / 256, BATCH), 256, 0, stream>>>(
        dt, xc, xdbl, A_log, hA, aP);
    scan_combine<<<(BATCH * DINNER * DSTATE) / 256, 256, 0, stream>>>(hA, aP);
    scan_apply<<<dim3(NC, DINNER / 256, BATCH), 256, 0, stream>>>(
        dt, xc, xdbl, xzA, xzB, A_log, Dp, hA, ybb);

    // 6) mo_z = y @ out_proj_w^T  (bf16 MFMA split-K=4; 2048 x 768, K=1536 -> 384 blocks)
    gemm_mfma_bt_sk<<<dim3(DMODEL / 128, NTOK / 128, KSPL_OUT), 256, 0, stream>>>(
        ybb, opw16, mo, NTOK, DMODEL, DINNER, DINNER / KSPL_OUT);

    // 7) out = LayerNorm(sum mo_z + x) * ln_w + ln_b
    ln_kernel<<<NTOK, 256, 0, stream>>>(mo, x, ln_w, ln_b, out);
}

// Round 12
// 244.184 us; speedup vs baseline: 4.9093x; 1.0531x over previous
//
#include <hip/hip_runtime.h>
#include <hip/hip_bf16.h>
#include <math.h>

// Problem dims (compile-time constants)
#define BATCH   2
#define SEQ     1024
#define DMODEL  768
#define DINNER  1536
#define DSTATE  16
#define DTRANK  48
#define NTOK    (BATCH*SEQ)          // 2048
#define XPROJ_N (DTRANK + 2*DSTATE)  // 80
#define XP_PSZ  ((size_t)NTOK * XPROJ_N)   // one x_proj partial

// chunked scan params
#define LC      32
#define NC      (SEQ/LC)             // 32

// split-K factors
#define KSPL_IN   2                  // in_proj: 24x16x2 = 768 blocks
#define KSPL_OUT  4                  // out_proj: 6x16x4 = 384 blocks
#define KSPL_XP   8                  // x_proj: partial buffers, consumer-side reduce

typedef unsigned short ushort_t;
typedef __attribute__((ext_vector_type(8))) short bf16x8;
typedef __attribute__((ext_vector_type(4))) float f32x4;

__device__ __forceinline__ ushort_t f2bf(float f) {
    unsigned int u = __float_as_uint(f);
    u += 0x7FFF + ((u >> 16) & 1);       // round-to-nearest-even
    return (ushort_t)(u >> 16);
}

// ---------------- fused fp32 -> bf16 converter (3 segments) ----------------
__global__ __launch_bounds__(256)
void f2b_3(const float* __restrict__ s0, ushort_t* __restrict__ d0, int n0,
           const float* __restrict__ s1, ushort_t* __restrict__ d1, int n1,
           const float* __restrict__ s2, ushort_t* __restrict__ d2, int n2)
{
    const int i = (blockIdx.x * 256 + threadIdx.x) * 4;
    const float* s; ushort_t* d;
    if (i < n0)               { s = s0 + i;            d = d0 + i; }
    else if (i < n0 + n1)     { s = s1 + (i - n0);     d = d1 + (i - n0); }
    else if (i < n0 + n1 + n2){ s = s2 + (i - n0 - n1);d = d2 + (i - n0 - n1); }
    else return;
    const float4 v = *reinterpret_cast<const float4*>(s);
    ushort4 o;
    o.x = f2bf(v.x); o.y = f2bf(v.y); o.z = f2bf(v.z); o.w = f2bf(v.w);
    *reinterpret_cast<ushort4*>(d) = o;
}

// ---------------- split-K bf16 MFMA GEMM (TN): partial z -> C + z*M*N ----------------
#define GLOAD_LDS16(gp, lp) \
    __builtin_amdgcn_global_load_lds((const __attribute__((address_space(1))) void*)(gp), \
                                     (__attribute__((address_space(3))) void*)(lp), 16, 0, 0)

__global__ __launch_bounds__(256)
void gemm_mfma_bt_sk(const ushort_t* __restrict__ A, const ushort_t* __restrict__ W,
                     float* __restrict__ C, int M, int N, int K, int klen)
{
    __shared__ ushort_t As[128 * 32];
    __shared__ ushort_t Bs[128 * 32];

    const int tid  = threadIdx.x;
    const int w    = tid >> 6;
    const int lane = tid & 63;
    const int m0 = blockIdx.y * 128;
    const int n0 = blockIdx.x * 128;
    const int kbeg = blockIdx.z * klen;
    float* Cp = C + (size_t)blockIdx.z * M * N;

    const int lrow = lane >> 2;
    const int lcol = (lane & 3) * 8;

    const ushort_t* ga0 = A + (size_t)(m0 + w * 16 + lrow) * K + kbeg + lcol;
    const ushort_t* ga1 = ga0 + (size_t)64 * K;
    const ushort_t* gb0 = W + (size_t)(n0 + w * 16 + lrow) * K + kbeg + lcol;
    const ushort_t* gb1 = gb0 + (size_t)64 * K;

    ushort_t* lA0 = As + w * 512;
    ushort_t* lA1 = As + 64 * 32 + w * 512;
    ushort_t* lB0 = Bs + w * 512;
    ushort_t* lB1 = Bs + 64 * 32 + w * 512;

    const int wm = w >> 1, wn = w & 1;
    const int fr = lane & 15;
    const int kg = lane >> 4;

    f32x4 acc[4][4] = {};

    for (int kt = 0; kt < klen; kt += 32) {
        __syncthreads();
        GLOAD_LDS16(ga0 + kt, lA0);
        GLOAD_LDS16(ga1 + kt, lA1);
        GLOAD_LDS16(gb0 + kt, lB0);
        GLOAD_LDS16(gb1 + kt, lB1);
        __syncthreads();

        bf16x8 af[4], bfr[4];
        #pragma unroll
        for (int i = 0; i < 4; ++i) {
            af[i]  = *reinterpret_cast<const bf16x8*>(&As[(wm * 64 + i * 16 + fr) * 32 + kg * 8]);
            bfr[i] = *reinterpret_cast<const bf16x8*>(&Bs[(wn * 64 + i * 16 + fr) * 32 + kg * 8]);
        }
        #pragma unroll
        for (int i = 0; i < 4; ++i)
            #pragma unroll
            for (int j = 0; j < 4; ++j)
                acc[i][j] = __builtin_amdgcn_mfma_f32_16x16x32_bf16(af[i], bfr[j], acc[i][j], 0, 0, 0);
    }

    // C/D layout: col = lane&15, row = (lane>>4)*4 + reg
    #pragma unroll
    for (int i = 0; i < 4; ++i) {
        const int row_base = m0 + wm * 64 + i * 16 + kg * 4;
        #pragma unroll
        for (int j = 0; j < 4; ++j) {
            const int col = n0 + wn * 64 + j * 16 + fr;
            #pragma unroll
            for (int r = 0; r < 4; ++r)
                Cp[(size_t)(row_base + r) * N + col] = acc[i][j][r];
        }
    }
}

#define BM 64
#define BN 64
#define BK 16

// ---------------- x_proj split-K fp32 SGEMM -> 8 partial buffers (no atomics) ----------------
__global__ __launch_bounds__(256)
void gemm_tn_xp(const float* __restrict__ A, const float* __restrict__ W,
                float* __restrict__ C)   // C: KSPL_XP partials of (NTOK x 80)
{
    __shared__ float As[BK][BM + 4];
    __shared__ float Ws[BK][BN + 4];

    const int M = NTOK, N = XPROJ_N, K = DINNER, lda = DINNER;
    const int kchunk = DINNER / KSPL_XP;

    const int t  = threadIdx.x;
    const int tx = t & 15;
    const int ty = t >> 4;
    const int row0 = blockIdx.y * BM;
    const int col0 = blockIdx.x * BN;
    const int kbeg = blockIdx.z * kchunk;
    const int kend = kbeg + kchunk;
    float* Cp = C + (size_t)blockIdx.z * XP_PSZ;

    const int m_l = t >> 2;
    const int k_l = (t & 3) * 4;

    float acc[4][4] = {};

    for (int kt = kbeg; kt < kend; kt += BK) {
        float4 av, wv;
        {
            const float* ap = A + (size_t)(row0 + m_l) * lda + kt + k_l;
            av = *reinterpret_cast<const float4*>(ap);
        }
        {
            const int wn = col0 + m_l;
            if (wn < N) {
                const float* wp = W + (size_t)wn * K + kt + k_l;
                wv = *reinterpret_cast<const float4*>(wp);
            } else {
                wv = make_float4(0.f, 0.f, 0.f, 0.f);
            }
        }
        __syncthreads();
        As[k_l + 0][m_l] = av.x; As[k_l + 1][m_l] = av.y;
        As[k_l + 2][m_l] = av.z; As[k_l + 3][m_l] = av.w;
        Ws[k_l + 0][m_l] = wv.x; Ws[k_l + 1][m_l] = wv.y;
        Ws[k_l + 2][m_l] = wv.z; Ws[k_l + 3][m_l] = wv.w;
        __syncthreads();

        #pragma unroll
        for (int k = 0; k < BK; ++k) {
            float4 a4 = *reinterpret_cast<const float4*>(&As[k][ty * 4]);
            float4 w4 = *reinterpret_cast<const float4*>(&Ws[k][tx * 4]);
            float af[4] = {a4.x, a4.y, a4.z, a4.w};
            float wf[4] = {w4.x, w4.y, w4.z, w4.w};
            #pragma unroll
            for (int i = 0; i < 4; ++i)
                #pragma unroll
                for (int j = 0; j < 4; ++j)
                    acc[i][j] += af[i] * wf[j];
        }
    }

    #pragma unroll
    for (int i = 0; i < 4; ++i) {
        const int m = row0 + ty * 4 + i;
        #pragma unroll
        for (int j = 0; j < 4; ++j) {
            const int n = col0 + tx * 4 + j;
            if (n < N)
                Cp[(size_t)m * N + n] = acc[i][j];
        }
    }
}

// ---------------- dt_proj fp32 SGEMM; A = sum of 8 x_proj partials; softplus epilogue ----------------
__global__ __launch_bounds__(256)
void gemm_tn_dt(const float* __restrict__ Ap, const float* __restrict__ W,
                const float* __restrict__ bias, float* __restrict__ C)
{
    __shared__ float As[BK][BM + 4];
    __shared__ float Ws[BK][BN + 4];

    const int N = DINNER, K = DTRANK, lda = XPROJ_N;

    const int t  = threadIdx.x;
    const int tx = t & 15;
    const int ty = t >> 4;
    const int row0 = blockIdx.y * BM;
    const int col0 = blockIdx.x * BN;

    const int m_l = t >> 2;
    const int k_l = (t & 3) * 4;

    float acc[4][4] = {};

    for (int kt = 0; kt < K; kt += BK) {
        float4 av = make_float4(0.f, 0.f, 0.f, 0.f);
        {
            const size_t off = (size_t)(row0 + m_l) * lda + kt + k_l;
            #pragma unroll
            for (int p = 0; p < KSPL_XP; ++p) {
                const float4 v = *reinterpret_cast<const float4*>(Ap + p * XP_PSZ + off);
                av.x += v.x; av.y += v.y; av.z += v.z; av.w += v.w;
            }
        }
        float4 wv;
        {
            const int wn = col0 + m_l;
            const float* wp = W + (size_t)wn * K + kt + k_l;
            wv = *reinterpret_cast<const float4*>(wp);
        }
        __syncthreads();
        As[k_l + 0][m_l] = av.x; As[k_l + 1][m_l] = av.y;
        As[k_l + 2][m_l] = av.z; As[k_l + 3][m_l] = av.w;
        Ws[k_l + 0][m_l] = wv.x; Ws[k_l + 1][m_l] = wv.y;
        Ws[k_l + 2][m_l] = wv.z; Ws[k_l + 3][m_l] = wv.w;
        __syncthreads();

        #pragma unroll
        for (int k = 0; k < BK; ++k) {
            float4 a4 = *reinterpret_cast<const float4*>(&As[k][ty * 4]);
            float4 w4 = *reinterpret_cast<const float4*>(&Ws[k][tx * 4]);
            float af[4] = {a4.x, a4.y, a4.z, a4.w};
            float wf[4] = {w4.x, w4.y, w4.z, w4.w};
            #pragma unroll
            for (int i = 0; i < 4; ++i)
                #pragma unroll
                for (int j = 0; j < 4; ++j)
                    acc[i][j] += af[i] * wf[j];
        }
    }

    #pragma unroll
    for (int i = 0; i < 4; ++i) {
        const int m = row0 + ty * 4 + i;
        #pragma unroll
        for (int j = 0; j < 4; ++j) {
            const int n = col0 + tx * 4 + j;
            float v = acc[i][j] + bias[n];
            v = (v > 20.f) ? v : log1pf(expf(v));
            C[(size_t)m * N + n] = v;
        }
    }
}

// ---------------- depthwise causal conv (k=4) + bias + SiLU; float4, 2 in_proj partials ----------------
__global__ __launch_bounds__(256)
void conv_silu(const float* __restrict__ xzA, const float* __restrict__ xzB,
               const float* __restrict__ cw, const float* __restrict__ cb,
               float* __restrict__ xc)
{
    const int vid = blockIdx.x * 256 + threadIdx.x;        // over NTOK*DINNER/4
    const int c4 = (vid % (DINNER / 4)) * 4;
    const int m  = vid / (DINNER / 4);
    const int l  = m & (SEQ - 1);
    const int R  = 2 * DINNER;

    const float* a = xzA + (size_t)m * R + c4;
    const float* b = xzB + (size_t)m * R + c4;

    // weights: W[j] = cw[(c4+j)*4 .. +3]
    float4 W0 = *reinterpret_cast<const float4*>(cw + (c4 + 0) * 4);
    float4 W1 = *reinterpret_cast<const float4*>(cw + (c4 + 1) * 4);
    float4 W2 = *reinterpret_cast<const float4*>(cw + (c4 + 2) * 4);
    float4 W3 = *reinterpret_cast<const float4*>(cw + (c4 + 3) * 4);
    const float4 bias = *reinterpret_cast<const float4*>(cb + c4);

    float4 s0 = *reinterpret_cast<const float4*>(a);
    {
        const float4 t = *reinterpret_cast<const float4*>(b);
        s0.x += t.x; s0.y += t.y; s0.z += t.z; s0.w += t.w;
    }
    float acc0 = bias.x + s0.x * W0.w;
    float acc1 = bias.y + s0.y * W1.w;
    float acc2 = bias.z + s0.z * W2.w;
    float acc3 = bias.w + s0.w * W3.w;

    if (l >= 1) {
        float4 s = *reinterpret_cast<const float4*>(a - R);
        const float4 t = *reinterpret_cast<const float4*>(b - R);
        s.x += t.x; s.y += t.y; s.z += t.z; s.w += t.w;
        acc0 += s.x * W0.z; acc1 += s.y * W1.z; acc2 += s.z * W2.z; acc3 += s.w * W3.z;
    }
    if (l >= 2) {
        float4 s = *reinterpret_cast<const float4*>(a - 2 * R);
        const float4 t = *reinterpret_cast<const float4*>(b - 2 * R);
        s.x += t.x; s.y += t.y; s.z += t.z; s.w += t.w;
        acc0 += s.x * W0.y; acc1 += s.y * W1.y; acc2 += s.z * W2.y; acc3 += s.w * W3.y;
    }
    if (l >= 3) {
        float4 s = *reinterpret_cast<const float4*>(a - 3 * R);
        const float4 t = *reinterpret_cast<const float4*>(b - 3 * R);
        s.x += t.x; s.y += t.y; s.z += t.z; s.w += t.w;
        acc0 += s.x * W0.x; acc1 += s.y * W1.x; acc2 += s.z * W2.x; acc3 += s.w * W3.x;
    }

    float4 o;
    o.x = acc0 / (1.f + __expf(-acc0));
    o.y = acc1 / (1.f + __expf(-acc1));
    o.z = acc2 / (1.f + __expf(-acc2));
    o.w = acc3 / (1.f + __expf(-acc3));
    *reinterpret_cast<float4*>(xc + (size_t)m * DINNER + c4) = o;
}

// ---------------- chunked selective scan: thread-owns-d, 16 states in registers ----------------
// B/C staged from 8 x_proj partials (summed).
__global__ __launch_bounds__(256)
void scan_chunk_state(const float* __restrict__ dt, const float* __restrict__ xc,
                      const float* __restrict__ xdblP, const float* __restrict__ A_log,
                      float* __restrict__ hA, float* __restrict__ aP)
{
    __shared__ float B_s[LC * 16];

    const int c  = blockIdx.x;
    const int d0 = blockIdx.y * 256;
    const int b  = blockIdx.z;
    const int t  = threadIdx.x;
    const int d  = d0 + t;

    const size_t row0 = (size_t)b * SEQ + (size_t)c * LC;

    #pragma unroll
    for (int p = 0; p < (LC * 16) / 256; ++p) {
        const int idx = p * 256 + t;
        const int l = idx >> 4, j = idx & 15;
        const size_t off = (row0 + l) * XPROJ_N + DTRANK + j;
        float v = 0.f;
        #pragma unroll
        for (int q = 0; q < KSPL_XP; ++q) v += xdblP[q * XP_PSZ + off];
        B_s[idx] = v;
    }
    __syncthreads();

    float Aval[16];
    #pragma unroll
    for (int q = 0; q < 4; ++q) {
        const float4 a4 = *reinterpret_cast<const float4*>(&A_log[(size_t)d * DSTATE + q * 4]);
        Aval[q*4+0] = -expf(a4.x); Aval[q*4+1] = -expf(a4.y);
        Aval[q*4+2] = -expf(a4.z); Aval[q*4+3] = -expf(a4.w);
    }

    float h[16];
    #pragma unroll
    for (int s = 0; s < 16; ++s) h[s] = 0.f;
    float dts = 0.f;

    #pragma unroll 2
    for (int l = 0; l < LC; ++l) {
        const size_t m = row0 + l;
        const float dtv = dt[m * DINNER + d];
        const float u   = xc[m * DINNER + d];
        const float du  = dtv * u;
        dts += dtv;
        float Bv[16];
        #pragma unroll
        for (int q = 0; q < 4; ++q) {
            const float4 b4 = *reinterpret_cast<const float4*>(&B_s[l * 16 + q * 4]);
            Bv[q*4+0] = b4.x; Bv[q*4+1] = b4.y; Bv[q*4+2] = b4.z; Bv[q*4+3] = b4.w;
        }
        #pragma unroll
        for (int s = 0; s < 16; ++s)
            h[s] = h[s] * __expf(dtv * Aval[s]) + du * Bv[s];
    }

    const size_t o = (((size_t)(b * NC + c) * DINNER) + d) * DSTATE;
    #pragma unroll
    for (int q = 0; q < 4; ++q) {
        float4 hv = make_float4(h[q*4+0], h[q*4+1], h[q*4+2], h[q*4+3]);
        float4 pv = make_float4(__expf(Aval[q*4+0]*dts), __expf(Aval[q*4+1]*dts),
                                __expf(Aval[q*4+2]*dts), __expf(Aval[q*4+3]*dts));
        *reinterpret_cast<float4*>(&hA[o + q*4]) = hv;
        *reinterpret_cast<float4*>(&aP[o + q*4]) = pv;
    }
}

// Phase B: prefetch all NC aggregates (independent loads), then run the dependent chain.
__global__ __launch_bounds__(256)
void scan_combine(float* __restrict__ hA, const float* __restrict__ aP)
{
    const int idx = blockIdx.x * 256 + threadIdx.x;   // over BATCH*DINNER*DSTATE
    const int b  = idx / (DINNER * DSTATE);
    const int ds = idx % (DINNER * DSTATE);
    const size_t stride = (size_t)DINNER * DSTATE;
    const size_t base = (size_t)b * NC * stride + ds;

    float a[NC], p[NC];
    #pragma unroll
    for (int c = 0; c < NC; ++c) {
        a[c] = hA[base + (size_t)c * stride];
        p[c] = aP[base + (size_t)c * stride];
    }
    float h = 0.f;
    #pragma unroll
    for (int c = 0; c < NC; ++c) {
        const float hn = a[c] + h * p[c];
        hA[base + (size_t)c * stride] = h;
        h = hn;
    }
}

// Phase C: z from 2 in_proj partials; B/C from 8 x_proj partials; emit y as bf16.
__global__ __launch_bounds__(256)
void scan_apply(const float* __restrict__ dt, const float* __restrict__ xc,
                const float* __restrict__ xdblP,
                const float* __restrict__ xzA, const float* __restrict__ xzB,
                const float* __restrict__ A_log, const float* __restrict__ Dp,
                const float* __restrict__ hInit, ushort_t* __restrict__ y)
{
    __shared__ float B_s[LC * 16];
    __shared__ float C_s[LC * 16];

    const int c  = blockIdx.x;
    const int d0 = blockIdx.y * 256;
    const int b  = blockIdx.z;
    const int t  = threadIdx.x;
    const int d  = d0 + t;

    const size_t row0 = (size_t)b * SEQ + (size_t)c * LC;

    #pragma unroll
    for (int p = 0; p < (LC * 16) / 256; ++p) {
        const int idx = p * 256 + t;
        const int l = idx >> 4, j = idx & 15;
        const size_t offB = (row0 + l) * XPROJ_N + DTRANK + j;
        float vb = 0.f, vc = 0.f;
        #pragma unroll
        for (int q = 0; q < KSPL_XP; ++q) {
            vb += xdblP[q * XP_PSZ + offB];
            vc += xdblP[q * XP_PSZ + offB + DSTATE];
        }
        B_s[idx] = vb;
        C_s[idx] = vc;
    }
    __syncthreads();

    float Aval[16];
    #pragma unroll
    for (int q = 0; q < 4; ++q) {
        const float4 a4 = *reinterpret_cast<const float4*>(&A_log[(size_t)d * DSTATE + q * 4]);
        Aval[q*4+0] = -expf(a4.x); Aval[q*4+1] = -expf(a4.y);
        Aval[q*4+2] = -expf(a4.z); Aval[q*4+3] = -expf(a4.w);
    }
    const float Dd = Dp[d];

    const size_t o = (((size_t)(b * NC + c) * DINNER) + d) * DSTATE;
    float h[16];
    #pragma unroll
    for (int q = 0; q < 4; ++q) {
        const float4 h4 = *reinterpret_cast<const float4*>(&hInit[o + q*4]);
        h[q*4+0] = h4.x; h[q*4+1] = h4.y; h[q*4+2] = h4.z; h[q*4+3] = h4.w;
    }

    #pragma unroll 2
    for (int l = 0; l < LC; ++l) {
        const size_t m = row0 + l;
        const float dtv = dt[m * DINNER + d];
        const float u   = xc[m * DINNER + d];
        const size_t zi = m * (2 * DINNER) + DINNER + d;
        const float zv  = xzA[zi] + xzB[zi];
        const float du  = dtv * u;

        float acc = 0.f;
        #pragma unroll
        for (int q = 0; q < 4; ++q) {
            const float4 b4 = *reinterpret_cast<const float4*>(&B_s[l * 16 + q * 4]);
            const float4 c4 = *reinterpret_cast<const float4*>(&C_s[l * 16 + q * 4]);
            const float bb[4] = {b4.x, b4.y, b4.z, b4.w};
            const float cc[4] = {c4.x, c4.y, c4.z, c4.w};
            #pragma unroll
            for (int r = 0; r < 4; ++r) {
                const int s = q * 4 + r;
                h[s] = h[s] * __expf(dtv * Aval[s]) + du * bb[r];
                acc += h[s] * cc[r];
            }
        }

        const float yv  = acc + u * Dd;
        const float sig = 1.f / (1.f + __expf(-zv));
        y[m * DINNER + d] = f2bf(yv * zv * sig);
    }
}

// ---------------- residual + LayerNorm; mo = sum of KSPL_OUT partials ----------------
__global__ __launch_bounds__(256)
void ln_kernel(const float* __restrict__ mo, const float* __restrict__ x,
               const float* __restrict__ w, const float* __restrict__ bias,
               float* __restrict__ out)
{
    const int m = blockIdx.x;
    const int t = threadIdx.x;
    const size_t MN = (size_t)NTOK * DMODEL;
    const float* mrow = mo + (size_t)m * DMODEL;
    const float* xrow = x  + (size_t)m * DMODEL;

    float v[3];
    float sum = 0.f, ss = 0.f;
    #pragma unroll
    for (int i = 0; i < 3; ++i) {
        const int col = t + 256 * i;
        float acc = xrow[col];
        #pragma unroll
        for (int p = 0; p < KSPL_OUT; ++p)
            acc += mrow[p * MN + col];
        v[i] = acc;
        sum += acc;
        ss  += acc * acc;
    }
    #pragma unroll
    for (int o = 1; o < 64; o <<= 1) {
        sum += __shfl_xor(sum, o);
        ss  += __shfl_xor(ss, o);
    }
    __shared__ float red[2][4];
    const int wid = t >> 6;
    if ((t & 63) == 0) { red[0][wid] = sum; red[1][wid] = ss; }
    __syncthreads();
    sum = red[0][0] + red[0][1] + red[0][2] + red[0][3];
    ss  = red[1][0] + red[1][1] + red[1][2] + red[1][3];

    const float mu   = sum * (1.f / DMODEL);
    const float var  = ss * (1.f / DMODEL) - mu * mu;
    const float rstd = rsqrtf(var + 1e-5f);

    #pragma unroll
    for (int i = 0; i < 3; ++i) {
        const int col = t + 256 * i;
        out[(size_t)m * DMODEL + col] = (v[i] - mu) * rstd * w[col] + bias[col];
    }
}

// ---------------- launcher ----------------
extern "C" void kernel_launch(void* const* d_in, const int* in_sizes, int n_in,
                              void* d_out, int out_size, void* d_ws, size_t ws_size,
                              hipStream_t stream)
{
    const float* x          = (const float*)d_in[0];
    const float* in_proj_w  = (const float*)d_in[1];
    const float* conv_w     = (const float*)d_in[2];
    const float* conv_b     = (const float*)d_in[3];
    const float* x_proj_w   = (const float*)d_in[4];
    const float* dt_proj_w  = (const float*)d_in[5];
    const float* dt_proj_b  = (const float*)d_in[6];
    const float* A_log      = (const float*)d_in[7];
    const float* Dp         = (const float*)d_in[8];
    const float* out_proj_w = (const float*)d_in[9];
    const float* ln_w       = (const float*)d_in[10];
    const float* ln_b       = (const float*)d_in[11];
    float* out = (float*)d_out;

    // workspace layout (~122 MB of the ~268 MB ws)
    float* ws   = (float*)d_ws;
    float* xz   = ws;                                      // KSPL_IN x NTOK*3072
    float* xc   = xz   + (size_t)KSPL_IN * NTOK * 3072;    // NTOK*1536
    float* xdbl = xc   + (size_t)NTOK * 1536;              // KSPL_XP x NTOK*80
    float* dt   = xdbl + (size_t)KSPL_XP * XP_PSZ;         // NTOK*1536
    float* mo   = dt   + (size_t)NTOK * 1536;              // KSPL_OUT x NTOK*768
    ushort_t* xb16 = (ushort_t*)(mo + (size_t)KSPL_OUT * NTOK * 768);
    ushort_t* ipw16 = xb16  + (size_t)NTOK * DMODEL;           // 2*DINNER*DMODEL
    ushort_t* opw16 = ipw16 + (size_t)2 * DINNER * DMODEL;     // DMODEL*DINNER
    ushort_t* ybb   = opw16 + (size_t)DMODEL * DINNER;         // NTOK*DINNER

    float* xzA = xz;
    float* xzB = xz + (size_t)NTOK * 3072;

    // scan scratch aliases (dead during scan): aP -> mo partial 0; hA -> d_out
    float* aP = mo;             // 1,572,864 floats == NTOK*768, exact fit
    float* hA = (float*)d_out;  // == out_size, exact fit

    // 0) bf16 conversions: x, in_proj_w, out_proj_w
    {
        const int n0 = NTOK * DMODEL;
        const int n1 = 2 * DINNER * DMODEL;
        const int n2 = DMODEL * DINNER;
        const int nvec = (n0 + n1 + n2) / 4;
        f2b_3<<<(nvec + 255) / 256, 256, 0, stream>>>(
            x, xb16, n0, in_proj_w, ipw16, n1, out_proj_w, opw16, n2);
    }

    // 1) xz = x @ in_proj_w^T  (bf16 MFMA split-K=2 -> 768 blocks)
    gemm_mfma_bt_sk<<<dim3(2 * DINNER / 128, NTOK / 128, KSPL_IN), 256, 0, stream>>>(
        xb16, ipw16, xz, NTOK, 2 * DINNER, DMODEL, DMODEL / KSPL_IN);

    // 2) xc = silu(conv(xbA+xbB) + conv_b)   (float4 vectorized)
    conv_silu<<<(NTOK * DINNER / 4) / 256, 256, 0, stream>>>(xzA, xzB, conv_w, conv_b, xc);

    // 3) x_dbl partials = xc @ x_proj_w^T  (fp32 split-K=8, partial buffers, no atomics)
    gemm_tn_xp<<<dim3((XPROJ_N + BN - 1) / BN, NTOK / BM, KSPL_XP), 256, 0, stream>>>(
        xc, x_proj_w, xdbl);

    // 4) dt = softplus((sum partials)[:, :48] @ dt_proj_w^T + dt_proj_b)
    gemm_tn_dt<<<dim3(DINNER / BN, NTOK / BM), 256, 0, stream>>>(
        xdbl, dt_proj_w, dt_proj_b, dt);

    // 5) chunked selective scan (thread-owns-d); phase C writes y as bf16
    scan_chunk_state<<<dim3(NC, DINNER / 256, BATCH), 256, 0, stream>>>(
        dt, xc, xdbl, A_log, hA, aP);
    scan_combine<<<(BATCH * DINNER * DSTATE) / 256, 256, 0, stream>>>(hA, aP);
    scan_apply<<<dim3(NC, DINNER / 256, BATCH), 256, 0, stream>>>(
        dt, xc, xdbl, xzA, xzB, A_log, Dp, hA, ybb);

    // 6) mo_z = y @ out_proj_w^T  (bf16 MFMA split-K=4 -> 384 blocks)
    gemm_mfma_bt_sk<<<dim3(DMODEL / 128, NTOK / 128, KSPL_OUT), 256, 0, stream>>>(
        ybb, opw16, mo, NTOK, DMODEL, DINNER, DINNER / KSPL_OUT);

    // 7) out = LayerNorm(sum mo_z + x) * ln_w + ln_b
    ln_kernel<<<NTOK, 256, 0, stream>>>(mo, x, ln_w, ln_b, out);
}

// Round 15
// 237.048 us; speedup vs baseline: 5.0571x; 1.0301x over previous
//
#include <hip/hip_runtime.h>
#include <hip/hip_bf16.h>
#include <math.h>

// Problem dims (compile-time constants)
#define BATCH   2
#define SEQ     1024
#define DMODEL  768
#define DINNER  1536
#define DSTATE  16
#define DTRANK  48
#define NTOK    (BATCH*SEQ)          // 2048
#define XPROJ_N (DTRANK + 2*DSTATE)  // 80
#define XP_PSZ  ((size_t)NTOK * XPROJ_N)   // one x_proj partial

// chunked scan params
#define LC      32
#define NC      (SEQ/LC)             // 32

// split-K factors
#define KSPL_IN   2                  // in_proj: 24x16x2 = 768 blocks
#define KSPL_OUT  4                  // out_proj: 6x16x4 = 384 blocks
#define KSPL_XP   8                  // x_proj: partial buffers, consumer-side reduce

typedef unsigned short ushort_t;
typedef __attribute__((ext_vector_type(8))) short bf16x8;
typedef __attribute__((ext_vector_type(4))) float f32x4;

__device__ __forceinline__ ushort_t f2bf(float f) {
    unsigned int u = __float_as_uint(f);
    u += 0x7FFF + ((u >> 16) & 1);       // round-to-nearest-even
    return (ushort_t)(u >> 16);
}
__device__ __forceinline__ float bf2f(ushort_t u) {
    return __uint_as_float((unsigned int)u << 16);
}

// ---------------- fused fp32 -> bf16 converter (3 segments) ----------------
__global__ __launch_bounds__(256)
void f2b_3(const float* __restrict__ s0, ushort_t* __restrict__ d0, int n0,
           const float* __restrict__ s1, ushort_t* __restrict__ d1, int n1,
           const float* __restrict__ s2, ushort_t* __restrict__ d2, int n2)
{
    const int i = (blockIdx.x * 256 + threadIdx.x) * 4;
    const float* s; ushort_t* d;
    if (i < n0)               { s = s0 + i;            d = d0 + i; }
    else if (i < n0 + n1)     { s = s1 + (i - n0);     d = d1 + (i - n0); }
    else if (i < n0 + n1 + n2){ s = s2 + (i - n0 - n1);d = d2 + (i - n0 - n1); }
    else return;
    const float4 v = *reinterpret_cast<const float4*>(s);
    ushort4 o;
    o.x = f2bf(v.x); o.y = f2bf(v.y); o.z = f2bf(v.z); o.w = f2bf(v.w);
    *reinterpret_cast<ushort4*>(d) = o;
}

// ---------------- split-K bf16 MFMA GEMM (TN), bf16 OUTPUT partials, XCD swizzle ----------------
// partial z -> C + z*M*N (ushort). Consumers sum the KSPL partials.
#define GLOAD_LDS16(gp, lp) \
    __builtin_amdgcn_global_load_lds((const __attribute__((address_space(1))) void*)(gp), \
                                     (__attribute__((address_space(3))) void*)(lp), 16, 0, 0)

__global__ __launch_bounds__(256)
void gemm_mfma_bt_sk(const ushort_t* __restrict__ A, const ushort_t* __restrict__ W,
                     ushort_t* __restrict__ C, int M, int N, int K, int klen)
{
    __shared__ ushort_t As[128 * 32];
    __shared__ ushort_t Bs[128 * 32];

    // XCD-aware bijective swizzle (nwg % 8 == 0 for both call sites)
    int flat = blockIdx.x + gridDim.x * (blockIdx.y + gridDim.y * blockIdx.z);
    const int nwg = gridDim.x * gridDim.y * gridDim.z;
    flat = (flat & 7) * (nwg >> 3) + (flat >> 3);
    const int bx = flat % gridDim.x;
    const int rem = flat / gridDim.x;
    const int by = rem % gridDim.y;
    const int bz = rem / gridDim.y;

    const int tid  = threadIdx.x;
    const int w    = tid >> 6;
    const int lane = tid & 63;
    const int m0 = by * 128;
    const int n0 = bx * 128;
    const int kbeg = bz * klen;
    ushort_t* Cp = C + (size_t)bz * M * N;

    const int lrow = lane >> 2;
    const int lcol = (lane & 3) * 8;

    const ushort_t* ga0 = A + (size_t)(m0 + w * 16 + lrow) * K + kbeg + lcol;
    const ushort_t* ga1 = ga0 + (size_t)64 * K;
    const ushort_t* gb0 = W + (size_t)(n0 + w * 16 + lrow) * K + kbeg + lcol;
    const ushort_t* gb1 = gb0 + (size_t)64 * K;

    ushort_t* lA0 = As + w * 512;
    ushort_t* lA1 = As + 64 * 32 + w * 512;
    ushort_t* lB0 = Bs + w * 512;
    ushort_t* lB1 = Bs + 64 * 32 + w * 512;

    const int wm = w >> 1, wn = w & 1;
    const int fr = lane & 15;
    const int kg = lane >> 4;

    f32x4 acc[4][4] = {};

    for (int kt = 0; kt < klen; kt += 32) {
        __syncthreads();
        GLOAD_LDS16(ga0 + kt, lA0);
        GLOAD_LDS16(ga1 + kt, lA1);
        GLOAD_LDS16(gb0 + kt, lB0);
        GLOAD_LDS16(gb1 + kt, lB1);
        __syncthreads();

        bf16x8 af[4], bfr[4];
        #pragma unroll
        for (int i = 0; i < 4; ++i) {
            af[i]  = *reinterpret_cast<const bf16x8*>(&As[(wm * 64 + i * 16 + fr) * 32 + kg * 8]);
            bfr[i] = *reinterpret_cast<const bf16x8*>(&Bs[(wn * 64 + i * 16 + fr) * 32 + kg * 8]);
        }
        #pragma unroll
        for (int i = 0; i < 4; ++i)
            #pragma unroll
            for (int j = 0; j < 4; ++j)
                acc[i][j] = __builtin_amdgcn_mfma_f32_16x16x32_bf16(af[i], bfr[j], acc[i][j], 0, 0, 0);
    }

    // C/D layout: col = lane&15, row = (lane>>4)*4 + reg
    #pragma unroll
    for (int i = 0; i < 4; ++i) {
        const int row_base = m0 + wm * 64 + i * 16 + kg * 4;
        #pragma unroll
        for (int j = 0; j < 4; ++j) {
            const int col = n0 + wn * 64 + j * 16 + fr;
            #pragma unroll
            for (int r = 0; r < 4; ++r)
                Cp[(size_t)(row_base + r) * N + col] = f2bf(acc[i][j][r]);
        }
    }
}

#define BM 64
#define BN 64
#define BK 16

// ---------------- x_proj split-K fp32 SGEMM -> 8 partial buffers (no atomics) ----------------
__global__ __launch_bounds__(256)
void gemm_tn_xp(const float* __restrict__ A, const float* __restrict__ W,
                float* __restrict__ C)   // C: KSPL_XP partials of (NTOK x 80)
{
    __shared__ float As[BK][BM + 4];
    __shared__ float Ws[BK][BN + 4];

    const int N = XPROJ_N, K = DINNER, lda = DINNER;
    const int kchunk = DINNER / KSPL_XP;

    const int t  = threadIdx.x;
    const int tx = t & 15;
    const int ty = t >> 4;
    const int row0 = blockIdx.y * BM;
    const int col0 = blockIdx.x * BN;
    const int kbeg = blockIdx.z * kchunk;
    const int kend = kbeg + kchunk;
    float* Cp = C + (size_t)blockIdx.z * XP_PSZ;

    const int m_l = t >> 2;
    const int k_l = (t & 3) * 4;

    float acc[4][4] = {};

    for (int kt = kbeg; kt < kend; kt += BK) {
        float4 av, wv;
        {
            const float* ap = A + (size_t)(row0 + m_l) * lda + kt + k_l;
            av = *reinterpret_cast<const float4*>(ap);
        }
        {
            const int wn = col0 + m_l;
            if (wn < N) {
                const float* wp = W + (size_t)wn * K + kt + k_l;
                wv = *reinterpret_cast<const float4*>(wp);
            } else {
                wv = make_float4(0.f, 0.f, 0.f, 0.f);
            }
        }
        __syncthreads();
        As[k_l + 0][m_l] = av.x; As[k_l + 1][m_l] = av.y;
        As[k_l + 2][m_l] = av.z; As[k_l + 3][m_l] = av.w;
        Ws[k_l + 0][m_l] = wv.x; Ws[k_l + 1][m_l] = wv.y;
        Ws[k_l + 2][m_l] = wv.z; Ws[k_l + 3][m_l] = wv.w;
        __syncthreads();

        #pragma unroll
        for (int k = 0; k < BK; ++k) {
            float4 a4 = *reinterpret_cast<const float4*>(&As[k][ty * 4]);
            float4 w4 = *reinterpret_cast<const float4*>(&Ws[k][tx * 4]);
            float af[4] = {a4.x, a4.y, a4.z, a4.w};
            float wf[4] = {w4.x, w4.y, w4.z, w4.w};
            #pragma unroll
            for (int i = 0; i < 4; ++i)
                #pragma unroll
                for (int j = 0; j < 4; ++j)
                    acc[i][j] += af[i] * wf[j];
        }
    }

    #pragma unroll
    for (int i = 0; i < 4; ++i) {
        const int m = row0 + ty * 4 + i;
        #pragma unroll
        for (int j = 0; j < 4; ++j) {
            const int n = col0 + tx * 4 + j;
            if (n < N)
                Cp[(size_t)m * N + n] = acc[i][j];
        }
    }
}

// ---------------- dt_proj fp32 SGEMM; A = sum of 8 x_proj partials; softplus; bf16 out ----------------
__global__ __launch_bounds__(256)
void gemm_tn_dt(const float* __restrict__ Ap, const float* __restrict__ W,
                const float* __restrict__ bias, ushort_t* __restrict__ C)
{
    __shared__ float As[BK][BM + 4];
    __shared__ float Ws[BK][BN + 4];

    const int N = DINNER, K = DTRANK, lda = XPROJ_N;

    const int t  = threadIdx.x;
    const int tx = t & 15;
    const int ty = t >> 4;
    const int row0 = blockIdx.y * BM;
    const int col0 = blockIdx.x * BN;

    const int m_l = t >> 2;
    const int k_l = (t & 3) * 4;

    float acc[4][4] = {};

    for (int kt = 0; kt < K; kt += BK) {
        float4 av = make_float4(0.f, 0.f, 0.f, 0.f);
        {
            const size_t off = (size_t)(row0 + m_l) * lda + kt + k_l;
            #pragma unroll
            for (int p = 0; p < KSPL_XP; ++p) {
                const float4 v = *reinterpret_cast<const float4*>(Ap + p * XP_PSZ + off);
                av.x += v.x; av.y += v.y; av.z += v.z; av.w += v.w;
            }
        }
        float4 wv;
        {
            const int wn = col0 + m_l;
            const float* wp = W + (size_t)wn * K + kt + k_l;
            wv = *reinterpret_cast<const float4*>(wp);
        }
        __syncthreads();
        As[k_l + 0][m_l] = av.x; As[k_l + 1][m_l] = av.y;
        As[k_l + 2][m_l] = av.z; As[k_l + 3][m_l] = av.w;
        Ws[k_l + 0][m_l] = wv.x; Ws[k_l + 1][m_l] = wv.y;
        Ws[k_l + 2][m_l] = wv.z; Ws[k_l + 3][m_l] = wv.w;
        __syncthreads();

        #pragma unroll
        for (int k = 0; k < BK; ++k) {
            float4 a4 = *reinterpret_cast<const float4*>(&As[k][ty * 4]);
            float4 w4 = *reinterpret_cast<const float4*>(&Ws[k][tx * 4]);
            float af[4] = {a4.x, a4.y, a4.z, a4.w};
            float wf[4] = {w4.x, w4.y, w4.z, w4.w};
            #pragma unroll
            for (int i = 0; i < 4; ++i)
                #pragma unroll
                for (int j = 0; j < 4; ++j)
                    acc[i][j] += af[i] * wf[j];
        }
    }

    #pragma unroll
    for (int i = 0; i < 4; ++i) {
        const int m = row0 + ty * 4 + i;
        #pragma unroll
        for (int j = 0; j < 4; ++j) {
            const int n = col0 + tx * 4 + j;
            float v = acc[i][j] + bias[n];
            v = (v > 20.f) ? v : log1pf(expf(v));
            C[(size_t)m * N + n] = f2bf(v);
        }
    }
}

// ---------------- depthwise causal conv (k=4) + bias + SiLU; bf16 xz partials in, fp32 xc out ----------------
__global__ __launch_bounds__(256)
void conv_silu(const ushort_t* __restrict__ xzA, const ushort_t* __restrict__ xzB,
               const float* __restrict__ cw, const float* __restrict__ cb,
               float* __restrict__ xc)
{
    const int vid = blockIdx.x * 256 + threadIdx.x;        // over NTOK*DINNER/4
    const int c4 = (vid % (DINNER / 4)) * 4;
    const int m  = vid / (DINNER / 4);
    const int l  = m & (SEQ - 1);
    const int R  = 2 * DINNER;

    const ushort_t* a = xzA + (size_t)m * R + c4;
    const ushort_t* b = xzB + (size_t)m * R + c4;

    float4 W0 = *reinterpret_cast<const float4*>(cw + (c4 + 0) * 4);
    float4 W1 = *reinterpret_cast<const float4*>(cw + (c4 + 1) * 4);
    float4 W2 = *reinterpret_cast<const float4*>(cw + (c4 + 2) * 4);
    float4 W3 = *reinterpret_cast<const float4*>(cw + (c4 + 3) * 4);
    const float4 bias = *reinterpret_cast<const float4*>(cb + c4);

    float acc0 = bias.x, acc1 = bias.y, acc2 = bias.z, acc3 = bias.w;

    {
        const ushort4 ua = *reinterpret_cast<const ushort4*>(a);
        const ushort4 ub = *reinterpret_cast<const ushort4*>(b);
        acc0 += (bf2f(ua.x) + bf2f(ub.x)) * W0.w;
        acc1 += (bf2f(ua.y) + bf2f(ub.y)) * W1.w;
        acc2 += (bf2f(ua.z) + bf2f(ub.z)) * W2.w;
        acc3 += (bf2f(ua.w) + bf2f(ub.w)) * W3.w;
    }
    if (l >= 1) {
        const ushort4 ua = *reinterpret_cast<const ushort4*>(a - R);
        const ushort4 ub = *reinterpret_cast<const ushort4*>(b - R);
        acc0 += (bf2f(ua.x) + bf2f(ub.x)) * W0.z;
        acc1 += (bf2f(ua.y) + bf2f(ub.y)) * W1.z;
        acc2 += (bf2f(ua.z) + bf2f(ub.z)) * W2.z;
        acc3 += (bf2f(ua.w) + bf2f(ub.w)) * W3.z;
    }
    if (l >= 2) {
        const ushort4 ua = *reinterpret_cast<const ushort4*>(a - 2 * R);
        const ushort4 ub = *reinterpret_cast<const ushort4*>(b - 2 * R);
        acc0 += (bf2f(ua.x) + bf2f(ub.x)) * W0.y;
        acc1 += (bf2f(ua.y) + bf2f(ub.y)) * W1.y;
        acc2 += (bf2f(ua.z) + bf2f(ub.z)) * W2.y;
        acc3 += (bf2f(ua.w) + bf2f(ub.w)) * W3.y;
    }
    if (l >= 3) {
        const ushort4 ua = *reinterpret_cast<const ushort4*>(a - 3 * R);
        const ushort4 ub = *reinterpret_cast<const ushort4*>(b - 3 * R);
        acc0 += (bf2f(ua.x) + bf2f(ub.x)) * W0.x;
        acc1 += (bf2f(ua.y) + bf2f(ub.y)) * W1.x;
        acc2 += (bf2f(ua.z) + bf2f(ub.z)) * W2.x;
        acc3 += (bf2f(ua.w) + bf2f(ub.w)) * W3.x;
    }

    float4 o;
    o.x = acc0 / (1.f + __expf(-acc0));
    o.y = acc1 / (1.f + __expf(-acc1));
    o.z = acc2 / (1.f + __expf(-acc2));
    o.w = acc3 / (1.f + __expf(-acc3));
    *reinterpret_cast<float4*>(xc + (size_t)m * DINNER + c4) = o;
}

// ---------------- chunked selective scan: thread-owns-d, 16 states in registers ----------------
__global__ __launch_bounds__(256)
void scan_chunk_state(const ushort_t* __restrict__ dt, const float* __restrict__ xc,
                      const float* __restrict__ xdblP, const float* __restrict__ A_log,
                      float* __restrict__ hA, float* __restrict__ aP)
{
    __shared__ float B_s[LC * 16];

    const int c  = blockIdx.x;
    const int d0 = blockIdx.y * 256;
    const int b  = blockIdx.z;
    const int t  = threadIdx.x;
    const int d  = d0 + t;

    const size_t row0 = (size_t)b * SEQ + (size_t)c * LC;

    #pragma unroll
    for (int p = 0; p < (LC * 16) / 256; ++p) {
        const int idx = p * 256 + t;
        const int l = idx >> 4, j = idx & 15;
        const size_t off = (row0 + l) * XPROJ_N + DTRANK + j;
        float v = 0.f;
        #pragma unroll
        for (int q = 0; q < KSPL_XP; ++q) v += xdblP[q * XP_PSZ + off];
        B_s[idx] = v;
    }
    __syncthreads();

    float Aval[16];
    #pragma unroll
    for (int q = 0; q < 4; ++q) {
        const float4 a4 = *reinterpret_cast<const float4*>(&A_log[(size_t)d * DSTATE + q * 4]);
        Aval[q*4+0] = -expf(a4.x); Aval[q*4+1] = -expf(a4.y);
        Aval[q*4+2] = -expf(a4.z); Aval[q*4+3] = -expf(a4.w);
    }

    float h[16];
    #pragma unroll
    for (int s = 0; s < 16; ++s) h[s] = 0.f;
    float dts = 0.f;

    #pragma unroll 2
    for (int l = 0; l < LC; ++l) {
        const size_t m = row0 + l;
        const float dtv = bf2f(dt[m * DINNER + d]);
        const float u   = xc[m * DINNER + d];
        const float du  = dtv * u;
        dts += dtv;
        float Bv[16];
        #pragma unroll
        for (int q = 0; q < 4; ++q) {
            const float4 b4 = *reinterpret_cast<const float4*>(&B_s[l * 16 + q * 4]);
            Bv[q*4+0] = b4.x; Bv[q*4+1] = b4.y; Bv[q*4+2] = b4.z; Bv[q*4+3] = b4.w;
        }
        #pragma unroll
        for (int s = 0; s < 16; ++s)
            h[s] = h[s] * __expf(dtv * Aval[s]) + du * Bv[s];
    }

    const size_t o = (((size_t)(b * NC + c) * DINNER) + d) * DSTATE;
    #pragma unroll
    for (int q = 0; q < 4; ++q) {
        float4 hv = make_float4(h[q*4+0], h[q*4+1], h[q*4+2], h[q*4+3]);
        float4 pv = make_float4(__expf(Aval[q*4+0]*dts), __expf(Aval[q*4+1]*dts),
                                __expf(Aval[q*4+2]*dts), __expf(Aval[q*4+3]*dts));
        *reinterpret_cast<float4*>(&hA[o + q*4]) = hv;
        *reinterpret_cast<float4*>(&aP[o + q*4]) = pv;
    }
}

// Phase B: prefetch all NC aggregates, then run the dependent chain.
__global__ __launch_bounds__(256)
void scan_combine(float* __restrict__ hA, const float* __restrict__ aP)
{
    const int idx = blockIdx.x * 256 + threadIdx.x;   // over BATCH*DINNER*DSTATE
    const int b  = idx / (DINNER * DSTATE);
    const int ds = idx % (DINNER * DSTATE);
    const size_t stride = (size_t)DINNER * DSTATE;
    const size_t base = (size_t)b * NC * stride + ds;

    float a[NC], p[NC];
    #pragma unroll
    for (int c = 0; c < NC; ++c) {
        a[c] = hA[base + (size_t)c * stride];
        p[c] = aP[base + (size_t)c * stride];
    }
    float h = 0.f;
    #pragma unroll
    for (int c = 0; c < NC; ++c) {
        const float hn = a[c] + h * p[c];
        hA[base + (size_t)c * stride] = h;
        h = hn;
    }
}

// Phase C: z from 2 bf16 in_proj partials; B/C from 8 x_proj partials; emit y as bf16.
__global__ __launch_bounds__(256)
void scan_apply(const ushort_t* __restrict__ dt, const float* __restrict__ xc,
                const float* __restrict__ xdblP,
                const ushort_t* __restrict__ xzA, const ushort_t* __restrict__ xzB,
                const float* __restrict__ A_log, const float* __restrict__ Dp,
                const float* __restrict__ hInit, ushort_t* __restrict__ y)
{
    __shared__ float B_s[LC * 16];
    __shared__ float C_s[LC * 16];

    const int c  = blockIdx.x;
    const int d0 = blockIdx.y * 256;
    const int b  = blockIdx.z;
    const int t  = threadIdx.x;
    const int d  = d0 + t;

    const size_t row0 = (size_t)b * SEQ + (size_t)c * LC;

    #pragma unroll
    for (int p = 0; p < (LC * 16) / 256; ++p) {
        const int idx = p * 256 + t;
        const int l = idx >> 4, j = idx & 15;
        const size_t offB = (row0 + l) * XPROJ_N + DTRANK + j;
        float vb = 0.f, vc = 0.f;
        #pragma unroll
        for (int q = 0; q < KSPL_XP; ++q) {
            vb += xdblP[q * XP_PSZ + offB];
            vc += xdblP[q * XP_PSZ + offB + DSTATE];
        }
        B_s[idx] = vb;
        C_s[idx] = vc;
    }
    __syncthreads();

    float Aval[16];
    #pragma unroll
    for (int q = 0; q < 4; ++q) {
        const float4 a4 = *reinterpret_cast<const float4*>(&A_log[(size_t)d * DSTATE + q * 4]);
        Aval[q*4+0] = -expf(a4.x); Aval[q*4+1] = -expf(a4.y);
        Aval[q*4+2] = -expf(a4.z); Aval[q*4+3] = -expf(a4.w);
    }
    const float Dd = Dp[d];

    const size_t o = (((size_t)(b * NC + c) * DINNER) + d) * DSTATE;
    float h[16];
    #pragma unroll
    for (int q = 0; q < 4; ++q) {
        const float4 h4 = *reinterpret_cast<const float4*>(&hInit[o + q*4]);
        h[q*4+0] = h4.x; h[q*4+1] = h4.y; h[q*4+2] = h4.z; h[q*4+3] = h4.w;
    }

    #pragma unroll 2
    for (int l = 0; l < LC; ++l) {
        const size_t m = row0 + l;
        const float dtv = bf2f(dt[m * DINNER + d]);
        const float u   = xc[m * DINNER + d];
        const size_t zi = m * (2 * DINNER) + DINNER + d;
        const float zv  = bf2f(xzA[zi]) + bf2f(xzB[zi]);
        const float du  = dtv * u;

        float acc = 0.f;
        #pragma unroll
        for (int q = 0; q < 4; ++q) {
            const float4 b4 = *reinterpret_cast<const float4*>(&B_s[l * 16 + q * 4]);
            const float4 c4 = *reinterpret_cast<const float4*>(&C_s[l * 16 + q * 4]);
            const float bb[4] = {b4.x, b4.y, b4.z, b4.w};
            const float cc[4] = {c4.x, c4.y, c4.z, c4.w};
            #pragma unroll
            for (int r = 0; r < 4; ++r) {
                const int s = q * 4 + r;
                h[s] = h[s] * __expf(dtv * Aval[s]) + du * bb[r];
                acc += h[s] * cc[r];
            }
        }

        const float yv  = acc + u * Dd;
        const float sig = 1.f / (1.f + __expf(-zv));
        y[m * DINNER + d] = f2bf(yv * zv * sig);
    }
}

// ---------------- residual + LayerNorm; mo = sum of KSPL_OUT bf16 partials ----------------
__global__ __launch_bounds__(256)
void ln_kernel(const ushort_t* __restrict__ mo, const float* __restrict__ x,
               const float* __restrict__ w, const float* __restrict__ bias,
               float* __restrict__ out)
{
    const int m = blockIdx.x;
    const int t = threadIdx.x;
    const size_t MN = (size_t)NTOK * DMODEL;
    const ushort_t* mrow = mo + (size_t)m * DMODEL;
    const float* xrow = x + (size_t)m * DMODEL;

    float v[3];
    float sum = 0.f, ss = 0.f;
    #pragma unroll
    for (int i = 0; i < 3; ++i) {
        const int col = t + 256 * i;
        float acc = xrow[col];
        #pragma unroll
        for (int p = 0; p < KSPL_OUT; ++p)
            acc += bf2f(mrow[p * MN + col]);
        v[i] = acc;
        sum += acc;
        ss  += acc * acc;
    }
    #pragma unroll
    for (int o = 1; o < 64; o <<= 1) {
        sum += __shfl_xor(sum, o);
        ss  += __shfl_xor(ss, o);
    }
    __shared__ float red[2][4];
    const int wid = t >> 6;
    if ((t & 63) == 0) { red[0][wid] = sum; red[1][wid] = ss; }
    __syncthreads();
    sum = red[0][0] + red[0][1] + red[0][2] + red[0][3];
    ss  = red[1][0] + red[1][1] + red[1][2] + red[1][3];

    const float mu   = sum * (1.f / DMODEL);
    const float var  = ss * (1.f / DMODEL) - mu * mu;
    const float rstd = rsqrtf(var + 1e-5f);

    #pragma unroll
    for (int i = 0; i < 3; ++i) {
        const int col = t + 256 * i;
        out[(size_t)m * DMODEL + col] = (v[i] - mu) * rstd * w[col] + bias[col];
    }
}

// ---------------- launcher ----------------
extern "C" void kernel_launch(void* const* d_in, const int* in_sizes, int n_in,
                              void* d_out, int out_size, void* d_ws, size_t ws_size,
                              hipStream_t stream)
{
    const float* x          = (const float*)d_in[0];
    const float* in_proj_w  = (const float*)d_in[1];
    const float* conv_w     = (const float*)d_in[2];
    const float* conv_b     = (const float*)d_in[3];
    const float* x_proj_w   = (const float*)d_in[4];
    const float* dt_proj_w  = (const float*)d_in[5];
    const float* dt_proj_b  = (const float*)d_in[6];
    const float* A_log      = (const float*)d_in[7];
    const float* Dp         = (const float*)d_in[8];
    const float* out_proj_w = (const float*)d_in[9];
    const float* ln_w       = (const float*)d_in[10];
    const float* ln_b       = (const float*)d_in[11];
    float* out = (float*)d_out;

    // workspace layout: fp32 arrays first, then bf16 arrays (all 16B-aligned)
    float* ws   = (float*)d_ws;
    float* xc   = ws;                                      // NTOK*1536 fp32
    float* xdbl = xc + (size_t)NTOK * 1536;                // KSPL_XP x NTOK*80 fp32
    ushort_t* xz   = (ushort_t*)(xdbl + (size_t)KSPL_XP * XP_PSZ);  // KSPL_IN x NTOK*3072 bf16
    ushort_t* dt   = xz + (size_t)KSPL_IN * NTOK * 3072;   // NTOK*1536 bf16
    ushort_t* mo   = dt + (size_t)NTOK * 1536;             // KSPL_OUT x NTOK*768 bf16
    ushort_t* xb16 = mo + (size_t)KSPL_OUT * NTOK * 768;   // NTOK*768 bf16
    ushort_t* ipw16 = xb16  + (size_t)NTOK * DMODEL;       // 2*DINNER*DMODEL
    ushort_t* opw16 = ipw16 + (size_t)2 * DINNER * DMODEL; // DMODEL*DINNER
    ushort_t* ybb   = opw16 + (size_t)DMODEL * DINNER;     // NTOK*DINNER

    ushort_t* xzA = xz;
    ushort_t* xzB = xz + (size_t)NTOK * 3072;

    // scan scratch aliases (dead during scan):
    //   aP -> mo region (12.6 MB >= 6.3 MB needed); hA -> d_out (exact fit)
    float* aP = (float*)mo;
    float* hA = (float*)d_out;

    // 0) bf16 conversions: x, in_proj_w, out_proj_w
    {
        const int n0 = NTOK * DMODEL;
        const int n1 = 2 * DINNER * DMODEL;
        const int n2 = DMODEL * DINNER;
        const int nvec = (n0 + n1 + n2) / 4;
        f2b_3<<<(nvec + 255) / 256, 256, 0, stream>>>(
            x, xb16, n0, in_proj_w, ipw16, n1, out_proj_w, opw16, n2);
    }

    // 1) xz = x @ in_proj_w^T  (bf16 MFMA split-K=2 -> 768 blocks; bf16 partials out)
    gemm_mfma_bt_sk<<<dim3(2 * DINNER / 128, NTOK / 128, KSPL_IN), 256, 0, stream>>>(
        xb16, ipw16, xz, NTOK, 2 * DINNER, DMODEL, DMODEL / KSPL_IN);

    // 2) xc = silu(conv(xbA+xbB) + conv_b)   (bf16 in, fp32 out)
    conv_silu<<<(NTOK * DINNER / 4) / 256, 256, 0, stream>>>(xzA, xzB, conv_w, conv_b, xc);

    // 3) x_dbl partials = xc @ x_proj_w^T  (fp32 split-K=8, partial buffers)
    gemm_tn_xp<<<dim3((XPROJ_N + BN - 1) / BN, NTOK / BM, KSPL_XP), 256, 0, stream>>>(
        xc, x_proj_w, xdbl);

    // 4) dt = softplus((sum partials)[:, :48] @ dt_proj_w^T + dt_proj_b)  (bf16 out)
    gemm_tn_dt<<<dim3(DINNER / BN, NTOK / BM), 256, 0, stream>>>(
        xdbl, dt_proj_w, dt_proj_b, dt);

    // 5) chunked selective scan (thread-owns-d); phase C writes y as bf16
    scan_chunk_state<<<dim3(NC, DINNER / 256, BATCH), 256, 0, stream>>>(
        dt, xc, xdbl, A_log, hA, aP);
    scan_combine<<<(BATCH * DINNER * DSTATE) / 256, 256, 0, stream>>>(hA, aP);
    scan_apply<<<dim3(NC, DINNER / 256, BATCH), 256, 0, stream>>>(
        dt, xc, xdbl, xzA, xzB, A_log, Dp, hA, ybb);

    // 6) mo_z = y @ out_proj_w^T  (bf16 MFMA split-K=4 -> 384 blocks; bf16 partials out)
    gemm_mfma_bt_sk<<<dim3(DMODEL / 128, NTOK / 128, KSPL_OUT), 256, 0, stream>>>(
        ybb, opw16, mo, NTOK, DMODEL, DINNER, DINNER / KSPL_OUT);

    // 7) out = LayerNorm(sum mo_z + x) * ln_w + ln_b
    ln_kernel<<<NTOK, 256, 0, stream>>>(mo, x, ln_w, ln_b, out);
}